// Round 2
// baseline (7038.593 us; speedup 1.0000x reference)
//
#include <hip/hip_runtime.h>
#include <math.h>

#define EPS 1e-5f

// ---------------- wave/block reduction helpers ----------------
__device__ __forceinline__ float wave_sum(float v) {
#pragma unroll
    for (int o = 32; o; o >>= 1) v += __shfl_xor(v, o);
    return v;
}
__device__ __forceinline__ float wave_max(float v) {
#pragma unroll
    for (int o = 32; o; o >>= 1) v = fmaxf(v, __shfl_xor(v, o));
    return v;
}

// ---------------- scatter 1: q = cls(copied) += rmsnorm(roots)[r] * w at col c ----------------
// unit = h*1024 + i  (H=16, CR=1024); one wave per unit
__global__ __launch_bounds__(256) void scatter1(const float* __restrict__ roots,
                                                const float* __restrict__ w,
                                                const int* __restrict__ idx,
                                                float* __restrict__ q) {
    int unit = (blockIdx.x << 2) + (threadIdx.x >> 6);
    int lane = threadIdx.x & 63;
    int h = unit >> 10;
    int i = unit & 1023;
    int r = idx[i];           // [0,256)
    int c = idx[1024 + i];    // [0,4096)
    float val = roots[(h * 256 + r) * 64 + lane];
    float ss = wave_sum(val * val);
    float rs = rsqrtf(ss * (1.f / 64.f) + EPS);
    atomicAdd(&q[(h * 4096 + c) * 64 + lane], val * rs * w[(h << 10) + i]);
}

// ---------------- scatter 2: q += q_det[c1] * w at col c2 ----------------
// unit = h*2048 + i  (SC=2048)
__global__ __launch_bounds__(256) void scatter2(const float* __restrict__ qdet,
                                                const float* __restrict__ w,
                                                const int* __restrict__ idx,
                                                float* __restrict__ q) {
    int unit = (blockIdx.x << 2) + (threadIdx.x >> 6);
    int lane = threadIdx.x & 63;
    int h = unit >> 11;
    int i = unit & 2047;
    int c1 = idx[i];
    int c2 = idx[2048 + i];
    float val = qdet[(h * 4096 + c1) * 64 + lane] * w[(h << 11) + i];
    atomicAdd(&q[(h * 4096 + c2) * 64 + lane], val);
}

// ---------------- rmsnorm rows of length 64, in place (65536 rows) ----------------
__global__ __launch_bounds__(256) void rms_rows64(float* __restrict__ q) {
    int unit = (blockIdx.x << 2) + (threadIdx.x >> 6);
    int lane = threadIdx.x & 63;
    float v = q[unit * 64 + lane];
    float ss = wave_sum(v * v);
    q[unit * 64 + lane] = v * rsqrtf(ss * (1.f / 64.f) + EPS);
}

// ---------------- GEMM: kv = x (1024x1024) @ kv_w^T (2048x1024) ----------------
__global__ __launch_bounds__(256) void gemm_kv(const float* __restrict__ A,
                                               const float* __restrict__ Bw,
                                               float* __restrict__ Cout) {
    const int K = 1024, N = 2048;
    __shared__ float As[16][65];
    __shared__ float Bs[16][65];
    int tid = threadIdx.x;
    int tx = tid & 15, ty = tid >> 4;
    int bm = blockIdx.y, bn = blockIdx.x;
    float acc[4][4] = {};
    for (int k0 = 0; k0 < K; k0 += 16) {
#pragma unroll
        for (int mm = 0; mm < 4; ++mm) {
            int m = (tid >> 4) + mm * 16;
            int kk = tid & 15;
            As[kk][m] = A[(bm * 64 + m) * K + k0 + kk];
            Bs[kk][m] = Bw[(bn * 64 + m) * K + k0 + kk];
        }
        __syncthreads();
#pragma unroll
        for (int kk = 0; kk < 16; ++kk) {
            float a[4], b[4];
#pragma unroll
            for (int i = 0; i < 4; i++) a[i] = As[kk][ty * 4 + i];
#pragma unroll
            for (int j = 0; j < 4; j++) b[j] = Bs[kk][tx * 4 + j];
#pragma unroll
            for (int i = 0; i < 4; i++)
#pragma unroll
                for (int j = 0; j < 4; j++) acc[i][j] += a[i] * b[j];
        }
        __syncthreads();
    }
#pragma unroll
    for (int i = 0; i < 4; i++)
#pragma unroll
        for (int j = 0; j < 4; j++)
            Cout[(bm * 64 + ty * 4 + i) * N + bn * 64 + tx * 4 + j] = acc[i][j];
}

// ---------------- kv split: k rmsnorm + transpose to (B,H,S,64); v transpose ----------------
// unit = ((b*16+h)*256+s), 16384 units
__global__ __launch_bounds__(256) void kvsplit(const float* __restrict__ kv,
                                               float* __restrict__ kn,
                                               float* __restrict__ vout) {
    int unit = (blockIdx.x << 2) + (threadIdx.x >> 6);
    int lane = threadIdx.x & 63;
    int b = unit >> 12;
    int h = (unit >> 8) & 15;
    int s = unit & 255;
    int row = b * 256 + s;
    float kvl = kv[row * 2048 + (h << 6) + lane];
    float vvl = kv[row * 2048 + 1024 + (h << 6) + lane];
    float ss = wave_sum(kvl * kvl);
    float rs = rsqrtf(ss * (1.f / 64.f) + EPS);
    kn[unit * 64 + lane] = kvl * rs;
    vout[unit * 64 + lane] = vvl;
}

// ---------------- attention: per block (b,h, chunk of 16 c rows) ----------------
__global__ __launch_bounds__(256) void attn_kernel(const float* __restrict__ qn,
                                                   const float* __restrict__ kn,
                                                   const float* __restrict__ vv,
                                                   float* __restrict__ o) {
    __shared__ float qL[16][64];
    __shared__ float p[256];
    __shared__ float part[4][64];
    __shared__ float redm[4];
    __shared__ float reds[4];
    int bid = blockIdx.x;
    int bh = bid >> 8;   // 256 c-chunks per (b,h)
    int cc = bid & 255;
    int b = bh >> 4, h = bh & 15;
    int tid = threadIdx.x;
    int c0 = cc << 4;
    for (int e = tid; e < 1024; e += 256)
        qL[e >> 6][e & 63] = qn[h * 262144 + (c0 << 6) + e];
    // cache this thread's K row (s = tid) in registers
    const float4* k4 = (const float4*)(kn + bh * 16384);
    float4 kreg[16];
#pragma unroll
    for (int i = 0; i < 16; i++) kreg[i] = k4[tid * 16 + i];
    // cache this thread's V column slice in registers
    int sg = tid >> 6, d = tid & 63;
    const float* vp = vv + bh * 16384 + (sg << 6) * 64 + d;
    float vreg[64];
#pragma unroll
    for (int si = 0; si < 64; si++) vreg[si] = vp[si * 64];
    __syncthreads();

    for (int ci = 0; ci < 16; ++ci) {
        float sc = 0.f;
#pragma unroll
        for (int i = 0; i < 16; i++) {
            float4 kkv = kreg[i];
            sc += qL[ci][4 * i + 0] * kkv.x + qL[ci][4 * i + 1] * kkv.y +
                  qL[ci][4 * i + 2] * kkv.z + qL[ci][4 * i + 3] * kkv.w;
        }
        sc *= 0.125f;  // 1/sqrt(64)
        float m = wave_max(sc);
        if ((tid & 63) == 0) redm[tid >> 6] = m;
        __syncthreads();
        m = fmaxf(fmaxf(redm[0], redm[1]), fmaxf(redm[2], redm[3]));
        float ev = expf(sc - m);
        p[tid] = ev;
        float ssum = wave_sum(ev);
        if ((tid & 63) == 0) reds[tid >> 6] = ssum;
        __syncthreads();  // covers p[] and reds[]
        float denom = reds[0] + reds[1] + reds[2] + reds[3];
        float acc = 0.f;
#pragma unroll
        for (int si = 0; si < 64; si++) acc += p[(sg << 6) + si] * vreg[si];
        part[sg][d] = acc;
        __syncthreads();
        if (tid < 64) {
            float ov = (part[0][tid] + part[1][tid] + part[2][tid] + part[3][tid]) / denom;
            o[((b << 12) + c0 + ci) * 1024 + (h << 6) + tid] = ov;
        }
        __syncthreads();  // protect p/redm/reds/part for next iter
    }
}

// ---------------- LayerNorm stats per row of 1024 ----------------
__global__ __launch_bounds__(256) void ln_stats(const float* __restrict__ o,
                                                float* __restrict__ mu,
                                                float* __restrict__ rstd) {
    __shared__ float r0[4], r1[4];
    int row = blockIdx.x;
    int tid = threadIdx.x;
    const float* op = o + (size_t)row * 1024;
    float s = 0, sq = 0;
    for (int a = tid; a < 1024; a += 256) {
        float v = op[a];
        s += v;
        sq += v * v;
    }
    s = wave_sum(s);
    sq = wave_sum(sq);
    if ((tid & 63) == 0) { r0[tid >> 6] = s; r1[tid >> 6] = sq; }
    __syncthreads();
    if (tid == 0) {
        float S = r0[0] + r0[1] + r0[2] + r0[3];
        float Q = r1[0] + r1[1] + r1[2] + r1[3];
        float m = S * (1.f / 1024.f);
        float var = Q * (1.f / 1024.f) - m * m;
        mu[row] = m;
        rstd[row] = rsqrtf(var + EPS);
    }
}

// ---------------- FFN GEMM1: u = silu(LN(o) @ W1a^T) * (LN(o) @ W1b^T) ----------------
// rows are slice-global (R0 offset); u is slice-local 2048x3072
__global__ __launch_bounds__(256) void gemm_ffn1(const float* __restrict__ o,
                                                 const float* __restrict__ mu,
                                                 const float* __restrict__ rstd,
                                                 const float* __restrict__ gamma,
                                                 const float* __restrict__ beta,
                                                 const float* __restrict__ W,
                                                 float* __restrict__ u, int R0) {
    const int K = 1024, FF = 3072;
    __shared__ float As[16][65];
    __shared__ float B1s[16][65];
    __shared__ float B2s[16][65];
    int tid = threadIdx.x;
    int tx = tid & 15, ty = tid >> 4;
    int bm = blockIdx.y, bn = blockIdx.x;
    float acc1[4][4] = {}, acc2[4][4] = {};
    for (int k0 = 0; k0 < K; k0 += 16) {
#pragma unroll
        for (int mm = 0; mm < 4; ++mm) {
            int m = (tid >> 4) + mm * 16;
            int kk = tid & 15;
            int gr = R0 + bm * 64 + m;
            float val = (o[(size_t)gr * 1024 + k0 + kk] - mu[gr]) * rstd[gr] * gamma[k0 + kk] + beta[k0 + kk];
            As[kk][m] = val;
            B1s[kk][m] = W[(bn * 64 + m) * K + k0 + kk];
            B2s[kk][m] = W[(FF + bn * 64 + m) * K + k0 + kk];
        }
        __syncthreads();
#pragma unroll
        for (int kk = 0; kk < 16; ++kk) {
            float a[4], b1[4], b2[4];
#pragma unroll
            for (int i = 0; i < 4; i++) a[i] = As[kk][ty * 4 + i];
#pragma unroll
            for (int j = 0; j < 4; j++) { b1[j] = B1s[kk][tx * 4 + j]; b2[j] = B2s[kk][tx * 4 + j]; }
#pragma unroll
            for (int i = 0; i < 4; i++)
#pragma unroll
                for (int j = 0; j < 4; j++) {
                    acc1[i][j] += a[i] * b1[j];
                    acc2[i][j] += a[i] * b2[j];
                }
        }
        __syncthreads();
    }
#pragma unroll
    for (int i = 0; i < 4; i++)
#pragma unroll
        for (int j = 0; j < 4; j++) {
            float f1 = acc1[i][j], f2 = acc2[i][j];
            float sg = f1 / (1.f + expf(-f1));
            u[(size_t)(bm * 64 + ty * 4 + i) * 3072 + bn * 64 + tx * 4 + j] = sg * f2;
        }
}

// ---------------- FFN GEMM2: o[r] += u @ ff_out_w^T  (z = o + h, in place) ----------------
__global__ __launch_bounds__(256) void gemm_ffn2(const float* __restrict__ u,
                                                 const float* __restrict__ W,
                                                 float* __restrict__ o, int R0) {
    const int K = 3072;
    __shared__ float As[16][65];
    __shared__ float Bs[16][65];
    int tid = threadIdx.x;
    int tx = tid & 15, ty = tid >> 4;
    int bm = blockIdx.y, bn = blockIdx.x;
    float acc[4][4] = {};
    for (int k0 = 0; k0 < K; k0 += 16) {
#pragma unroll
        for (int mm = 0; mm < 4; ++mm) {
            int m = (tid >> 4) + mm * 16;
            int kk = tid & 15;
            As[kk][m] = u[(size_t)(bm * 64 + m) * 3072 + k0 + kk];
            Bs[kk][m] = W[(bn * 64 + m) * K + k0 + kk];
        }
        __syncthreads();
#pragma unroll
        for (int kk = 0; kk < 16; ++kk) {
            float a[4], b[4];
#pragma unroll
            for (int i = 0; i < 4; i++) a[i] = As[kk][ty * 4 + i];
#pragma unroll
            for (int j = 0; j < 4; j++) b[j] = Bs[kk][tx * 4 + j];
#pragma unroll
            for (int i = 0; i < 4; i++)
#pragma unroll
                for (int j = 0; j < 4; j++) acc[i][j] += a[i] * b[j];
        }
        __syncthreads();
    }
#pragma unroll
    for (int i = 0; i < 4; i++)
#pragma unroll
        for (int j = 0; j < 4; j++) {
            int gr = R0 + bm * 64 + ty * 4 + i;
            int col = bn * 64 + tx * 4 + j;
            o[(size_t)gr * 1024 + col] += acc[i][j];
        }
}

// ---------------- final: y = z @ out_w[c], out = silu(y0)*y1 ----------------
__global__ __launch_bounds__(256) void out_proj(const float* __restrict__ z,
                                                const float* __restrict__ ow,
                                                float* __restrict__ out) {
    __shared__ float r0[4], r1[4];
    int row = blockIdx.x;  // b*4096 + c
    int c = row & 4095;
    int tid = threadIdx.x;
    const float2* w2 = (const float2*)ow + (size_t)c * 1024;
    float y0 = 0, y1 = 0;
    for (int a = tid; a < 1024; a += 256) {
        float zv = z[(size_t)row * 1024 + a];
        float2 w = w2[a];
        y0 += zv * w.x;
        y1 += zv * w.y;
    }
    y0 = wave_sum(y0);
    y1 = wave_sum(y1);
    if ((tid & 63) == 0) { r0[tid >> 6] = y0; r1[tid >> 6] = y1; }
    __syncthreads();
    if (tid == 0) {
        float a0 = r0[0] + r0[1] + r0[2] + r0[3];
        float a1 = r1[0] + r1[1] + r1[2] + r1[3];
        out[row] = a0 / (1.f + expf(-a0)) * a1;
    }
}

extern "C" void kernel_launch(void* const* d_in, const int* in_sizes, int n_in,
                              void* d_out, int out_size, void* d_ws, size_t ws_size,
                              hipStream_t stream) {
    const float* x = (const float*)d_in[0];
    const float* cls = (const float*)d_in[1];
    const float* roots = (const float*)d_in[2];
    const float* crw = (const float*)d_in[3];
    const float* ccw = (const float*)d_in[4];
    const float* kv_w = (const float*)d_in[5];
    const float* gamma = (const float*)d_in[6];
    const float* beta = (const float*)d_in[7];
    const float* ffin = (const float*)d_in[8];
    const float* ffout = (const float*)d_in[9];
    const float* ow = (const float*)d_in[10];
    const int* cridx = (const int*)d_in[11];
    const int* ccidx = (const int*)d_in[12];
    float* out = (float*)d_out;

    // Workspace layout with lifetime overlap (~101 MB total):
    //   region A [0 .. 8,388,608): q(4M) kv(2M) kn(1M) v(1M) -- dead after attn
    //   region B [8,388,608 .. 25,165,824): o (16M floats, 64MB) -- live to end
    //   mu/rstd after o
    //   qdet aliases o (only live before attn writes o)
    //   u aliases region A (only live after attn)
    float* ws = (float*)d_ws;
    float* q = ws;                        // 4,194,304 floats
    float* kv = q + 4194304;              // 2,097,152
    float* kn = kv + 2097152;             // 1,048,576
    float* v = kn + 1048576;              // 1,048,576
    float* o = ws + 8388608;              // 16,777,216
    float* mu = o + 16777216;             // 16,384
    float* rstd = mu + 16384;             // 16,384
    float* qdet = o;                      // alias: live only before attn
    float* u = ws;                        // alias region A: 2048*3072 = 6,291,456 floats

    // q = cls
    hipMemcpyAsync(q, cls, 4194304 * sizeof(float), hipMemcpyDeviceToDevice, stream);
    // q += scatter(rmsnorm(roots))
    scatter1<<<4096, 256, 0, stream>>>(roots, crw, cridx, q);
    // q_det snapshot
    hipMemcpyAsync(qdet, q, 4194304 * sizeof(float), hipMemcpyDeviceToDevice, stream);
    // q += scatter(q_det)
    scatter2<<<8192, 256, 0, stream>>>(qdet, ccw, ccidx, q);
    // q = rmsnorm(q)
    rms_rows64<<<16384, 256, 0, stream>>>(q);
    // kv = x @ kv_w^T
    gemm_kv<<<dim3(32, 16), 256, 0, stream>>>(x, kv_w, kv);
    // split + k rmsnorm
    kvsplit<<<4096, 256, 0, stream>>>(kv, kn, v);
    // attention -> o (B,C,1024)
    attn_kernel<<<16384, 256, 0, stream>>>(q, kn, v, o);
    // LN stats
    ln_stats<<<16384, 256, 0, stream>>>(o, mu, rstd);
    // FFN in 8 row-slices of 2048; GEMM2 writes z=o+h in place over o
    for (int sl = 0; sl < 8; ++sl) {
        int R0 = sl * 2048;
        gemm_ffn1<<<dim3(48, 32), 256, 0, stream>>>(o, mu, rstd, gamma, beta, ffin, u, R0);
        gemm_ffn2<<<dim3(16, 32), 256, 0, stream>>>(u, ffout, o, R0);
    }
    // output projection
    out_proj<<<16384, 256, 0, stream>>>(o, ow, out);
}

// Round 3
// 1596.129 us; speedup vs baseline: 4.4098x; 4.4098x over previous
//
#include <hip/hip_runtime.h>
#include <math.h>

#define EPS 1e-5f

typedef __bf16 bf16x8 __attribute__((ext_vector_type(8)));
typedef __bf16 bf16x4 __attribute__((ext_vector_type(4)));
typedef float f32x4 __attribute__((ext_vector_type(4)));

#define GPTR(p) ((const __attribute__((address_space(1))) void*)(p))
#define LPTR(p) ((__attribute__((address_space(3))) void*)(p))

// ---------------- wave/block reduction helpers ----------------
__device__ __forceinline__ float wave_sum(float v) {
#pragma unroll
    for (int o = 32; o; o >>= 1) v += __shfl_xor(v, o);
    return v;
}
__device__ __forceinline__ float wave_max(float v) {
#pragma unroll
    for (int o = 32; o; o >>= 1) v = fmaxf(v, __shfl_xor(v, o));
    return v;
}

// ---------------- scatter 1 ----------------
__global__ __launch_bounds__(256) void scatter1(const float* __restrict__ roots,
                                                const float* __restrict__ w,
                                                const int* __restrict__ idx,
                                                float* __restrict__ q) {
    int unit = (blockIdx.x << 2) + (threadIdx.x >> 6);
    int lane = threadIdx.x & 63;
    int h = unit >> 10;
    int i = unit & 1023;
    int r = idx[i];
    int c = idx[1024 + i];
    float val = roots[(h * 256 + r) * 64 + lane];
    float ss = wave_sum(val * val);
    float rs = rsqrtf(ss * (1.f / 64.f) + EPS);
    atomicAdd(&q[(h * 4096 + c) * 64 + lane], val * rs * w[(h << 10) + i]);
}

// ---------------- scatter 2 ----------------
__global__ __launch_bounds__(256) void scatter2(const float* __restrict__ qdet,
                                                const float* __restrict__ w,
                                                const int* __restrict__ idx,
                                                float* __restrict__ q) {
    int unit = (blockIdx.x << 2) + (threadIdx.x >> 6);
    int lane = threadIdx.x & 63;
    int h = unit >> 11;
    int i = unit & 2047;
    int c1 = idx[i];
    int c2 = idx[2048 + i];
    float val = qdet[(h * 4096 + c1) * 64 + lane] * w[(h << 11) + i];
    atomicAdd(&q[(h * 4096 + c2) * 64 + lane], val);
}

// ---------------- rmsnorm rows of length 64 ----------------
__global__ __launch_bounds__(256) void rms_rows64(float* __restrict__ q) {
    int unit = (blockIdx.x << 2) + (threadIdx.x >> 6);
    int lane = threadIdx.x & 63;
    float v = q[unit * 64 + lane];
    float ss = wave_sum(v * v);
    q[unit * 64 + lane] = v * rsqrtf(ss * (1.f / 64.f) + EPS);
}

// ---------------- GEMM: kv = x @ kv_w^T (fp32) ----------------
__global__ __launch_bounds__(256) void gemm_kv(const float* __restrict__ A,
                                               const float* __restrict__ Bw,
                                               float* __restrict__ Cout) {
    const int K = 1024, N = 2048;
    __shared__ float As[16][65];
    __shared__ float Bs[16][65];
    int tid = threadIdx.x;
    int tx = tid & 15, ty = tid >> 4;
    int bm = blockIdx.y, bn = blockIdx.x;
    float acc[4][4] = {};
    for (int k0 = 0; k0 < K; k0 += 16) {
#pragma unroll
        for (int mm = 0; mm < 4; ++mm) {
            int m = (tid >> 4) + mm * 16;
            int kk = tid & 15;
            As[kk][m] = A[(bm * 64 + m) * K + k0 + kk];
            Bs[kk][m] = Bw[(bn * 64 + m) * K + k0 + kk];
        }
        __syncthreads();
#pragma unroll
        for (int kk = 0; kk < 16; ++kk) {
            float a[4], b[4];
#pragma unroll
            for (int i = 0; i < 4; i++) a[i] = As[kk][ty * 4 + i];
#pragma unroll
            for (int j = 0; j < 4; j++) b[j] = Bs[kk][tx * 4 + j];
#pragma unroll
            for (int i = 0; i < 4; i++)
#pragma unroll
                for (int j = 0; j < 4; j++) acc[i][j] += a[i] * b[j];
        }
        __syncthreads();
    }
#pragma unroll
    for (int i = 0; i < 4; i++)
#pragma unroll
        for (int j = 0; j < 4; j++)
            Cout[(bm * 64 + ty * 4 + i) * N + bn * 64 + tx * 4 + j] = acc[i][j];
}

// ---------------- kv split ----------------
__global__ __launch_bounds__(256) void kvsplit(const float* __restrict__ kv,
                                               float* __restrict__ kn,
                                               float* __restrict__ vout) {
    int unit = (blockIdx.x << 2) + (threadIdx.x >> 6);
    int lane = threadIdx.x & 63;
    int b = unit >> 12;
    int h = (unit >> 8) & 15;
    int s = unit & 255;
    int row = b * 256 + s;
    float kvl = kv[row * 2048 + (h << 6) + lane];
    float vvl = kv[row * 2048 + 1024 + (h << 6) + lane];
    float ss = wave_sum(kvl * kvl);
    float rs = rsqrtf(ss * (1.f / 64.f) + EPS);
    kn[unit * 64 + lane] = kvl * rs;
    vout[unit * 64 + lane] = vvl;
}

// ---------------- attention (fp32 compute, bf16 output) ----------------
__global__ __launch_bounds__(256) void attn_kernel(const float* __restrict__ qn,
                                                   const float* __restrict__ kn,
                                                   const float* __restrict__ vv,
                                                   __bf16* __restrict__ ob) {
    __shared__ float qL[16][64];
    __shared__ float p[256];
    __shared__ float part[4][64];
    __shared__ float redm[4];
    __shared__ float reds[4];
    int bid = blockIdx.x;
    int bh = bid >> 8;
    int cc = bid & 255;
    int b = bh >> 4, h = bh & 15;
    int tid = threadIdx.x;
    int c0 = cc << 4;
    for (int e = tid; e < 1024; e += 256)
        qL[e >> 6][e & 63] = qn[h * 262144 + (c0 << 6) + e];
    const float4* k4 = (const float4*)(kn + bh * 16384);
    float4 kreg[16];
#pragma unroll
    for (int i = 0; i < 16; i++) kreg[i] = k4[tid * 16 + i];
    int sg = tid >> 6, d = tid & 63;
    const float* vp = vv + bh * 16384 + (sg << 6) * 64 + d;
    float vreg[64];
#pragma unroll
    for (int si = 0; si < 64; si++) vreg[si] = vp[si * 64];
    __syncthreads();

    for (int ci = 0; ci < 16; ++ci) {
        float sc = 0.f;
#pragma unroll
        for (int i = 0; i < 16; i++) {
            float4 kkv = kreg[i];
            sc += qL[ci][4 * i + 0] * kkv.x + qL[ci][4 * i + 1] * kkv.y +
                  qL[ci][4 * i + 2] * kkv.z + qL[ci][4 * i + 3] * kkv.w;
        }
        sc *= 0.125f;
        float m = wave_max(sc);
        if ((tid & 63) == 0) redm[tid >> 6] = m;
        __syncthreads();
        m = fmaxf(fmaxf(redm[0], redm[1]), fmaxf(redm[2], redm[3]));
        float ev = expf(sc - m);
        p[tid] = ev;
        float ssum = wave_sum(ev);
        if ((tid & 63) == 0) reds[tid >> 6] = ssum;
        __syncthreads();
        float denom = reds[0] + reds[1] + reds[2] + reds[3];
        float acc = 0.f;
#pragma unroll
        for (int si = 0; si < 64; si++) acc += p[(sg << 6) + si] * vreg[si];
        part[sg][d] = acc;
        __syncthreads();
        if (tid < 64) {
            float ov = (part[0][tid] + part[1][tid] + part[2][tid] + part[3][tid]) / denom;
            ob[((size_t)((b << 12) + c0 + ci)) * 1024 + (h << 6) + tid] = (__bf16)ov;
        }
        __syncthreads();
    }
}

// ---------------- fp32 -> bf16 conversion (8 elems/thread) ----------------
__global__ __launch_bounds__(256) void cvt_bf16(const float* __restrict__ in,
                                                __bf16* __restrict__ out, int n8) {
    int i = blockIdx.x * 256 + threadIdx.x;
    if (i >= n8) return;
    const float4* p = (const float4*)in + (size_t)i * 2;
    float4 u0 = p[0], u1 = p[1];
    bf16x8 v;
    v[0] = (__bf16)u0.x; v[1] = (__bf16)u0.y; v[2] = (__bf16)u0.z; v[3] = (__bf16)u0.w;
    v[4] = (__bf16)u1.x; v[5] = (__bf16)u1.y; v[6] = (__bf16)u1.z; v[7] = (__bf16)u1.w;
    *((bf16x8*)out + i) = v;
}

// ---------------- LayerNorm stats (bf16 input) ----------------
__global__ __launch_bounds__(256) void ln_stats(const __bf16* __restrict__ ob,
                                                float* __restrict__ mu,
                                                float* __restrict__ rstd) {
    __shared__ float r0[4], r1[4];
    int row = blockIdx.x;
    int tid = threadIdx.x;
    const bf16x4* op = (const bf16x4*)(ob + (size_t)row * 1024);
    bf16x4 v = op[tid];
    float s = 0, sq = 0;
#pragma unroll
    for (int j = 0; j < 4; ++j) { float f = (float)v[j]; s += f; sq += f * f; }
    s = wave_sum(s);
    sq = wave_sum(sq);
    if ((tid & 63) == 0) { r0[tid >> 6] = s; r1[tid >> 6] = sq; }
    __syncthreads();
    if (tid == 0) {
        float S = r0[0] + r0[1] + r0[2] + r0[3];
        float Q = r1[0] + r1[1] + r1[2] + r1[3];
        float m = S * (1.f / 1024.f);
        float var = Q * (1.f / 1024.f) - m * m;
        mu[row] = m;
        rstd[row] = rsqrtf(var + EPS);
    }
}

// ---------------- LN apply -> bf16 f (slice-local), 8 elems/thread ----------------
__global__ __launch_bounds__(256) void ln_apply(const __bf16* __restrict__ ob,
                                                const float* __restrict__ mu,
                                                const float* __restrict__ rstd,
                                                const float* __restrict__ gamma,
                                                const float* __restrict__ beta,
                                                __bf16* __restrict__ f, int R0) {
    int i = blockIdx.x * 256 + threadIdx.x;  // [0, 524288)
    int row = i >> 7;
    int c8 = (i & 127) * 8;
    int gr = R0 + row;
    float m = mu[gr], rs = rstd[gr];
    bf16x8 ov = *((const bf16x8*)(ob + (size_t)gr * 1024 + c8));
    bf16x8 r;
#pragma unroll
    for (int j = 0; j < 8; ++j) {
        float v = (float)ov[j];
        r[j] = (__bf16)((v - m) * rs * gamma[c8 + j] + beta[c8 + j]);
    }
    *((bf16x8*)(f + (size_t)row * 1024 + c8)) = r;
}

// ---------------- MFMA GEMM1: u = silu(f@W1a^T) * (f@W1b^T), bf16 ----------------
// f: [4096][1024] bf16 (slice), W: [6144][1024] bf16, U: [4096][3072] bf16
__global__ __launch_bounds__(256) void gemm1_mfma(const __bf16* __restrict__ A,
                                                  const __bf16* __restrict__ W,
                                                  __bf16* __restrict__ U) {
    __shared__ __bf16 sA[128 * 64];
    __shared__ __bf16 sB1[128 * 64];
    __shared__ __bf16 sB2[128 * 64];
    const int K = 1024;
    int tid = threadIdx.x;
    int bn = blockIdx.x, bm = blockIdx.y;
    int lane = tid & 63;
    int w = tid >> 6;
    int wr = (w >> 1) * 64, wc = (w & 1) * 64;
    f32x4 acc1[4][4] = {};
    f32x4 acc2[4][4] = {};
    const __bf16* Ab = A + (size_t)(bm * 128) * K;
    const __bf16* B1b = W + (size_t)(bn * 128) * K;
    const __bf16* B2b = W + (size_t)(3072 + bn * 128) * K;
    int frow = lane & 15, fk = (lane >> 4) * 8;
    for (int k0 = 0; k0 < K; k0 += 64) {
#pragma unroll
        for (int t = 0; t < 4; ++t) {
            int e = (t * 256 + tid) * 8;
            int r = e >> 6, c = e & 63;
            __builtin_amdgcn_global_load_lds(GPTR(Ab + (size_t)r * K + k0 + c), LPTR(sA + e), 16, 0, 0);
            __builtin_amdgcn_global_load_lds(GPTR(B1b + (size_t)r * K + k0 + c), LPTR(sB1 + e), 16, 0, 0);
            __builtin_amdgcn_global_load_lds(GPTR(B2b + (size_t)r * K + k0 + c), LPTR(sB2 + e), 16, 0, 0);
        }
        __syncthreads();
#pragma unroll
        for (int ks = 0; ks < 2; ++ks) {
            bf16x8 a[4], b1[4], b2[4];
#pragma unroll
            for (int m = 0; m < 4; ++m)
                a[m] = *(const bf16x8*)(sA + (wr + m * 16 + frow) * 64 + ks * 32 + fk);
#pragma unroll
            for (int n = 0; n < 4; ++n) {
                b1[n] = *(const bf16x8*)(sB1 + (wc + n * 16 + frow) * 64 + ks * 32 + fk);
                b2[n] = *(const bf16x8*)(sB2 + (wc + n * 16 + frow) * 64 + ks * 32 + fk);
            }
#pragma unroll
            for (int m = 0; m < 4; ++m)
#pragma unroll
                for (int n = 0; n < 4; ++n) {
                    acc1[m][n] = __builtin_amdgcn_mfma_f32_16x16x32_bf16(a[m], b1[n], acc1[m][n], 0, 0, 0);
                    acc2[m][n] = __builtin_amdgcn_mfma_f32_16x16x32_bf16(a[m], b2[n], acc2[m][n], 0, 0, 0);
                }
        }
        __syncthreads();
    }
    int crow = (lane >> 4) * 4, ccol = lane & 15;
#pragma unroll
    for (int m = 0; m < 4; ++m)
#pragma unroll
        for (int n = 0; n < 4; ++n)
#pragma unroll
            for (int j = 0; j < 4; ++j) {
                float f1 = acc1[m][n][j], f2 = acc2[m][n][j];
                float sg = f1 / (1.f + expf(-f1));
                int row = bm * 128 + wr + m * 16 + crow + j;
                int col = bn * 128 + wc + n * 16 + ccol;
                U[(size_t)row * 3072 + col] = (__bf16)(sg * f2);
            }
}

// ---------------- MFMA GEMM2: z = o + u@W2^T (in place over o_bf) ----------------
// U: [4096][3072] bf16, W2: [1024][3072] bf16, Oz: rows pre-offset, [.][1024] bf16
__global__ __launch_bounds__(256) void gemm2_mfma(const __bf16* __restrict__ U,
                                                  const __bf16* __restrict__ W2,
                                                  __bf16* __restrict__ Oz) {
    __shared__ __bf16 sA[128 * 64];
    __shared__ __bf16 sB[128 * 64];
    const int K = 3072;
    int tid = threadIdx.x;
    int bn = blockIdx.x, bm = blockIdx.y;
    int lane = tid & 63;
    int w = tid >> 6;
    int wr = (w >> 1) * 64, wc = (w & 1) * 64;
    f32x4 acc[4][4] = {};
    const __bf16* Ab = U + (size_t)(bm * 128) * K;
    const __bf16* Bb = W2 + (size_t)(bn * 128) * K;
    int frow = lane & 15, fk = (lane >> 4) * 8;
    for (int k0 = 0; k0 < K; k0 += 64) {
#pragma unroll
        for (int t = 0; t < 4; ++t) {
            int e = (t * 256 + tid) * 8;
            int r = e >> 6, c = e & 63;
            __builtin_amdgcn_global_load_lds(GPTR(Ab + (size_t)r * K + k0 + c), LPTR(sA + e), 16, 0, 0);
            __builtin_amdgcn_global_load_lds(GPTR(Bb + (size_t)r * K + k0 + c), LPTR(sB + e), 16, 0, 0);
        }
        __syncthreads();
#pragma unroll
        for (int ks = 0; ks < 2; ++ks) {
            bf16x8 a[4], b[4];
#pragma unroll
            for (int m = 0; m < 4; ++m)
                a[m] = *(const bf16x8*)(sA + (wr + m * 16 + frow) * 64 + ks * 32 + fk);
#pragma unroll
            for (int n = 0; n < 4; ++n)
                b[n] = *(const bf16x8*)(sB + (wc + n * 16 + frow) * 64 + ks * 32 + fk);
#pragma unroll
            for (int m = 0; m < 4; ++m)
#pragma unroll
                for (int n = 0; n < 4; ++n)
                    acc[m][n] = __builtin_amdgcn_mfma_f32_16x16x32_bf16(a[m], b[n], acc[m][n], 0, 0, 0);
        }
        __syncthreads();
    }
    int crow = (lane >> 4) * 4, ccol = lane & 15;
#pragma unroll
    for (int m = 0; m < 4; ++m)
#pragma unroll
        for (int n = 0; n < 4; ++n)
#pragma unroll
            for (int j = 0; j < 4; ++j) {
                int row = bm * 128 + wr + m * 16 + crow + j;
                int col = bn * 128 + wc + n * 16 + ccol;
                size_t off = (size_t)row * 1024 + col;
                float z = (float)Oz[off] + acc[m][n][j];
                Oz[off] = (__bf16)z;
            }
}

// ---------------- final projection (z bf16) ----------------
__global__ __launch_bounds__(256) void out_proj(const __bf16* __restrict__ z,
                                                const float* __restrict__ ow,
                                                float* __restrict__ out) {
    __shared__ float r0[4], r1[4];
    int row = blockIdx.x;
    int c = row & 4095;
    int tid = threadIdx.x;
    const float2* w2 = (const float2*)ow + (size_t)c * 1024;
    float y0 = 0, y1 = 0;
    for (int a = tid; a < 1024; a += 256) {
        float zv = (float)z[(size_t)row * 1024 + a];
        float2 w = w2[a];
        y0 += zv * w.x;
        y1 += zv * w.y;
    }
    y0 = wave_sum(y0);
    y1 = wave_sum(y1);
    if ((tid & 63) == 0) { r0[tid >> 6] = y0; r1[tid >> 6] = y1; }
    __syncthreads();
    if (tid == 0) {
        float a0 = r0[0] + r0[1] + r0[2] + r0[3];
        float a1 = r1[0] + r1[1] + r1[2] + r1[3];
        out[row] = a0 / (1.f + expf(-a0)) * a1;
    }
}

extern "C" void kernel_launch(void* const* d_in, const int* in_sizes, int n_in,
                              void* d_out, int out_size, void* d_ws, size_t ws_size,
                              hipStream_t stream) {
    const float* x = (const float*)d_in[0];
    const float* cls = (const float*)d_in[1];
    const float* roots = (const float*)d_in[2];
    const float* crw = (const float*)d_in[3];
    const float* ccw = (const float*)d_in[4];
    const float* kv_w = (const float*)d_in[5];
    const float* gamma = (const float*)d_in[6];
    const float* beta = (const float*)d_in[7];
    const float* ffin = (const float*)d_in[8];
    const float* ffout = (const float*)d_in[9];
    const float* ow = (const float*)d_in[10];
    const int* cridx = (const int*)d_in[11];
    const int* ccidx = (const int*)d_in[12];
    float* out = (float*)d_out;

    // Workspace (floats): total 25,165,824 fl = 100.66 MB
    //  Region A [0 .. 8,388,608): phase1 q|kv|kn|v ; phase2 w1bf|w2bf|mu|rstd
    //  Region B [8,388,608 .. 16,777,216): o_bf (16,777,216 bf16) -- z in place later
    //  Region D [16,777,216 .. 25,165,824): qdet (early) ; later fbf_s|u_s per slice
    float* ws = (float*)d_ws;
    float* q = ws;                          // 4,194,304 fl
    float* kv = q + 4194304;                // 2,097,152 fl
    float* kn = kv + 2097152;               // 1,048,576 fl
    float* v = kn + 1048576;                // 1,048,576 fl
    __bf16* o_bf = (__bf16*)(ws + 8388608); // 16,777,216 bf16
    float* qdet = ws + 16777216;            // 4,194,304 fl (early only)
    __bf16* w1bf = (__bf16*)ws;             // 6,291,456 bf16 = 3,145,728 fl
    __bf16* w2bf = (__bf16*)(ws + 3145728); // 3,145,728 bf16 = 1,572,864 fl
    float* mu = ws + 4718592;               // 16,384 fl
    float* rstd = mu + 16384;               // 16,384 fl
    __bf16* fbf = (__bf16*)(ws + 16777216); // 4,194,304 bf16 (slice 4096x1024)
    __bf16* u_s = (__bf16*)(ws + 18874368); // 12,582,912 bf16 (slice 4096x3072)

    // q = cls
    hipMemcpyAsync(q, cls, 4194304 * sizeof(float), hipMemcpyDeviceToDevice, stream);
    scatter1<<<4096, 256, 0, stream>>>(roots, crw, cridx, q);
    hipMemcpyAsync(qdet, q, 4194304 * sizeof(float), hipMemcpyDeviceToDevice, stream);
    scatter2<<<8192, 256, 0, stream>>>(qdet, ccw, ccidx, q);
    rms_rows64<<<16384, 256, 0, stream>>>(q);
    gemm_kv<<<dim3(32, 16), 256, 0, stream>>>(x, kv_w, kv);
    kvsplit<<<4096, 256, 0, stream>>>(kv, kn, v);
    attn_kernel<<<16384, 256, 0, stream>>>(q, kn, v, o_bf);

    // region A free now: convert FFN weights to bf16
    cvt_bf16<<<3072, 256, 0, stream>>>(ffin, w1bf, 786432);   // 6144*1024/8
    cvt_bf16<<<1536, 256, 0, stream>>>(ffout, w2bf, 393216);  // 1024*3072/8
    ln_stats<<<16384, 256, 0, stream>>>(o_bf, mu, rstd);

    // FFN: 4 row-slices of 4096
    for (int sl = 0; sl < 4; ++sl) {
        int R0 = sl * 4096;
        ln_apply<<<2048, 256, 0, stream>>>(o_bf, mu, rstd, gamma, beta, fbf, R0);
        gemm1_mfma<<<dim3(24, 32), 256, 0, stream>>>(fbf, w1bf, u_s);
        gemm2_mfma<<<dim3(8, 32), 256, 0, stream>>>(u_s, w2bf, o_bf + (size_t)R0 * 1024);
    }
    out_proj<<<16384, 256, 0, stream>>>(o_bf, ow, out);
}

// Round 4
// 1114.034 us; speedup vs baseline: 6.3181x; 1.4327x over previous
//
#include <hip/hip_runtime.h>
#include <math.h>

#define EPS 1e-5f

typedef __bf16 bf16x8 __attribute__((ext_vector_type(8)));
typedef __bf16 bf16x4 __attribute__((ext_vector_type(4)));
typedef float f32x4 __attribute__((ext_vector_type(4)));

#define GPTR(p) ((const __attribute__((address_space(1))) void*)(p))
#define LPTR(p) ((__attribute__((address_space(3))) void*)(p))

// ---------------- wave reduction helpers ----------------
__device__ __forceinline__ float wave_sum(float v) {
#pragma unroll
    for (int o = 32; o; o >>= 1) v += __shfl_xor(v, o);
    return v;
}

// ---------------- scatter 1 ----------------
__global__ __launch_bounds__(256) void scatter1(const float* __restrict__ roots,
                                                const float* __restrict__ w,
                                                const int* __restrict__ idx,
                                                float* __restrict__ q) {
    int unit = (blockIdx.x << 2) + (threadIdx.x >> 6);
    int lane = threadIdx.x & 63;
    int h = unit >> 10;
    int i = unit & 1023;
    int r = idx[i];
    int c = idx[1024 + i];
    float val = roots[(h * 256 + r) * 64 + lane];
    float ss = wave_sum(val * val);
    float rs = rsqrtf(ss * (1.f / 64.f) + EPS);
    atomicAdd(&q[(h * 4096 + c) * 64 + lane], val * rs * w[(h << 10) + i]);
}

// ---------------- scatter 2 ----------------
__global__ __launch_bounds__(256) void scatter2(const float* __restrict__ qdet,
                                                const float* __restrict__ w,
                                                const int* __restrict__ idx,
                                                float* __restrict__ q) {
    int unit = (blockIdx.x << 2) + (threadIdx.x >> 6);
    int lane = threadIdx.x & 63;
    int h = unit >> 11;
    int i = unit & 2047;
    int c1 = idx[i];
    int c2 = idx[2048 + i];
    float val = qdet[(h * 4096 + c1) * 64 + lane] * w[(h << 11) + i];
    atomicAdd(&q[(h * 4096 + c2) * 64 + lane], val);
}

// ---------------- rmsnorm rows of 64 -> hi/lo bf16 ----------------
__global__ __launch_bounds__(256) void rms_q_hilo(const float* __restrict__ q,
                                                  __bf16* __restrict__ qhi,
                                                  __bf16* __restrict__ qlo) {
    int unit = (blockIdx.x << 2) + (threadIdx.x >> 6);
    int lane = threadIdx.x & 63;
    float v = q[(size_t)unit * 64 + lane];
    float ss = wave_sum(v * v);
    float r = v * rsqrtf(ss * (1.f / 64.f) + EPS);
    __bf16 hv = (__bf16)r;
    qhi[(size_t)unit * 64 + lane] = hv;
    qlo[(size_t)unit * 64 + lane] = (__bf16)(r - (float)hv);
}

// ---------------- split fp32 -> hi/lo bf16 (8/thread) ----------------
__global__ __launch_bounds__(256) void split8(const float* __restrict__ in,
                                              __bf16* __restrict__ hi,
                                              __bf16* __restrict__ lo, int n8) {
    int i = blockIdx.x * 256 + threadIdx.x;
    if (i >= n8) return;
    const float4* p = (const float4*)in + (size_t)i * 2;
    float4 u0 = p[0], u1 = p[1];
    float f[8] = {u0.x, u0.y, u0.z, u0.w, u1.x, u1.y, u1.z, u1.w};
    bf16x8 vh, vl;
#pragma unroll
    for (int j = 0; j < 8; ++j) {
        vh[j] = (__bf16)f[j];
        vl[j] = (__bf16)(f[j] - (float)vh[j]);
    }
    *((bf16x8*)hi + i) = vh;
    *((bf16x8*)lo + i) = vl;
}

// ---------------- MFMA GEMM: kv = x @ kv_w^T, hi/lo 3-term, fp32 out ----------------
// BM=64, BN=128, BK=64; grid (16,16)
__global__ __launch_bounds__(256) void gemm_kv_mfma(const __bf16* __restrict__ Ah,
                                                    const __bf16* __restrict__ Al,
                                                    const __bf16* __restrict__ Bh,
                                                    const __bf16* __restrict__ Bl,
                                                    float* __restrict__ Cout) {
    __shared__ __bf16 sAh[64 * 64], sAl[64 * 64];
    __shared__ __bf16 sBh[128 * 64], sBl[128 * 64];
    int tid = threadIdx.x;
    int bn = blockIdx.x, bm = blockIdx.y;
    int lane = tid & 63;
    int w = tid >> 6;
    int wr = (w >> 1) * 32, wc = (w & 1) * 64;
    int frow = lane & 15, fk = (lane >> 4) * 8;
    f32x4 acc[2][4] = {};
    const __bf16* Ahb = Ah + (size_t)(bm * 64) * 1024;
    const __bf16* Alb = Al + (size_t)(bm * 64) * 1024;
    const __bf16* Bhb = Bh + (size_t)(bn * 128) * 1024;
    const __bf16* Blb = Bl + (size_t)(bn * 128) * 1024;
    for (int k0 = 0; k0 < 1024; k0 += 64) {
#pragma unroll
        for (int t = 0; t < 2; ++t) {
            int e = (t * 256 + tid) * 8;
            int r = e >> 6, c = e & 63;
            __builtin_amdgcn_global_load_lds(GPTR(Ahb + (size_t)r * 1024 + k0 + c), LPTR(sAh + e), 16, 0, 0);
            __builtin_amdgcn_global_load_lds(GPTR(Alb + (size_t)r * 1024 + k0 + c), LPTR(sAl + e), 16, 0, 0);
        }
#pragma unroll
        for (int t = 0; t < 4; ++t) {
            int e = (t * 256 + tid) * 8;
            int r = e >> 6, c = e & 63;
            __builtin_amdgcn_global_load_lds(GPTR(Bhb + (size_t)r * 1024 + k0 + c), LPTR(sBh + e), 16, 0, 0);
            __builtin_amdgcn_global_load_lds(GPTR(Blb + (size_t)r * 1024 + k0 + c), LPTR(sBl + e), 16, 0, 0);
        }
        __syncthreads();
#pragma unroll
        for (int ks = 0; ks < 2; ++ks) {
            bf16x8 ah[2], al[2], bh2[4], bl2[4];
#pragma unroll
            for (int m = 0; m < 2; ++m) {
                ah[m] = *(const bf16x8*)(sAh + (wr + m * 16 + frow) * 64 + ks * 32 + fk);
                al[m] = *(const bf16x8*)(sAl + (wr + m * 16 + frow) * 64 + ks * 32 + fk);
            }
#pragma unroll
            for (int n = 0; n < 4; ++n) {
                bh2[n] = *(const bf16x8*)(sBh + (wc + n * 16 + frow) * 64 + ks * 32 + fk);
                bl2[n] = *(const bf16x8*)(sBl + (wc + n * 16 + frow) * 64 + ks * 32 + fk);
            }
#pragma unroll
            for (int m = 0; m < 2; ++m)
#pragma unroll
                for (int n = 0; n < 4; ++n) {
                    acc[m][n] = __builtin_amdgcn_mfma_f32_16x16x32_bf16(ah[m], bh2[n], acc[m][n], 0, 0, 0);
                    acc[m][n] = __builtin_amdgcn_mfma_f32_16x16x32_bf16(ah[m], bl2[n], acc[m][n], 0, 0, 0);
                    acc[m][n] = __builtin_amdgcn_mfma_f32_16x16x32_bf16(al[m], bh2[n], acc[m][n], 0, 0, 0);
                }
        }
        __syncthreads();
    }
    int crow = (lane >> 4) * 4, ccol = lane & 15;
#pragma unroll
    for (int m = 0; m < 2; ++m)
#pragma unroll
        for (int n = 0; n < 4; ++n)
#pragma unroll
            for (int j = 0; j < 4; ++j) {
                int row = bm * 64 + wr + m * 16 + crow + j;
                int col = bn * 128 + wc + n * 16 + ccol;
                Cout[(size_t)row * 2048 + col] = acc[m][n][j];
            }
}

// ---------------- kv split: K rmsnorm -> hi/lo bf16 [bh][s][64] ----------------
__global__ __launch_bounds__(256) void kvsplit_hilo(const float* __restrict__ kv,
                                                    __bf16* __restrict__ khi,
                                                    __bf16* __restrict__ klo) {
    int unit = (blockIdx.x << 2) + (threadIdx.x >> 6);  // bh*256+s
    int lane = threadIdx.x & 63;
    int b = unit >> 12;
    int h = (unit >> 8) & 15;
    int s = unit & 255;
    float kvl = kv[(size_t)(b * 256 + s) * 2048 + (h << 6) + lane];
    float ss = wave_sum(kvl * kvl);
    float kn = kvl * rsqrtf(ss * (1.f / 64.f) + EPS);
    __bf16 hv = (__bf16)kn;
    khi[(size_t)unit * 64 + lane] = hv;
    klo[(size_t)unit * 64 + lane] = (__bf16)(kn - (float)hv);
}

// ---------------- V transpose: kv -> vt hi/lo [bh][d=64][s=256] ----------------
__global__ __launch_bounds__(256) void vtrans(const float* __restrict__ kv,
                                              __bf16* __restrict__ vthi,
                                              __bf16* __restrict__ vtlo) {
    __shared__ float T[64][65];
    int bh = blockIdx.x >> 2;
    int sc = blockIdx.x & 3;
    int b = bh >> 4, h = bh & 15;
    int tid = threadIdx.x;
    int s0 = sc * 64;
    int sl = tid >> 2, d0 = (tid & 3) * 16;
    const float* src = kv + (size_t)(b * 256 + s0 + sl) * 2048 + 1024 + (h << 6) + d0;
#pragma unroll
    for (int t = 0; t < 4; ++t) {
        float4 v4 = *(const float4*)(src + t * 4);
        T[sl][d0 + t * 4 + 0] = v4.x;
        T[sl][d0 + t * 4 + 1] = v4.y;
        T[sl][d0 + t * 4 + 2] = v4.z;
        T[sl][d0 + t * 4 + 3] = v4.w;
    }
    __syncthreads();
    int dr = tid >> 2, c0 = (tid & 3) * 16;
    bf16x8 h0, h1, l0, l1;
#pragma unroll
    for (int jj = 0; jj < 8; ++jj) {
        float f = T[c0 + jj][dr];
        h0[jj] = (__bf16)f;
        l0[jj] = (__bf16)(f - (float)h0[jj]);
    }
#pragma unroll
    for (int jj = 0; jj < 8; ++jj) {
        float f = T[c0 + 8 + jj][dr];
        h1[jj] = (__bf16)f;
        l1[jj] = (__bf16)(f - (float)h1[jj]);
    }
    size_t base = (size_t)bh * 16384 + (size_t)dr * 256 + s0 + c0;
    *(bf16x8*)(vthi + base) = h0;
    *(bf16x8*)(vthi + base + 8) = h1;
    *(bf16x8*)(vtlo + base) = l0;
    *(bf16x8*)(vtlo + base + 8) = l1;
}

// ---------------- MFMA attention ----------------
// block: one (b,h) x 64-query tile; 4 waves.
// QK^T: scoresT[s][q] = mfma(K, Q); wave w owns s in [w*64, w*64+64).
// PV:   OT[d][q] = mfma(VT, P); wave w owns q in [w*16, w*16+16).
__global__ __launch_bounds__(256) void attn_mfma(const __bf16* __restrict__ qhi,
                                                 const __bf16* __restrict__ qlo,
                                                 const __bf16* __restrict__ khi,
                                                 const __bf16* __restrict__ klo,
                                                 const __bf16* __restrict__ vthi,
                                                 const __bf16* __restrict__ vtlo,
                                                 __bf16* __restrict__ ob) {
    __shared__ __bf16 Phi[64 * 264];
    __shared__ __bf16 Plo[64 * 264];
    __shared__ float wred[8][64];  // rows 0-3: wave max; 4-7: wave sum
    __shared__ float denomL[64];
    __shared__ __bf16 Ot[64 * 72];

    int wg = blockIdx.x;
    int swz = (wg & 7) * 512 + (wg >> 3);  // XCD-chunked: each XCD gets 8 contiguous bh
    int bh = swz >> 6;
    int qt = swz & 63;
    int b = bh >> 4, h = bh & 15;
    int tid = threadIdx.x;
    int lane = tid & 63;
    int w = tid >> 6;
    int frow = lane & 15;
    int fk = (lane >> 4) * 8;
    int crow = (lane >> 4) * 4;
    int ccol = lane & 15;
    int q0 = qt * 64;
    int ws = w * 64;

    const __bf16* kh = khi + (size_t)bh * 16384;
    const __bf16* kl = klo + (size_t)bh * 16384;
    const __bf16* qh = qhi + (size_t)h * 262144 + (size_t)q0 * 64;
    const __bf16* ql = qlo + (size_t)h * 262144 + (size_t)q0 * 64;

    f32x4 acc[4][4] = {};  // [m=s-frag][n=q-frag]
#pragma unroll
    for (int ks = 0; ks < 2; ++ks) {
        bf16x8 kfh[4], kfl[4];
#pragma unroll
        for (int m = 0; m < 4; ++m) {
            int off = (ws + m * 16 + frow) * 64 + ks * 32 + fk;
            kfh[m] = *(const bf16x8*)(kh + off);
            kfl[m] = *(const bf16x8*)(kl + off);
        }
#pragma unroll
        for (int n = 0; n < 4; ++n) {
            int off = (n * 16 + frow) * 64 + ks * 32 + fk;
            bf16x8 qfh = *(const bf16x8*)(qh + off);
            bf16x8 qfl = *(const bf16x8*)(ql + off);
#pragma unroll
            for (int m = 0; m < 4; ++m) {
                acc[m][n] = __builtin_amdgcn_mfma_f32_16x16x32_bf16(kfh[m], qfh, acc[m][n], 0, 0, 0);
                acc[m][n] = __builtin_amdgcn_mfma_f32_16x16x32_bf16(kfh[m], qfl, acc[m][n], 0, 0, 0);
                acc[m][n] = __builtin_amdgcn_mfma_f32_16x16x32_bf16(kfl[m], qfh, acc[m][n], 0, 0, 0);
            }
        }
    }
#pragma unroll
    for (int m = 0; m < 4; ++m)
#pragma unroll
        for (int n = 0; n < 4; ++n)
#pragma unroll
            for (int j = 0; j < 4; ++j) acc[m][n][j] *= 0.125f;

    // wave max per q (over this wave's 64 s)
    float lm[4];
#pragma unroll
    for (int n = 0; n < 4; ++n) {
        float v = -1e30f;
#pragma unroll
        for (int m = 0; m < 4; ++m)
#pragma unroll
            for (int j = 0; j < 4; ++j) v = fmaxf(v, acc[m][n][j]);
        v = fmaxf(v, __shfl_xor(v, 16));
        v = fmaxf(v, __shfl_xor(v, 32));
        lm[n] = v;
    }
    if (lane < 16) {
#pragma unroll
        for (int n = 0; n < 4; ++n) wred[w][n * 16 + lane] = lm[n];
    }
    __syncthreads();
    float gm[4];
#pragma unroll
    for (int n = 0; n < 4; ++n) {
        int qq = n * 16 + ccol;
        gm[n] = fmaxf(fmaxf(wred[0][qq], wred[1][qq]), fmaxf(wred[2][qq], wred[3][qq]));
    }
    float lsum[4] = {0.f, 0.f, 0.f, 0.f};
#pragma unroll
    for (int m = 0; m < 4; ++m)
#pragma unroll
        for (int n = 0; n < 4; ++n)
#pragma unroll
            for (int j = 0; j < 4; ++j) {
                float p = __expf(acc[m][n][j] - gm[n]);
                acc[m][n][j] = p;
                lsum[n] += p;
            }
#pragma unroll
    for (int n = 0; n < 4; ++n) {
        float v = lsum[n];
        v += __shfl_xor(v, 16);
        v += __shfl_xor(v, 32);
        lsum[n] = v;
    }
    if (lane < 16) {
#pragma unroll
        for (int n = 0; n < 4; ++n) wred[4 + w][n * 16 + lane] = lsum[n];
    }
    // write P hi/lo to padded LDS [q][264]
#pragma unroll
    for (int m = 0; m < 4; ++m)
#pragma unroll
        for (int n = 0; n < 4; ++n)
#pragma unroll
            for (int j = 0; j < 4; ++j) {
                int s = ws + m * 16 + crow + j;
                int qq = n * 16 + ccol;
                float p = acc[m][n][j];
                __bf16 ph = (__bf16)p;
                Phi[qq * 264 + s] = ph;
                Plo[qq * 264 + s] = (__bf16)(p - (float)ph);
            }
    __syncthreads();
    if (tid < 64)
        denomL[tid] = wred[4][tid] + wred[5][tid] + wred[6][tid] + wred[7][tid];

    // PV
    const __bf16* vh = vthi + (size_t)bh * 16384;
    const __bf16* vl = vtlo + (size_t)bh * 16384;
    f32x4 accO[4] = {};
#pragma unroll
    for (int ks = 0; ks < 8; ++ks) {
        bf16x8 pf_h = *(const bf16x8*)(Phi + (w * 16 + frow) * 264 + ks * 32 + fk);
        bf16x8 pf_l = *(const bf16x8*)(Plo + (w * 16 + frow) * 264 + ks * 32 + fk);
#pragma unroll
        for (int m = 0; m < 4; ++m) {
            int off = (m * 16 + frow) * 256 + ks * 32 + fk;
            bf16x8 a_h = *(const bf16x8*)(vh + off);
            bf16x8 a_l = *(const bf16x8*)(vl + off);
            accO[m] = __builtin_amdgcn_mfma_f32_16x16x32_bf16(a_h, pf_h, accO[m], 0, 0, 0);
            accO[m] = __builtin_amdgcn_mfma_f32_16x16x32_bf16(a_h, pf_l, accO[m], 0, 0, 0);
            accO[m] = __builtin_amdgcn_mfma_f32_16x16x32_bf16(a_l, pf_h, accO[m], 0, 0, 0);
        }
    }
    __syncthreads();
    float rd = 1.0f / denomL[w * 16 + ccol];
#pragma unroll
    for (int m = 0; m < 4; ++m)
#pragma unroll
        for (int j = 0; j < 4; ++j)
            Ot[(w * 16 + ccol) * 72 + m * 16 + crow + j] = (__bf16)(accO[m][j] * rd);
    __syncthreads();
    {
        int qq = tid >> 2, dc = tid & 3;
        bf16x8 o0 = *(const bf16x8*)(Ot + qq * 72 + dc * 16);
        bf16x8 o1 = *(const bf16x8*)(Ot + qq * 72 + dc * 16 + 8);
        size_t base = (size_t)((b << 12) + q0 + qq) * 1024 + (h << 6) + dc * 16;
        *(bf16x8*)(ob + base) = o0;
        *(bf16x8*)(ob + base + 8) = o1;
    }
}

// ---------------- fp32 -> bf16 conversion ----------------
__global__ __launch_bounds__(256) void cvt_bf16(const float* __restrict__ in,
                                                __bf16* __restrict__ out, int n8) {
    int i = blockIdx.x * 256 + threadIdx.x;
    if (i >= n8) return;
    const float4* p = (const float4*)in + (size_t)i * 2;
    float4 u0 = p[0], u1 = p[1];
    bf16x8 v;
    v[0] = (__bf16)u0.x; v[1] = (__bf16)u0.y; v[2] = (__bf16)u0.z; v[3] = (__bf16)u0.w;
    v[4] = (__bf16)u1.x; v[5] = (__bf16)u1.y; v[6] = (__bf16)u1.z; v[7] = (__bf16)u1.w;
    *((bf16x8*)out + i) = v;
}

// ---------------- LayerNorm stats (bf16 input) ----------------
__global__ __launch_bounds__(256) void ln_stats(const __bf16* __restrict__ ob,
                                                float* __restrict__ mu,
                                                float* __restrict__ rstd) {
    __shared__ float r0[4], r1[4];
    int row = blockIdx.x;
    int tid = threadIdx.x;
    const bf16x4* op = (const bf16x4*)(ob + (size_t)row * 1024);
    bf16x4 v = op[tid];
    float s = 0, sq = 0;
#pragma unroll
    for (int j = 0; j < 4; ++j) { float f = (float)v[j]; s += f; sq += f * f; }
    s = wave_sum(s);
    sq = wave_sum(sq);
    if ((tid & 63) == 0) { r0[tid >> 6] = s; r1[tid >> 6] = sq; }
    __syncthreads();
    if (tid == 0) {
        float S = r0[0] + r0[1] + r0[2] + r0[3];
        float Q = r1[0] + r1[1] + r1[2] + r1[3];
        float m = S * (1.f / 1024.f);
        float var = Q * (1.f / 1024.f) - m * m;
        mu[row] = m;
        rstd[row] = rsqrtf(var + EPS);
    }
}

// ---------------- LN apply -> bf16 f (slice-local) ----------------
__global__ __launch_bounds__(256) void ln_apply(const __bf16* __restrict__ ob,
                                                const float* __restrict__ mu,
                                                const float* __restrict__ rstd,
                                                const float* __restrict__ gamma,
                                                const float* __restrict__ beta,
                                                __bf16* __restrict__ f, int R0) {
    int i = blockIdx.x * 256 + threadIdx.x;
    int row = i >> 7;
    int c8 = (i & 127) * 8;
    int gr = R0 + row;
    float m = mu[gr], rs = rstd[gr];
    bf16x8 ov = *((const bf16x8*)(ob + (size_t)gr * 1024 + c8));
    bf16x8 r;
#pragma unroll
    for (int j = 0; j < 8; ++j) {
        float v = (float)ov[j];
        r[j] = (__bf16)((v - m) * rs * gamma[c8 + j] + beta[c8 + j]);
    }
    *((bf16x8*)(f + (size_t)row * 1024 + c8)) = r;
}

// ---------------- MFMA GEMM1: u = silu(f@W1a^T) * (f@W1b^T) ----------------
__global__ __launch_bounds__(256) void gemm1_mfma(const __bf16* __restrict__ A,
                                                  const __bf16* __restrict__ W,
                                                  __bf16* __restrict__ U) {
    __shared__ __bf16 sA[128 * 64];
    __shared__ __bf16 sB1[128 * 64];
    __shared__ __bf16 sB2[128 * 64];
    const int K = 1024;
    int tid = threadIdx.x;
    int bn = blockIdx.x, bm = blockIdx.y;
    int lane = tid & 63;
    int w = tid >> 6;
    int wr = (w >> 1) * 64, wc = (w & 1) * 64;
    f32x4 acc1[4][4] = {};
    f32x4 acc2[4][4] = {};
    const __bf16* Ab = A + (size_t)(bm * 128) * K;
    const __bf16* B1b = W + (size_t)(bn * 128) * K;
    const __bf16* B2b = W + (size_t)(3072 + bn * 128) * K;
    int frow = lane & 15, fk = (lane >> 4) * 8;
    for (int k0 = 0; k0 < K; k0 += 64) {
#pragma unroll
        for (int t = 0; t < 4; ++t) {
            int e = (t * 256 + tid) * 8;
            int r = e >> 6, c = e & 63;
            __builtin_amdgcn_global_load_lds(GPTR(Ab + (size_t)r * K + k0 + c), LPTR(sA + e), 16, 0, 0);
            __builtin_amdgcn_global_load_lds(GPTR(B1b + (size_t)r * K + k0 + c), LPTR(sB1 + e), 16, 0, 0);
            __builtin_amdgcn_global_load_lds(GPTR(B2b + (size_t)r * K + k0 + c), LPTR(sB2 + e), 16, 0, 0);
        }
        __syncthreads();
#pragma unroll
        for (int ks = 0; ks < 2; ++ks) {
            bf16x8 a[4], b1[4], b2[4];
#pragma unroll
            for (int m = 0; m < 4; ++m)
                a[m] = *(const bf16x8*)(sA + (wr + m * 16 + frow) * 64 + ks * 32 + fk);
#pragma unroll
            for (int n = 0; n < 4; ++n) {
                b1[n] = *(const bf16x8*)(sB1 + (wc + n * 16 + frow) * 64 + ks * 32 + fk);
                b2[n] = *(const bf16x8*)(sB2 + (wc + n * 16 + frow) * 64 + ks * 32 + fk);
            }
#pragma unroll
            for (int m = 0; m < 4; ++m)
#pragma unroll
                for (int n = 0; n < 4; ++n) {
                    acc1[m][n] = __builtin_amdgcn_mfma_f32_16x16x32_bf16(a[m], b1[n], acc1[m][n], 0, 0, 0);
                    acc2[m][n] = __builtin_amdgcn_mfma_f32_16x16x32_bf16(a[m], b2[n], acc2[m][n], 0, 0, 0);
                }
        }
        __syncthreads();
    }
    int crow = (lane >> 4) * 4, ccol = lane & 15;
#pragma unroll
    for (int m = 0; m < 4; ++m)
#pragma unroll
        for (int n = 0; n < 4; ++n)
#pragma unroll
            for (int j = 0; j < 4; ++j) {
                float f1 = acc1[m][n][j], f2 = acc2[m][n][j];
                float sg = f1 / (1.f + expf(-f1));
                int row = bm * 128 + wr + m * 16 + crow + j;
                int col = bn * 128 + wc + n * 16 + ccol;
                U[(size_t)row * 3072 + col] = (__bf16)(sg * f2);
            }
}

// ---------------- MFMA GEMM2: z = o + u@W2^T (in place) ----------------
__global__ __launch_bounds__(256) void gemm2_mfma(const __bf16* __restrict__ U,
                                                  const __bf16* __restrict__ W2,
                                                  __bf16* __restrict__ Oz) {
    __shared__ __bf16 sA[128 * 64];
    __shared__ __bf16 sB[128 * 64];
    const int K = 3072;
    int tid = threadIdx.x;
    int bn = blockIdx.x, bm = blockIdx.y;
    int lane = tid & 63;
    int w = tid >> 6;
    int wr = (w >> 1) * 64, wc = (w & 1) * 64;
    f32x4 acc[4][4] = {};
    const __bf16* Ab = U + (size_t)(bm * 128) * K;
    const __bf16* Bb = W2 + (size_t)(bn * 128) * K;
    int frow = lane & 15, fk = (lane >> 4) * 8;
    for (int k0 = 0; k0 < K; k0 += 64) {
#pragma unroll
        for (int t = 0; t < 4; ++t) {
            int e = (t * 256 + tid) * 8;
            int r = e >> 6, c = e & 63;
            __builtin_amdgcn_global_load_lds(GPTR(Ab + (size_t)r * K + k0 + c), LPTR(sA + e), 16, 0, 0);
            __builtin_amdgcn_global_load_lds(GPTR(Bb + (size_t)r * K + k0 + c), LPTR(sB + e), 16, 0, 0);
        }
        __syncthreads();
#pragma unroll
        for (int ks = 0; ks < 2; ++ks) {
            bf16x8 a[4], b[4];
#pragma unroll
            for (int m = 0; m < 4; ++m)
                a[m] = *(const bf16x8*)(sA + (wr + m * 16 + frow) * 64 + ks * 32 + fk);
#pragma unroll
            for (int n = 0; n < 4; ++n)
                b[n] = *(const bf16x8*)(sB + (wc + n * 16 + frow) * 64 + ks * 32 + fk);
#pragma unroll
            for (int m = 0; m < 4; ++m)
#pragma unroll
                for (int n = 0; n < 4; ++n)
                    acc[m][n] = __builtin_amdgcn_mfma_f32_16x16x32_bf16(a[m], b[n], acc[m][n], 0, 0, 0);
        }
        __syncthreads();
    }
    int crow = (lane >> 4) * 4, ccol = lane & 15;
#pragma unroll
    for (int m = 0; m < 4; ++m)
#pragma unroll
        for (int n = 0; n < 4; ++n)
#pragma unroll
            for (int j = 0; j < 4; ++j) {
                int row = bm * 128 + wr + m * 16 + crow + j;
                int col = bn * 128 + wc + n * 16 + ccol;
                size_t off = (size_t)row * 1024 + col;
                float z = (float)Oz[off] + acc[m][n][j];
                Oz[off] = (__bf16)z;
            }
}

// ---------------- final projection: 4 batch rows per block ----------------
__global__ __launch_bounds__(256) void out_proj4(const __bf16* __restrict__ z,
                                                 const float* __restrict__ ow,
                                                 float* __restrict__ out) {
    __shared__ float red[4][8];
    int c = blockIdx.x;
    int tid = threadIdx.x;
    int a0 = tid * 4;
    const float4* w4 = (const float4*)(ow + (size_t)c * 2048);
    float4 wA = w4[tid * 2];
    float4 wB = w4[tid * 2 + 1];
    float y[8];
#pragma unroll
    for (int jj = 0; jj < 8; ++jj) y[jj] = 0.f;
#pragma unroll
    for (int bb = 0; bb < 4; ++bb) {
        bf16x4 zv = *(const bf16x4*)(z + (size_t)((bb << 12) + c) * 1024 + a0);
        float z0 = (float)zv[0], z1 = (float)zv[1], z2 = (float)zv[2], z3 = (float)zv[3];
        y[2 * bb] += z0 * wA.x + z1 * wA.z + z2 * wB.x + z3 * wB.z;
        y[2 * bb + 1] += z0 * wA.y + z1 * wA.w + z2 * wB.y + z3 * wB.w;
    }
#pragma unroll
    for (int jj = 0; jj < 8; ++jj) y[jj] = wave_sum(y[jj]);
    if ((tid & 63) == 0) {
#pragma unroll
        for (int jj = 0; jj < 8; ++jj) red[tid >> 6][jj] = y[jj];
    }
    __syncthreads();
    if (tid < 4) {
        float a0s = red[0][2 * tid] + red[1][2 * tid] + red[2][2 * tid] + red[3][2 * tid];
        float a1s = red[0][2 * tid + 1] + red[1][2 * tid + 1] + red[2][2 * tid + 1] + red[3][2 * tid + 1];
        out[(size_t)tid * 4096 + c] = a0s / (1.f + expf(-a0s)) * a1s;
    }
}

extern "C" void kernel_launch(void* const* d_in, const int* in_sizes, int n_in,
                              void* d_out, int out_size, void* d_ws, size_t ws_size,
                              hipStream_t stream) {
    const float* x = (const float*)d_in[0];
    const float* cls = (const float*)d_in[1];
    const float* roots = (const float*)d_in[2];
    const float* crw = (const float*)d_in[3];
    const float* ccw = (const float*)d_in[4];
    const float* kv_w = (const float*)d_in[5];
    const float* gamma = (const float*)d_in[6];
    const float* beta = (const float*)d_in[7];
    const float* ffin = (const float*)d_in[8];
    const float* ffout = (const float*)d_in[9];
    const float* ow = (const float*)d_in[10];
    const int* cridx = (const int*)d_in[11];
    const int* ccidx = (const int*)d_in[12];
    float* out = (float*)d_out;

    // Workspace (floats), total 25,165,824 fl = 100.7 MB
    float* ws = (float*)d_ws;
    // Region A [0, 8388608)
    float* q = ws;                              // 4M fl
    float* kvb = ws + 4194304;                  // 2M fl
    __bf16* khi = (__bf16*)(ws + 6291456);      // 1M bf16
    __bf16* klo = (__bf16*)(ws + 6815744);
    __bf16* vthi = (__bf16*)(ws + 7340032);
    __bf16* vtlo = (__bf16*)(ws + 7864320);
    // Region B [8388608, 16777216): o_bf; early: x/kvw hi-lo splits
    __bf16* o_bf = (__bf16*)(ws + 8388608);
    __bf16* xhi = (__bf16*)(ws + 8388608);
    __bf16* xlo = (__bf16*)(ws + 8912896);
    __bf16* kvwhi = (__bf16*)(ws + 9437184);
    __bf16* kvwlo = (__bf16*)(ws + 10485760);
    // Region D [16777216, 25165824)
    float* qdet = ws + 16777216;                // 4M fl (early)
    __bf16* qhib = (__bf16*)(ws + 20971520);    // 4M bf16
    __bf16* qlob = (__bf16*)(ws + 23068672);    // 4M bf16
    // FFN phase (A + D reuse)
    __bf16* w1bf = (__bf16*)ws;
    __bf16* w2bf = (__bf16*)(ws + 3145728);
    float* mu = ws + 4718592;
    float* rstd = mu + 16384;
    __bf16* fbf = (__bf16*)(ws + 16777216);
    __bf16* u_s = (__bf16*)(ws + 18874368);

    hipMemcpyAsync(q, cls, 4194304 * sizeof(float), hipMemcpyDeviceToDevice, stream);
    scatter1<<<4096, 256, 0, stream>>>(roots, crw, cridx, q);
    hipMemcpyAsync(qdet, q, 4194304 * sizeof(float), hipMemcpyDeviceToDevice, stream);
    scatter2<<<8192, 256, 0, stream>>>(qdet, ccw, ccidx, q);
    rms_q_hilo<<<16384, 256, 0, stream>>>(q, qhib, qlob);
    split8<<<512, 256, 0, stream>>>(x, xhi, xlo, 131072);
    split8<<<1024, 256, 0, stream>>>(kv_w, kvwhi, kvwlo, 262144);
    gemm_kv_mfma<<<dim3(16, 16), 256, 0, stream>>>(xhi, xlo, kvwhi, kvwlo, kvb);
    kvsplit_hilo<<<4096, 256, 0, stream>>>(kvb, khi, klo);
    vtrans<<<256, 256, 0, stream>>>(kvb, vthi, vtlo);
    attn_mfma<<<4096, 256, 0, stream>>>(qhib, qlob, khi, klo, vthi, vtlo, o_bf);

    cvt_bf16<<<3072, 256, 0, stream>>>(ffin, w1bf, 786432);
    cvt_bf16<<<1536, 256, 0, stream>>>(ffout, w2bf, 393216);
    ln_stats<<<16384, 256, 0, stream>>>(o_bf, mu, rstd);
    for (int sl = 0; sl < 4; ++sl) {
        int R0 = sl * 4096;
        ln_apply<<<2048, 256, 0, stream>>>(o_bf, mu, rstd, gamma, beta, fbf, R0);
        gemm1_mfma<<<dim3(24, 32), 256, 0, stream>>>(fbf, w1bf, u_s);
        gemm2_mfma<<<dim3(8, 32), 256, 0, stream>>>(u_s, w2bf, o_bf + (size_t)R0 * 1024);
    }
    out_proj4<<<4096, 256, 0, stream>>>(o_bf, ow, out);
}

// Round 5
// 1022.681 us; speedup vs baseline: 6.8825x; 1.0893x over previous
//
#include <hip/hip_runtime.h>
#include <math.h>

#define EPS 1e-5f

typedef __bf16 bf16x8 __attribute__((ext_vector_type(8)));
typedef __bf16 bf16x4 __attribute__((ext_vector_type(4)));
typedef float f32x4 __attribute__((ext_vector_type(4)));

#define GPTR(p) ((const __attribute__((address_space(1))) void*)(p))
#define LPTR(p) ((__attribute__((address_space(3))) void*)(p))

// ---------------- wave reduction helpers ----------------
__device__ __forceinline__ float wave_sum(float v) {
#pragma unroll
    for (int o = 32; o; o >>= 1) v += __shfl_xor(v, o);
    return v;
}

// ---------------- scatter 1 ----------------
__global__ __launch_bounds__(256) void scatter1(const float* __restrict__ roots,
                                                const float* __restrict__ w,
                                                const int* __restrict__ idx,
                                                float* __restrict__ q) {
    int unit = (blockIdx.x << 2) + (threadIdx.x >> 6);
    int lane = threadIdx.x & 63;
    int h = unit >> 10;
    int i = unit & 1023;
    int r = idx[i];
    int c = idx[1024 + i];
    float val = roots[(h * 256 + r) * 64 + lane];
    float ss = wave_sum(val * val);
    float rs = rsqrtf(ss * (1.f / 64.f) + EPS);
    atomicAdd(&q[(h * 4096 + c) * 64 + lane], val * rs * w[(h << 10) + i]);
}

// ---------------- scatter 2 ----------------
__global__ __launch_bounds__(256) void scatter2(const float* __restrict__ qdet,
                                                const float* __restrict__ w,
                                                const int* __restrict__ idx,
                                                float* __restrict__ q) {
    int unit = (blockIdx.x << 2) + (threadIdx.x >> 6);
    int lane = threadIdx.x & 63;
    int h = unit >> 11;
    int i = unit & 2047;
    int c1 = idx[i];
    int c2 = idx[2048 + i];
    float val = qdet[(h * 4096 + c1) * 64 + lane] * w[(h << 11) + i];
    atomicAdd(&q[(h * 4096 + c2) * 64 + lane], val);
}

// ---------------- rmsnorm rows of 64 -> bf16 ----------------
__global__ __launch_bounds__(256) void rms_q_bf(const float* __restrict__ q,
                                                __bf16* __restrict__ qb) {
    int unit = (blockIdx.x << 2) + (threadIdx.x >> 6);
    int lane = threadIdx.x & 63;
    float v = q[(size_t)unit * 64 + lane];
    float ss = wave_sum(v * v);
    float r = v * rsqrtf(ss * (1.f / 64.f) + EPS);
    qb[(size_t)unit * 64 + lane] = (__bf16)r;
}

// ---------------- split fp32 -> hi/lo bf16 (8/thread) ----------------
__global__ __launch_bounds__(256) void split8(const float* __restrict__ in,
                                              __bf16* __restrict__ hi,
                                              __bf16* __restrict__ lo, int n8) {
    int i = blockIdx.x * 256 + threadIdx.x;
    if (i >= n8) return;
    const float4* p = (const float4*)in + (size_t)i * 2;
    float4 u0 = p[0], u1 = p[1];
    float f[8] = {u0.x, u0.y, u0.z, u0.w, u1.x, u1.y, u1.z, u1.w};
    bf16x8 vh, vl;
#pragma unroll
    for (int j = 0; j < 8; ++j) {
        vh[j] = (__bf16)f[j];
        vl[j] = (__bf16)(f[j] - (float)vh[j]);
    }
    *((bf16x8*)hi + i) = vh;
    *((bf16x8*)lo + i) = vl;
}

// ---------------- MFMA GEMM: kv = x @ kv_w^T, hi/lo 3-term, fp32 out ----------------
__global__ __launch_bounds__(256) void gemm_kv_mfma(const __bf16* __restrict__ Ah,
                                                    const __bf16* __restrict__ Al,
                                                    const __bf16* __restrict__ Bh,
                                                    const __bf16* __restrict__ Bl,
                                                    float* __restrict__ Cout) {
    __shared__ __bf16 sAh[64 * 64], sAl[64 * 64];
    __shared__ __bf16 sBh[128 * 64], sBl[128 * 64];
    int tid = threadIdx.x;
    int bn = blockIdx.x, bm = blockIdx.y;
    int lane = tid & 63;
    int w = tid >> 6;
    int wr = (w >> 1) * 32, wc = (w & 1) * 64;
    int frow = lane & 15, fk = (lane >> 4) * 8;
    f32x4 acc[2][4] = {};
    const __bf16* Ahb = Ah + (size_t)(bm * 64) * 1024;
    const __bf16* Alb = Al + (size_t)(bm * 64) * 1024;
    const __bf16* Bhb = Bh + (size_t)(bn * 128) * 1024;
    const __bf16* Blb = Bl + (size_t)(bn * 128) * 1024;
    for (int k0 = 0; k0 < 1024; k0 += 64) {
#pragma unroll
        for (int t = 0; t < 2; ++t) {
            int e = (t * 256 + tid) * 8;
            int r = e >> 6, c = e & 63;
            __builtin_amdgcn_global_load_lds(GPTR(Ahb + (size_t)r * 1024 + k0 + c), LPTR(sAh + e), 16, 0, 0);
            __builtin_amdgcn_global_load_lds(GPTR(Alb + (size_t)r * 1024 + k0 + c), LPTR(sAl + e), 16, 0, 0);
        }
#pragma unroll
        for (int t = 0; t < 4; ++t) {
            int e = (t * 256 + tid) * 8;
            int r = e >> 6, c = e & 63;
            __builtin_amdgcn_global_load_lds(GPTR(Bhb + (size_t)r * 1024 + k0 + c), LPTR(sBh + e), 16, 0, 0);
            __builtin_amdgcn_global_load_lds(GPTR(Blb + (size_t)r * 1024 + k0 + c), LPTR(sBl + e), 16, 0, 0);
        }
        __syncthreads();
#pragma unroll
        for (int ks = 0; ks < 2; ++ks) {
            bf16x8 ah[2], al[2], bh2[4], bl2[4];
#pragma unroll
            for (int m = 0; m < 2; ++m) {
                ah[m] = *(const bf16x8*)(sAh + (wr + m * 16 + frow) * 64 + ks * 32 + fk);
                al[m] = *(const bf16x8*)(sAl + (wr + m * 16 + frow) * 64 + ks * 32 + fk);
            }
#pragma unroll
            for (int n = 0; n < 4; ++n) {
                bh2[n] = *(const bf16x8*)(sBh + (wc + n * 16 + frow) * 64 + ks * 32 + fk);
                bl2[n] = *(const bf16x8*)(sBl + (wc + n * 16 + frow) * 64 + ks * 32 + fk);
            }
#pragma unroll
            for (int m = 0; m < 2; ++m)
#pragma unroll
                for (int n = 0; n < 4; ++n) {
                    acc[m][n] = __builtin_amdgcn_mfma_f32_16x16x32_bf16(ah[m], bh2[n], acc[m][n], 0, 0, 0);
                    acc[m][n] = __builtin_amdgcn_mfma_f32_16x16x32_bf16(ah[m], bl2[n], acc[m][n], 0, 0, 0);
                    acc[m][n] = __builtin_amdgcn_mfma_f32_16x16x32_bf16(al[m], bh2[n], acc[m][n], 0, 0, 0);
                }
        }
        __syncthreads();
    }
    int crow = (lane >> 4) * 4, ccol = lane & 15;
#pragma unroll
    for (int m = 0; m < 2; ++m)
#pragma unroll
        for (int n = 0; n < 4; ++n)
#pragma unroll
            for (int j = 0; j < 4; ++j) {
                int row = bm * 64 + wr + m * 16 + crow + j;
                int col = bn * 128 + wc + n * 16 + ccol;
                Cout[(size_t)row * 2048 + col] = acc[m][n][j];
            }
}

// ---------------- kv split: K rmsnorm -> bf16 [bh][s][64] ----------------
__global__ __launch_bounds__(256) void kvsplit_bf(const float* __restrict__ kv,
                                                  __bf16* __restrict__ kb) {
    int unit = (blockIdx.x << 2) + (threadIdx.x >> 6);  // bh*256+s
    int lane = threadIdx.x & 63;
    int b = unit >> 12;
    int h = (unit >> 8) & 15;
    int s = unit & 255;
    float kvl = kv[(size_t)(b * 256 + s) * 2048 + (h << 6) + lane];
    float ss = wave_sum(kvl * kvl);
    float kn = kvl * rsqrtf(ss * (1.f / 64.f) + EPS);
    kb[(size_t)unit * 64 + lane] = (__bf16)kn;
}

// ---------------- V transpose: kv -> vt bf16 [bh][d=64][s=256] ----------------
__global__ __launch_bounds__(256) void vtrans_bf(const float* __restrict__ kv,
                                                 __bf16* __restrict__ vt) {
    __shared__ float T[64][65];
    int bh = blockIdx.x >> 2;
    int sc = blockIdx.x & 3;
    int b = bh >> 4, h = bh & 15;
    int tid = threadIdx.x;
    int s0 = sc * 64;
    int sl = tid >> 2, d0 = (tid & 3) * 16;
    const float* src = kv + (size_t)(b * 256 + s0 + sl) * 2048 + 1024 + (h << 6) + d0;
#pragma unroll
    for (int t = 0; t < 4; ++t) {
        float4 v4 = *(const float4*)(src + t * 4);
        T[sl][d0 + t * 4 + 0] = v4.x;
        T[sl][d0 + t * 4 + 1] = v4.y;
        T[sl][d0 + t * 4 + 2] = v4.z;
        T[sl][d0 + t * 4 + 3] = v4.w;
    }
    __syncthreads();
    int dr = tid >> 2, c0 = (tid & 3) * 16;
    bf16x8 h0, h1;
#pragma unroll
    for (int jj = 0; jj < 8; ++jj) h0[jj] = (__bf16)T[c0 + jj][dr];
#pragma unroll
    for (int jj = 0; jj < 8; ++jj) h1[jj] = (__bf16)T[c0 + 8 + jj][dr];
    size_t base = (size_t)bh * 16384 + (size_t)dr * 256 + s0 + c0;
    *(bf16x8*)(vt + base) = h0;
    *(bf16x8*)(vt + base + 8) = h1;
}

// ---------------- MFMA attention (plain bf16) ----------------
// block: one (b,h) x 64-query tile; 4 waves.
// QK^T: scoresT[s][q] = mfma(K, Q); wave w owns s in [w*64, w*64+64).
// PV:   OT[d][q] = mfma(VT, P); wave w owns q in [w*16, w*16+16).
__global__ __launch_bounds__(256) void attn_mfma(const __bf16* __restrict__ qb,
                                                 const __bf16* __restrict__ kb,
                                                 const __bf16* __restrict__ vtb,
                                                 __bf16* __restrict__ ob) {
    __shared__ __bf16 P[64 * 264];
    __shared__ float wred[8][64];  // rows 0-3: wave max; 4-7: wave sum
    __shared__ float denomL[64];
    __shared__ __bf16 Ot[64 * 72];

    int wg = blockIdx.x;
    int swz = (wg & 7) * 512 + (wg >> 3);  // XCD-chunked swizzle
    int bh = swz >> 6;
    int qt = swz & 63;
    int b = bh >> 4, h = bh & 15;
    int tid = threadIdx.x;
    int lane = tid & 63;
    int w = tid >> 6;
    int frow = lane & 15;
    int fk = (lane >> 4) * 8;
    int crow = (lane >> 4) * 4;
    int ccol = lane & 15;
    int q0 = qt * 64;
    int wsr = w * 64;

    const __bf16* kh = kb + (size_t)bh * 16384;
    const __bf16* qh = qb + (size_t)h * 262144 + (size_t)q0 * 64;

    f32x4 acc[4][4] = {};  // [m=s-frag][n=q-frag]
#pragma unroll
    for (int ks = 0; ks < 2; ++ks) {
        bf16x8 kf[4];
#pragma unroll
        for (int m = 0; m < 4; ++m)
            kf[m] = *(const bf16x8*)(kh + (wsr + m * 16 + frow) * 64 + ks * 32 + fk);
#pragma unroll
        for (int n = 0; n < 4; ++n) {
            bf16x8 qf = *(const bf16x8*)(qh + (n * 16 + frow) * 64 + ks * 32 + fk);
#pragma unroll
            for (int m = 0; m < 4; ++m)
                acc[m][n] = __builtin_amdgcn_mfma_f32_16x16x32_bf16(kf[m], qf, acc[m][n], 0, 0, 0);
        }
    }
#pragma unroll
    for (int m = 0; m < 4; ++m)
#pragma unroll
        for (int n = 0; n < 4; ++n)
#pragma unroll
            for (int j = 0; j < 4; ++j) acc[m][n][j] *= 0.125f;

    // wave max per q (over this wave's 64 s)
    float lm[4];
#pragma unroll
    for (int n = 0; n < 4; ++n) {
        float v = -1e30f;
#pragma unroll
        for (int m = 0; m < 4; ++m)
#pragma unroll
            for (int j = 0; j < 4; ++j) v = fmaxf(v, acc[m][n][j]);
        v = fmaxf(v, __shfl_xor(v, 16));
        v = fmaxf(v, __shfl_xor(v, 32));
        lm[n] = v;
    }
    if (lane < 16) {
#pragma unroll
        for (int n = 0; n < 4; ++n) wred[w][n * 16 + lane] = lm[n];
    }
    __syncthreads();
    float gm[4];
#pragma unroll
    for (int n = 0; n < 4; ++n) {
        int qq = n * 16 + ccol;
        gm[n] = fmaxf(fmaxf(wred[0][qq], wred[1][qq]), fmaxf(wred[2][qq], wred[3][qq]));
    }
    float lsum[4] = {0.f, 0.f, 0.f, 0.f};
#pragma unroll
    for (int m = 0; m < 4; ++m)
#pragma unroll
        for (int n = 0; n < 4; ++n)
#pragma unroll
            for (int j = 0; j < 4; ++j) {
                float p = __expf(acc[m][n][j] - gm[n]);
                acc[m][n][j] = p;
                lsum[n] += p;
            }
#pragma unroll
    for (int n = 0; n < 4; ++n) {
        float v = lsum[n];
        v += __shfl_xor(v, 16);
        v += __shfl_xor(v, 32);
        lsum[n] = v;
    }
    if (lane < 16) {
#pragma unroll
        for (int n = 0; n < 4; ++n) wred[4 + w][n * 16 + lane] = lsum[n];
    }
    // write P to padded LDS [q][264] as b64 chunks (s-consecutive)
#pragma unroll
    for (int m = 0; m < 4; ++m)
#pragma unroll
        for (int n = 0; n < 4; ++n) {
            bf16x4 pv;
#pragma unroll
            for (int j = 0; j < 4; ++j) pv[j] = (__bf16)acc[m][n][j];
            *(bf16x4*)(P + (n * 16 + ccol) * 264 + wsr + m * 16 + crow) = pv;
        }
    __syncthreads();
    if (tid < 64)
        denomL[tid] = wred[4][tid] + wred[5][tid] + wred[6][tid] + wred[7][tid];

    // PV
    const __bf16* vh = vtb + (size_t)bh * 16384;
    f32x4 accO[4] = {};
#pragma unroll
    for (int ks = 0; ks < 8; ++ks) {
        bf16x8 pf = *(const bf16x8*)(P + (w * 16 + frow) * 264 + ks * 32 + fk);
#pragma unroll
        for (int m = 0; m < 4; ++m) {
            bf16x8 vf = *(const bf16x8*)(vh + (m * 16 + frow) * 256 + ks * 32 + fk);
            accO[m] = __builtin_amdgcn_mfma_f32_16x16x32_bf16(vf, pf, accO[m], 0, 0, 0);
        }
    }
    __syncthreads();
    float rd = 1.0f / denomL[w * 16 + ccol];
#pragma unroll
    for (int m = 0; m < 4; ++m) {
        bf16x4 ov;
#pragma unroll
        for (int j = 0; j < 4; ++j) ov[j] = (__bf16)(accO[m][j] * rd);
        *(bf16x4*)(Ot + (w * 16 + ccol) * 72 + m * 16 + crow) = ov;
    }
    __syncthreads();
    {
        int qq = tid >> 2, dc = tid & 3;
        bf16x8 o0 = *(const bf16x8*)(Ot + qq * 72 + dc * 16);
        bf16x8 o1 = *(const bf16x8*)(Ot + qq * 72 + dc * 16 + 8);
        size_t base = (size_t)((b << 12) + q0 + qq) * 1024 + (h << 6) + dc * 16;
        *(bf16x8*)(ob + base) = o0;
        *(bf16x8*)(ob + base + 8) = o1;
    }
}

// ---------------- fp32 -> bf16 conversion ----------------
__global__ __launch_bounds__(256) void cvt_bf16(const float* __restrict__ in,
                                                __bf16* __restrict__ out, int n8) {
    int i = blockIdx.x * 256 + threadIdx.x;
    if (i >= n8) return;
    const float4* p = (const float4*)in + (size_t)i * 2;
    float4 u0 = p[0], u1 = p[1];
    bf16x8 v;
    v[0] = (__bf16)u0.x; v[1] = (__bf16)u0.y; v[2] = (__bf16)u0.z; v[3] = (__bf16)u0.w;
    v[4] = (__bf16)u1.x; v[5] = (__bf16)u1.y; v[6] = (__bf16)u1.z; v[7] = (__bf16)u1.w;
    *((bf16x8*)out + i) = v;
}

// ---------------- LayerNorm stats (bf16 input) ----------------
__global__ __launch_bounds__(256) void ln_stats(const __bf16* __restrict__ ob,
                                                float* __restrict__ mu,
                                                float* __restrict__ rstd) {
    __shared__ float r0[4], r1[4];
    int row = blockIdx.x;
    int tid = threadIdx.x;
    const bf16x4* op = (const bf16x4*)(ob + (size_t)row * 1024);
    bf16x4 v = op[tid];
    float s = 0, sq = 0;
#pragma unroll
    for (int j = 0; j < 4; ++j) { float f = (float)v[j]; s += f; sq += f * f; }
    s = wave_sum(s);
    sq = wave_sum(sq);
    if ((tid & 63) == 0) { r0[tid >> 6] = s; r1[tid >> 6] = sq; }
    __syncthreads();
    if (tid == 0) {
        float S = r0[0] + r0[1] + r0[2] + r0[3];
        float Q = r1[0] + r1[1] + r1[2] + r1[3];
        float m = S * (1.f / 1024.f);
        float var = Q * (1.f / 1024.f) - m * m;
        mu[row] = m;
        rstd[row] = rsqrtf(var + EPS);
    }
}

// ---------------- LN apply -> bf16 f (slice-local) ----------------
__global__ __launch_bounds__(256) void ln_apply(const __bf16* __restrict__ ob,
                                                const float* __restrict__ mu,
                                                const float* __restrict__ rstd,
                                                const float* __restrict__ gamma,
                                                const float* __restrict__ beta,
                                                __bf16* __restrict__ f, int R0) {
    int i = blockIdx.x * 256 + threadIdx.x;
    int row = i >> 7;
    int c8 = (i & 127) * 8;
    int gr = R0 + row;
    float m = mu[gr], rs = rstd[gr];
    bf16x8 ov = *((const bf16x8*)(ob + (size_t)gr * 1024 + c8));
    bf16x8 r;
#pragma unroll
    for (int j = 0; j < 8; ++j) {
        float v = (float)ov[j];
        r[j] = (__bf16)((v - m) * rs * gamma[c8 + j] + beta[c8 + j]);
    }
    *((bf16x8*)(f + (size_t)row * 1024 + c8)) = r;
}

// ---------------- MFMA GEMM1: u = silu(f@W1a^T) * (f@W1b^T) ----------------
__global__ __launch_bounds__(256) void gemm1_mfma(const __bf16* __restrict__ A,
                                                  const __bf16* __restrict__ W,
                                                  __bf16* __restrict__ U) {
    __shared__ __bf16 sA[128 * 64];
    __shared__ __bf16 sB1[128 * 64];
    __shared__ __bf16 sB2[128 * 64];
    const int K = 1024;
    int tid = threadIdx.x;
    int bn = blockIdx.x, bm = blockIdx.y;
    int lane = tid & 63;
    int w = tid >> 6;
    int wr = (w >> 1) * 64, wc = (w & 1) * 64;
    f32x4 acc1[4][4] = {};
    f32x4 acc2[4][4] = {};
    const __bf16* Ab = A + (size_t)(bm * 128) * K;
    const __bf16* B1b = W + (size_t)(bn * 128) * K;
    const __bf16* B2b = W + (size_t)(3072 + bn * 128) * K;
    int frow = lane & 15, fk = (lane >> 4) * 8;
    for (int k0 = 0; k0 < K; k0 += 64) {
#pragma unroll
        for (int t = 0; t < 4; ++t) {
            int e = (t * 256 + tid) * 8;
            int r = e >> 6, c = e & 63;
            __builtin_amdgcn_global_load_lds(GPTR(Ab + (size_t)r * K + k0 + c), LPTR(sA + e), 16, 0, 0);
            __builtin_amdgcn_global_load_lds(GPTR(B1b + (size_t)r * K + k0 + c), LPTR(sB1 + e), 16, 0, 0);
            __builtin_amdgcn_global_load_lds(GPTR(B2b + (size_t)r * K + k0 + c), LPTR(sB2 + e), 16, 0, 0);
        }
        __syncthreads();
#pragma unroll
        for (int ks = 0; ks < 2; ++ks) {
            bf16x8 a[4], b1[4], b2[4];
#pragma unroll
            for (int m = 0; m < 4; ++m)
                a[m] = *(const bf16x8*)(sA + (wr + m * 16 + frow) * 64 + ks * 32 + fk);
#pragma unroll
            for (int n = 0; n < 4; ++n) {
                b1[n] = *(const bf16x8*)(sB1 + (wc + n * 16 + frow) * 64 + ks * 32 + fk);
                b2[n] = *(const bf16x8*)(sB2 + (wc + n * 16 + frow) * 64 + ks * 32 + fk);
            }
#pragma unroll
            for (int m = 0; m < 4; ++m)
#pragma unroll
                for (int n = 0; n < 4; ++n) {
                    acc1[m][n] = __builtin_amdgcn_mfma_f32_16x16x32_bf16(a[m], b1[n], acc1[m][n], 0, 0, 0);
                    acc2[m][n] = __builtin_amdgcn_mfma_f32_16x16x32_bf16(a[m], b2[n], acc2[m][n], 0, 0, 0);
                }
        }
        __syncthreads();
    }
    int crow = (lane >> 4) * 4, ccol = lane & 15;
#pragma unroll
    for (int m = 0; m < 4; ++m)
#pragma unroll
        for (int n = 0; n < 4; ++n)
#pragma unroll
            for (int j = 0; j < 4; ++j) {
                float f1 = acc1[m][n][j], f2 = acc2[m][n][j];
                float sg = f1 / (1.f + expf(-f1));
                int row = bm * 128 + wr + m * 16 + crow + j;
                int col = bn * 128 + wc + n * 16 + ccol;
                U[(size_t)row * 3072 + col] = (__bf16)(sg * f2);
            }
}

// ---------------- MFMA GEMM2: z = o + u@W2^T (in place) ----------------
__global__ __launch_bounds__(256) void gemm2_mfma(const __bf16* __restrict__ U,
                                                  const __bf16* __restrict__ W2,
                                                  __bf16* __restrict__ Oz) {
    __shared__ __bf16 sA[128 * 64];
    __shared__ __bf16 sB[128 * 64];
    const int K = 3072;
    int tid = threadIdx.x;
    int bn = blockIdx.x, bm = blockIdx.y;
    int lane = tid & 63;
    int w = tid >> 6;
    int wr = (w >> 1) * 64, wc = (w & 1) * 64;
    f32x4 acc[4][4] = {};
    const __bf16* Ab = U + (size_t)(bm * 128) * K;
    const __bf16* Bb = W2 + (size_t)(bn * 128) * K;
    int frow = lane & 15, fk = (lane >> 4) * 8;
    for (int k0 = 0; k0 < K; k0 += 64) {
#pragma unroll
        for (int t = 0; t < 4; ++t) {
            int e = (t * 256 + tid) * 8;
            int r = e >> 6, c = e & 63;
            __builtin_amdgcn_global_load_lds(GPTR(Ab + (size_t)r * K + k0 + c), LPTR(sA + e), 16, 0, 0);
            __builtin_amdgcn_global_load_lds(GPTR(Bb + (size_t)r * K + k0 + c), LPTR(sB + e), 16, 0, 0);
        }
        __syncthreads();
#pragma unroll
        for (int ks = 0; ks < 2; ++ks) {
            bf16x8 a[4], b[4];
#pragma unroll
            for (int m = 0; m < 4; ++m)
                a[m] = *(const bf16x8*)(sA + (wr + m * 16 + frow) * 64 + ks * 32 + fk);
#pragma unroll
            for (int n = 0; n < 4; ++n)
                b[n] = *(const bf16x8*)(sB + (wc + n * 16 + frow) * 64 + ks * 32 + fk);
#pragma unroll
            for (int m = 0; m < 4; ++m)
#pragma unroll
                for (int n = 0; n < 4; ++n)
                    acc[m][n] = __builtin_amdgcn_mfma_f32_16x16x32_bf16(a[m], b[n], acc[m][n], 0, 0, 0);
        }
        __syncthreads();
    }
    int crow = (lane >> 4) * 4, ccol = lane & 15;
#pragma unroll
    for (int m = 0; m < 4; ++m)
#pragma unroll
        for (int n = 0; n < 4; ++n)
#pragma unroll
            for (int j = 0; j < 4; ++j) {
                int row = bm * 128 + wr + m * 16 + crow + j;
                int col = bn * 128 + wc + n * 16 + ccol;
                size_t off = (size_t)row * 1024 + col;
                float z = (float)Oz[off] + acc[m][n][j];
                Oz[off] = (__bf16)z;
            }
}

// ---------------- final projection: 4 batch rows per block ----------------
__global__ __launch_bounds__(256) void out_proj4(const __bf16* __restrict__ z,
                                                 const float* __restrict__ ow,
                                                 float* __restrict__ out) {
    __shared__ float red[4][8];
    int c = blockIdx.x;
    int tid = threadIdx.x;
    int a0 = tid * 4;
    const float4* w4 = (const float4*)(ow + (size_t)c * 2048);
    float4 wA = w4[tid * 2];
    float4 wB = w4[tid * 2 + 1];
    float y[8];
#pragma unroll
    for (int jj = 0; jj < 8; ++jj) y[jj] = 0.f;
#pragma unroll
    for (int bb = 0; bb < 4; ++bb) {
        bf16x4 zv = *(const bf16x4*)(z + (size_t)((bb << 12) + c) * 1024 + a0);
        float z0 = (float)zv[0], z1 = (float)zv[1], z2 = (float)zv[2], z3 = (float)zv[3];
        y[2 * bb] += z0 * wA.x + z1 * wA.z + z2 * wB.x + z3 * wB.z;
        y[2 * bb + 1] += z0 * wA.y + z1 * wA.w + z2 * wB.y + z3 * wB.w;
    }
#pragma unroll
    for (int jj = 0; jj < 8; ++jj) y[jj] = wave_sum(y[jj]);
    if ((tid & 63) == 0) {
#pragma unroll
        for (int jj = 0; jj < 8; ++jj) red[tid >> 6][jj] = y[jj];
    }
    __syncthreads();
    if (tid < 4) {
        float a0s = red[0][2 * tid] + red[1][2 * tid] + red[2][2 * tid] + red[3][2 * tid];
        float a1s = red[0][2 * tid + 1] + red[1][2 * tid + 1] + red[2][2 * tid + 1] + red[3][2 * tid + 1];
        out[(size_t)tid * 4096 + c] = a0s / (1.f + expf(-a0s)) * a1s;
    }
}

extern "C" void kernel_launch(void* const* d_in, const int* in_sizes, int n_in,
                              void* d_out, int out_size, void* d_ws, size_t ws_size,
                              hipStream_t stream) {
    const float* x = (const float*)d_in[0];
    const float* cls = (const float*)d_in[1];
    const float* roots = (const float*)d_in[2];
    const float* crw = (const float*)d_in[3];
    const float* ccw = (const float*)d_in[4];
    const float* kv_w = (const float*)d_in[5];
    const float* gamma = (const float*)d_in[6];
    const float* beta = (const float*)d_in[7];
    const float* ffin = (const float*)d_in[8];
    const float* ffout = (const float*)d_in[9];
    const float* ow = (const float*)d_in[10];
    const int* cridx = (const int*)d_in[11];
    const int* ccidx = (const int*)d_in[12];
    float* out = (float*)d_out;

    // Workspace (floats), total 25,165,824 fl = 100.7 MB
    float* ws = (float*)d_ws;
    // Region A [0, 8388608)
    float* q = ws;                              // 4M fl
    float* kvb = ws + 4194304;                  // 2M fl
    __bf16* kbf = (__bf16*)(ws + 6291456);      // 1M bf16 (524288 fl)
    __bf16* vtb = (__bf16*)(ws + 6815744);      // 1M bf16
    // Region B [8388608, 16777216): o_bf; early: x/kvw hi-lo splits
    __bf16* o_bf = (__bf16*)(ws + 8388608);
    __bf16* xhi = (__bf16*)(ws + 8388608);
    __bf16* xlo = (__bf16*)(ws + 8912896);
    __bf16* kvwhi = (__bf16*)(ws + 9437184);
    __bf16* kvwlo = (__bf16*)(ws + 10485760);
    // Region D [16777216, 25165824)
    float* qdet = ws + 16777216;                // 4M fl (early)
    __bf16* qbf = (__bf16*)(ws + 20971520);     // 4M bf16
    // FFN phase (A + D reuse)
    __bf16* w1bf = (__bf16*)ws;
    __bf16* w2bf = (__bf16*)(ws + 3145728);
    float* mu = ws + 4718592;
    float* rstd = mu + 16384;
    __bf16* fbf = (__bf16*)(ws + 16777216);
    __bf16* u_s = (__bf16*)(ws + 18874368);

    hipMemcpyAsync(q, cls, 4194304 * sizeof(float), hipMemcpyDeviceToDevice, stream);
    scatter1<<<4096, 256, 0, stream>>>(roots, crw, cridx, q);
    hipMemcpyAsync(qdet, q, 4194304 * sizeof(float), hipMemcpyDeviceToDevice, stream);
    scatter2<<<8192, 256, 0, stream>>>(qdet, ccw, ccidx, q);
    rms_q_bf<<<16384, 256, 0, stream>>>(q, qbf);
    split8<<<512, 256, 0, stream>>>(x, xhi, xlo, 131072);
    split8<<<1024, 256, 0, stream>>>(kv_w, kvwhi, kvwlo, 262144);
    gemm_kv_mfma<<<dim3(16, 16), 256, 0, stream>>>(xhi, xlo, kvwhi, kvwlo, kvb);
    kvsplit_bf<<<4096, 256, 0, stream>>>(kvb, kbf);
    vtrans_bf<<<256, 256, 0, stream>>>(kvb, vtb);
    attn_mfma<<<4096, 256, 0, stream>>>(qbf, kbf, vtb, o_bf);

    cvt_bf16<<<3072, 256, 0, stream>>>(ffin, w1bf, 786432);
    cvt_bf16<<<1536, 256, 0, stream>>>(ffout, w2bf, 393216);
    ln_stats<<<16384, 256, 0, stream>>>(o_bf, mu, rstd);
    for (int sl = 0; sl < 4; ++sl) {
        int R0 = sl * 4096;
        ln_apply<<<2048, 256, 0, stream>>>(o_bf, mu, rstd, gamma, beta, fbf, R0);
        gemm1_mfma<<<dim3(24, 32), 256, 0, stream>>>(fbf, w1bf, u_s);
        gemm2_mfma<<<dim3(8, 32), 256, 0, stream>>>(u_s, w2bf, o_bf + (size_t)R0 * 1024);
    }
    out_proj4<<<4096, 256, 0, stream>>>(o_bf, ow, out);
}

// Round 6
// 900.033 us; speedup vs baseline: 7.8204x; 1.1363x over previous
//
#include <hip/hip_runtime.h>
#include <math.h>

#define EPS 1e-5f

typedef __bf16 bf16x8 __attribute__((ext_vector_type(8)));
typedef __bf16 bf16x4 __attribute__((ext_vector_type(4)));
typedef float f32x4 __attribute__((ext_vector_type(4)));

#define GPTR(p) ((const __attribute__((address_space(1))) void*)(p))
#define LPTR(p) ((__attribute__((address_space(3))) void*)(p))

// ---------------- wave reduction helpers ----------------
__device__ __forceinline__ float wave_sum(float v) {
#pragma unroll
    for (int o = 32; o; o >>= 1) v += __shfl_xor(v, o);
    return v;
}

// ---------------- scatter 1 ----------------
__global__ __launch_bounds__(256) void scatter1(const float* __restrict__ roots,
                                                const float* __restrict__ w,
                                                const int* __restrict__ idx,
                                                float* __restrict__ q) {
    int unit = (blockIdx.x << 2) + (threadIdx.x >> 6);
    int lane = threadIdx.x & 63;
    int h = unit >> 10;
    int i = unit & 1023;
    int r = idx[i];
    int c = idx[1024 + i];
    float val = roots[(h * 256 + r) * 64 + lane];
    float ss = wave_sum(val * val);
    float rs = rsqrtf(ss * (1.f / 64.f) + EPS);
    atomicAdd(&q[(h * 4096 + c) * 64 + lane], val * rs * w[(h << 10) + i]);
}

// ---------------- scatter 2 ----------------
__global__ __launch_bounds__(256) void scatter2(const float* __restrict__ qdet,
                                                const float* __restrict__ w,
                                                const int* __restrict__ idx,
                                                float* __restrict__ q) {
    int unit = (blockIdx.x << 2) + (threadIdx.x >> 6);
    int lane = threadIdx.x & 63;
    int h = unit >> 11;
    int i = unit & 2047;
    int c1 = idx[i];
    int c2 = idx[2048 + i];
    float val = qdet[(h * 4096 + c1) * 64 + lane] * w[(h << 11) + i];
    atomicAdd(&q[(h * 4096 + c2) * 64 + lane], val);
}

// ---------------- rmsnorm rows of 64 -> bf16 ----------------
__global__ __launch_bounds__(256) void rms_q_bf(const float* __restrict__ q,
                                                __bf16* __restrict__ qb) {
    int unit = (blockIdx.x << 2) + (threadIdx.x >> 6);
    int lane = threadIdx.x & 63;
    float v = q[(size_t)unit * 64 + lane];
    float ss = wave_sum(v * v);
    float r = v * rsqrtf(ss * (1.f / 64.f) + EPS);
    qb[(size_t)unit * 64 + lane] = (__bf16)r;
}

// ---------------- split fp32 -> hi/lo bf16 (8/thread) ----------------
__global__ __launch_bounds__(256) void split8(const float* __restrict__ in,
                                              __bf16* __restrict__ hi,
                                              __bf16* __restrict__ lo, int n8) {
    int i = blockIdx.x * 256 + threadIdx.x;
    if (i >= n8) return;
    const float4* p = (const float4*)in + (size_t)i * 2;
    float4 u0 = p[0], u1 = p[1];
    float f[8] = {u0.x, u0.y, u0.z, u0.w, u1.x, u1.y, u1.z, u1.w};
    bf16x8 vh, vl;
#pragma unroll
    for (int j = 0; j < 8; ++j) {
        vh[j] = (__bf16)f[j];
        vl[j] = (__bf16)(f[j] - (float)vh[j]);
    }
    *((bf16x8*)hi + i) = vh;
    *((bf16x8*)lo + i) = vl;
}

// ---------------- MFMA GEMM: kv = x @ kv_w^T, hi/lo 3-term, fp32 out ----------------
__global__ __launch_bounds__(256) void gemm_kv_mfma(const __bf16* __restrict__ Ah,
                                                    const __bf16* __restrict__ Al,
                                                    const __bf16* __restrict__ Bh,
                                                    const __bf16* __restrict__ Bl,
                                                    float* __restrict__ Cout) {
    __shared__ __bf16 sAh[64 * 64], sAl[64 * 64];
    __shared__ __bf16 sBh[128 * 64], sBl[128 * 64];
    int tid = threadIdx.x;
    int bn = blockIdx.x, bm = blockIdx.y;
    int lane = tid & 63;
    int w = tid >> 6;
    int wr = (w >> 1) * 32, wc = (w & 1) * 64;
    int frow = lane & 15, fk = (lane >> 4) * 8;
    f32x4 acc[2][4] = {};
    const __bf16* Ahb = Ah + (size_t)(bm * 64) * 1024;
    const __bf16* Alb = Al + (size_t)(bm * 64) * 1024;
    const __bf16* Bhb = Bh + (size_t)(bn * 128) * 1024;
    const __bf16* Blb = Bl + (size_t)(bn * 128) * 1024;
    for (int k0 = 0; k0 < 1024; k0 += 64) {
#pragma unroll
        for (int t = 0; t < 2; ++t) {
            int e = (t * 256 + tid) * 8;
            int r = e >> 6, c = e & 63;
            __builtin_amdgcn_global_load_lds(GPTR(Ahb + (size_t)r * 1024 + k0 + c), LPTR(sAh + e), 16, 0, 0);
            __builtin_amdgcn_global_load_lds(GPTR(Alb + (size_t)r * 1024 + k0 + c), LPTR(sAl + e), 16, 0, 0);
        }
#pragma unroll
        for (int t = 0; t < 4; ++t) {
            int e = (t * 256 + tid) * 8;
            int r = e >> 6, c = e & 63;
            __builtin_amdgcn_global_load_lds(GPTR(Bhb + (size_t)r * 1024 + k0 + c), LPTR(sBh + e), 16, 0, 0);
            __builtin_amdgcn_global_load_lds(GPTR(Blb + (size_t)r * 1024 + k0 + c), LPTR(sBl + e), 16, 0, 0);
        }
        __syncthreads();
#pragma unroll
        for (int ks = 0; ks < 2; ++ks) {
            bf16x8 ah[2], al[2], bh2[4], bl2[4];
#pragma unroll
            for (int m = 0; m < 2; ++m) {
                ah[m] = *(const bf16x8*)(sAh + (wr + m * 16 + frow) * 64 + ks * 32 + fk);
                al[m] = *(const bf16x8*)(sAl + (wr + m * 16 + frow) * 64 + ks * 32 + fk);
            }
#pragma unroll
            for (int n = 0; n < 4; ++n) {
                bh2[n] = *(const bf16x8*)(sBh + (wc + n * 16 + frow) * 64 + ks * 32 + fk);
                bl2[n] = *(const bf16x8*)(sBl + (wc + n * 16 + frow) * 64 + ks * 32 + fk);
            }
#pragma unroll
            for (int m = 0; m < 2; ++m)
#pragma unroll
                for (int n = 0; n < 4; ++n) {
                    acc[m][n] = __builtin_amdgcn_mfma_f32_16x16x32_bf16(ah[m], bh2[n], acc[m][n], 0, 0, 0);
                    acc[m][n] = __builtin_amdgcn_mfma_f32_16x16x32_bf16(ah[m], bl2[n], acc[m][n], 0, 0, 0);
                    acc[m][n] = __builtin_amdgcn_mfma_f32_16x16x32_bf16(al[m], bh2[n], acc[m][n], 0, 0, 0);
                }
        }
        __syncthreads();
    }
    int crow = (lane >> 4) * 4, ccol = lane & 15;
#pragma unroll
    for (int m = 0; m < 2; ++m)
#pragma unroll
        for (int n = 0; n < 4; ++n)
#pragma unroll
            for (int j = 0; j < 4; ++j) {
                int row = bm * 64 + wr + m * 16 + crow + j;
                int col = bn * 128 + wc + n * 16 + ccol;
                Cout[(size_t)row * 2048 + col] = acc[m][n][j];
            }
}

// ---------------- kv split: K rmsnorm -> bf16 [bh][s][64] ----------------
__global__ __launch_bounds__(256) void kvsplit_bf(const float* __restrict__ kv,
                                                  __bf16* __restrict__ kb) {
    int unit = (blockIdx.x << 2) + (threadIdx.x >> 6);  // bh*256+s
    int lane = threadIdx.x & 63;
    int b = unit >> 12;
    int h = (unit >> 8) & 15;
    int s = unit & 255;
    float kvl = kv[(size_t)(b * 256 + s) * 2048 + (h << 6) + lane];
    float ss = wave_sum(kvl * kvl);
    float kn = kvl * rsqrtf(ss * (1.f / 64.f) + EPS);
    kb[(size_t)unit * 64 + lane] = (__bf16)kn;
}

// ---------------- V transpose: kv -> vt bf16 [bh][d=64][s=256] ----------------
__global__ __launch_bounds__(256) void vtrans_bf(const float* __restrict__ kv,
                                                 __bf16* __restrict__ vt) {
    __shared__ float T[64][65];
    int bh = blockIdx.x >> 2;
    int sc = blockIdx.x & 3;
    int b = bh >> 4, h = bh & 15;
    int tid = threadIdx.x;
    int s0 = sc * 64;
    int sl = tid >> 2, d0 = (tid & 3) * 16;
    const float* src = kv + (size_t)(b * 256 + s0 + sl) * 2048 + 1024 + (h << 6) + d0;
#pragma unroll
    for (int t = 0; t < 4; ++t) {
        float4 v4 = *(const float4*)(src + t * 4);
        T[sl][d0 + t * 4 + 0] = v4.x;
        T[sl][d0 + t * 4 + 1] = v4.y;
        T[sl][d0 + t * 4 + 2] = v4.z;
        T[sl][d0 + t * 4 + 3] = v4.w;
    }
    __syncthreads();
    int dr = tid >> 2, c0 = (tid & 3) * 16;
    bf16x8 h0, h1;
#pragma unroll
    for (int jj = 0; jj < 8; ++jj) h0[jj] = (__bf16)T[c0 + jj][dr];
#pragma unroll
    for (int jj = 0; jj < 8; ++jj) h1[jj] = (__bf16)T[c0 + 8 + jj][dr];
    size_t base = (size_t)bh * 16384 + (size_t)dr * 256 + s0 + c0;
    *(bf16x8*)(vt + base) = h0;
    *(bf16x8*)(vt + base + 8) = h1;
}

// ---------------- MFMA attention (plain bf16) ----------------
__global__ __launch_bounds__(256) void attn_mfma(const __bf16* __restrict__ qb,
                                                 const __bf16* __restrict__ kb,
                                                 const __bf16* __restrict__ vtb,
                                                 __bf16* __restrict__ ob) {
    __shared__ __bf16 P[64 * 264];
    __shared__ float wred[8][64];  // rows 0-3: wave max; 4-7: wave sum
    __shared__ float denomL[64];
    __shared__ __bf16 Ot[64 * 72];

    int wg = blockIdx.x;
    int swz = (wg & 7) * 512 + (wg >> 3);  // XCD-chunked swizzle
    int bh = swz >> 6;
    int qt = swz & 63;
    int b = bh >> 4, h = bh & 15;
    int tid = threadIdx.x;
    int lane = tid & 63;
    int w = tid >> 6;
    int frow = lane & 15;
    int fk = (lane >> 4) * 8;
    int crow = (lane >> 4) * 4;
    int ccol = lane & 15;
    int q0 = qt * 64;
    int wsr = w * 64;

    const __bf16* kh = kb + (size_t)bh * 16384;
    const __bf16* qh = qb + (size_t)h * 262144 + (size_t)q0 * 64;

    f32x4 acc[4][4] = {};  // [m=s-frag][n=q-frag]
#pragma unroll
    for (int ks = 0; ks < 2; ++ks) {
        bf16x8 kf[4];
#pragma unroll
        for (int m = 0; m < 4; ++m)
            kf[m] = *(const bf16x8*)(kh + (wsr + m * 16 + frow) * 64 + ks * 32 + fk);
#pragma unroll
        for (int n = 0; n < 4; ++n) {
            bf16x8 qf = *(const bf16x8*)(qh + (n * 16 + frow) * 64 + ks * 32 + fk);
#pragma unroll
            for (int m = 0; m < 4; ++m)
                acc[m][n] = __builtin_amdgcn_mfma_f32_16x16x32_bf16(kf[m], qf, acc[m][n], 0, 0, 0);
        }
    }
#pragma unroll
    for (int m = 0; m < 4; ++m)
#pragma unroll
        for (int n = 0; n < 4; ++n)
#pragma unroll
            for (int j = 0; j < 4; ++j) acc[m][n][j] *= 0.125f;

    float lm[4];
#pragma unroll
    for (int n = 0; n < 4; ++n) {
        float v = -1e30f;
#pragma unroll
        for (int m = 0; m < 4; ++m)
#pragma unroll
            for (int j = 0; j < 4; ++j) v = fmaxf(v, acc[m][n][j]);
        v = fmaxf(v, __shfl_xor(v, 16));
        v = fmaxf(v, __shfl_xor(v, 32));
        lm[n] = v;
    }
    if (lane < 16) {
#pragma unroll
        for (int n = 0; n < 4; ++n) wred[w][n * 16 + lane] = lm[n];
    }
    __syncthreads();
    float gm[4];
#pragma unroll
    for (int n = 0; n < 4; ++n) {
        int qq = n * 16 + ccol;
        gm[n] = fmaxf(fmaxf(wred[0][qq], wred[1][qq]), fmaxf(wred[2][qq], wred[3][qq]));
    }
    float lsum[4] = {0.f, 0.f, 0.f, 0.f};
#pragma unroll
    for (int m = 0; m < 4; ++m)
#pragma unroll
        for (int n = 0; n < 4; ++n)
#pragma unroll
            for (int j = 0; j < 4; ++j) {
                float p = __expf(acc[m][n][j] - gm[n]);
                acc[m][n][j] = p;
                lsum[n] += p;
            }
#pragma unroll
    for (int n = 0; n < 4; ++n) {
        float v = lsum[n];
        v += __shfl_xor(v, 16);
        v += __shfl_xor(v, 32);
        lsum[n] = v;
    }
    if (lane < 16) {
#pragma unroll
        for (int n = 0; n < 4; ++n) wred[4 + w][n * 16 + lane] = lsum[n];
    }
#pragma unroll
    for (int m = 0; m < 4; ++m)
#pragma unroll
        for (int n = 0; n < 4; ++n) {
            bf16x4 pv;
#pragma unroll
            for (int j = 0; j < 4; ++j) pv[j] = (__bf16)acc[m][n][j];
            *(bf16x4*)(P + (n * 16 + ccol) * 264 + wsr + m * 16 + crow) = pv;
        }
    __syncthreads();
    if (tid < 64)
        denomL[tid] = wred[4][tid] + wred[5][tid] + wred[6][tid] + wred[7][tid];

    const __bf16* vh = vtb + (size_t)bh * 16384;
    f32x4 accO[4] = {};
#pragma unroll
    for (int ks = 0; ks < 8; ++ks) {
        bf16x8 pf = *(const bf16x8*)(P + (w * 16 + frow) * 264 + ks * 32 + fk);
#pragma unroll
        for (int m = 0; m < 4; ++m) {
            bf16x8 vf = *(const bf16x8*)(vh + (m * 16 + frow) * 256 + ks * 32 + fk);
            accO[m] = __builtin_amdgcn_mfma_f32_16x16x32_bf16(vf, pf, accO[m], 0, 0, 0);
        }
    }
    __syncthreads();
    float rd = 1.0f / denomL[w * 16 + ccol];
#pragma unroll
    for (int m = 0; m < 4; ++m) {
        bf16x4 ov;
#pragma unroll
        for (int j = 0; j < 4; ++j) ov[j] = (__bf16)(accO[m][j] * rd);
        *(bf16x4*)(Ot + (w * 16 + ccol) * 72 + m * 16 + crow) = ov;
    }
    __syncthreads();
    {
        int qq = tid >> 2, dc = tid & 3;
        bf16x8 o0 = *(const bf16x8*)(Ot + qq * 72 + dc * 16);
        bf16x8 o1 = *(const bf16x8*)(Ot + qq * 72 + dc * 16 + 8);
        size_t base = (size_t)((b << 12) + q0 + qq) * 1024 + (h << 6) + dc * 16;
        *(bf16x8*)(ob + base) = o0;
        *(bf16x8*)(ob + base + 8) = o1;
    }
}

// ---------------- fp32 -> bf16 conversion ----------------
__global__ __launch_bounds__(256) void cvt_bf16(const float* __restrict__ in,
                                                __bf16* __restrict__ out, int n8) {
    int i = blockIdx.x * 256 + threadIdx.x;
    if (i >= n8) return;
    const float4* p = (const float4*)in + (size_t)i * 2;
    float4 u0 = p[0], u1 = p[1];
    bf16x8 v;
    v[0] = (__bf16)u0.x; v[1] = (__bf16)u0.y; v[2] = (__bf16)u0.z; v[3] = (__bf16)u0.w;
    v[4] = (__bf16)u1.x; v[5] = (__bf16)u1.y; v[6] = (__bf16)u1.z; v[7] = (__bf16)u1.w;
    *((bf16x8*)out + i) = v;
}

// ---------------- LayerNorm stats (bf16 input) ----------------
__global__ __launch_bounds__(256) void ln_stats(const __bf16* __restrict__ ob,
                                                float* __restrict__ mu,
                                                float* __restrict__ rstd) {
    __shared__ float r0[4], r1[4];
    int row = blockIdx.x;
    int tid = threadIdx.x;
    const bf16x4* op = (const bf16x4*)(ob + (size_t)row * 1024);
    bf16x4 v = op[tid];
    float s = 0, sq = 0;
#pragma unroll
    for (int j = 0; j < 4; ++j) { float f = (float)v[j]; s += f; sq += f * f; }
    s = wave_sum(s);
    sq = wave_sum(sq);
    if ((tid & 63) == 0) { r0[tid >> 6] = s; r1[tid >> 6] = sq; }
    __syncthreads();
    if (tid == 0) {
        float S = r0[0] + r0[1] + r0[2] + r0[3];
        float Q = r1[0] + r1[1] + r1[2] + r1[3];
        float m = S * (1.f / 1024.f);
        float var = Q * (1.f / 1024.f) - m * m;
        mu[row] = m;
        rstd[row] = rsqrtf(var + EPS);
    }
}

// ---------------- LN apply -> bf16 f (slice-local) ----------------
__global__ __launch_bounds__(256) void ln_apply(const __bf16* __restrict__ ob,
                                                const float* __restrict__ mu,
                                                const float* __restrict__ rstd,
                                                const float* __restrict__ gamma,
                                                const float* __restrict__ beta,
                                                __bf16* __restrict__ f, int R0) {
    int i = blockIdx.x * 256 + threadIdx.x;
    int row = i >> 7;
    int c8 = (i & 127) * 8;
    int gr = R0 + row;
    float m = mu[gr], rs = rstd[gr];
    bf16x8 ov = *((const bf16x8*)(ob + (size_t)gr * 1024 + c8));
    bf16x8 r;
#pragma unroll
    for (int j = 0; j < 8; ++j) {
        float v = (float)ov[j];
        r[j] = (__bf16)((v - m) * rs * gamma[c8 + j] + beta[c8 + j]);
    }
    *((bf16x8*)(f + (size_t)row * 1024 + c8)) = r;
}

// ---------------- MFMA GEMM1: u = silu(f@W1a^T) * (f@W1b^T) ----------------
// B-tile = 64 rows of W1a (cols) + 64 rows of W1b for the SAME output cols.
// Waves 0,2 accumulate f1; waves 1,3 accumulate f2; f1 exchanged via LDS epilogue.
__global__ __launch_bounds__(256) void gemm1_mfma(const __bf16* __restrict__ A,
                                                  const __bf16* __restrict__ W,
                                                  __bf16* __restrict__ U) {
    __shared__ __align__(16) unsigned char smemraw[32768];
    __bf16* sA = (__bf16*)smemraw;             // [128*64]
    __bf16* sB = (__bf16*)(smemraw + 16384);   // [128*64]; rows 0-63 W1a, 64-127 W1b
    float* sEx = (float*)smemraw;              // epilogue: [128][64] f32
    const int K = 1024;
    int tid = threadIdx.x;
    int bn = blockIdx.x, bm = blockIdx.y;
    int lane = tid & 63;
    int w = tid >> 6;
    int wr = (w >> 1) * 64, wc = (w & 1) * 64;
    f32x4 acc[4][4] = {};
    const __bf16* Ab = A + (size_t)(bm * 128) * K;
    const __bf16* B1b = W + (size_t)(bn * 64) * K;
    const __bf16* B2b = W + (size_t)(3072 + bn * 64) * K;
    int frow = lane & 15, fk = (lane >> 4) * 8;
    for (int k0 = 0; k0 < K; k0 += 64) {
#pragma unroll
        for (int t = 0; t < 4; ++t) {
            int e = (t * 256 + tid) * 8;
            int r = e >> 6, c = e & 63;
            __builtin_amdgcn_global_load_lds(GPTR(Ab + (size_t)r * K + k0 + c), LPTR(sA + e), 16, 0, 0);
        }
#pragma unroll
        for (int t = 0; t < 2; ++t) {
            int e = (t * 256 + tid) * 8;
            int r = e >> 6, c = e & 63;
            __builtin_amdgcn_global_load_lds(GPTR(B1b + (size_t)r * K + k0 + c), LPTR(sB + e), 16, 0, 0);
        }
#pragma unroll
        for (int t = 2; t < 4; ++t) {
            int e = (t * 256 + tid) * 8;
            int r = (e >> 6) - 64, c = e & 63;
            __builtin_amdgcn_global_load_lds(GPTR(B2b + (size_t)r * K + k0 + c), LPTR(sB + e), 16, 0, 0);
        }
        __syncthreads();
#pragma unroll
        for (int ks = 0; ks < 2; ++ks) {
            bf16x8 a[4], b[4];
#pragma unroll
            for (int m = 0; m < 4; ++m)
                a[m] = *(const bf16x8*)(sA + (wr + m * 16 + frow) * 64 + ks * 32 + fk);
#pragma unroll
            for (int n = 0; n < 4; ++n)
                b[n] = *(const bf16x8*)(sB + (wc + n * 16 + frow) * 64 + ks * 32 + fk);
#pragma unroll
            for (int m = 0; m < 4; ++m)
#pragma unroll
                for (int n = 0; n < 4; ++n)
                    acc[m][n] = __builtin_amdgcn_mfma_f32_16x16x32_bf16(a[m], b[n], acc[m][n], 0, 0, 0);
        }
        __syncthreads();
    }
    int crow = (lane >> 4) * 4, ccol = lane & 15;
    // f1 waves (wc==0) publish their acc to LDS
    if ((w & 1) == 0) {
#pragma unroll
        for (int m = 0; m < 4; ++m)
#pragma unroll
            for (int n = 0; n < 4; ++n)
#pragma unroll
                for (int j = 0; j < 4; ++j)
                    sEx[(wr + m * 16 + crow + j) * 64 + n * 16 + ccol] = acc[m][n][j];
    }
    __syncthreads();
    // f2 waves (wc==64) apply SwiGLU and store u
    if (w & 1) {
#pragma unroll
        for (int m = 0; m < 4; ++m)
#pragma unroll
            for (int n = 0; n < 4; ++n)
#pragma unroll
                for (int j = 0; j < 4; ++j) {
                    int row = wr + m * 16 + crow + j;
                    int col = n * 16 + ccol;
                    float f1 = sEx[row * 64 + col];
                    float f2 = acc[m][n][j];
                    float sg = f1 / (1.f + expf(-f1));
                    U[(size_t)(bm * 128 + row) * 3072 + bn * 64 + col] = (__bf16)(sg * f2);
                }
    }
}

// ---------------- MFMA GEMM2: z = o + u@W2^T (in place), 64x128 tile ----------------
__global__ __launch_bounds__(256) void gemm2_mfma(const __bf16* __restrict__ U,
                                                  const __bf16* __restrict__ W2,
                                                  __bf16* __restrict__ Oz) {
    __shared__ __bf16 sA[64 * 64];
    __shared__ __bf16 sB[128 * 64];
    const int K = 3072;
    int tid = threadIdx.x;
    int bn = blockIdx.x, bm = blockIdx.y;
    int lane = tid & 63;
    int w = tid >> 6;
    int wr = (w >> 1) * 32, wc = (w & 1) * 64;
    f32x4 acc[2][4] = {};
    const __bf16* Ab = U + (size_t)(bm * 64) * K;
    const __bf16* Bb = W2 + (size_t)(bn * 128) * K;
    int frow = lane & 15, fk = (lane >> 4) * 8;
    for (int k0 = 0; k0 < K; k0 += 64) {
#pragma unroll
        for (int t = 0; t < 2; ++t) {
            int e = (t * 256 + tid) * 8;
            int r = e >> 6, c = e & 63;
            __builtin_amdgcn_global_load_lds(GPTR(Ab + (size_t)r * K + k0 + c), LPTR(sA + e), 16, 0, 0);
        }
#pragma unroll
        for (int t = 0; t < 4; ++t) {
            int e = (t * 256 + tid) * 8;
            int r = e >> 6, c = e & 63;
            __builtin_amdgcn_global_load_lds(GPTR(Bb + (size_t)r * K + k0 + c), LPTR(sB + e), 16, 0, 0);
        }
        __syncthreads();
#pragma unroll
        for (int ks = 0; ks < 2; ++ks) {
            bf16x8 a[2], b[4];
#pragma unroll
            for (int m = 0; m < 2; ++m)
                a[m] = *(const bf16x8*)(sA + (wr + m * 16 + frow) * 64 + ks * 32 + fk);
#pragma unroll
            for (int n = 0; n < 4; ++n)
                b[n] = *(const bf16x8*)(sB + (wc + n * 16 + frow) * 64 + ks * 32 + fk);
#pragma unroll
            for (int m = 0; m < 2; ++m)
#pragma unroll
                for (int n = 0; n < 4; ++n)
                    acc[m][n] = __builtin_amdgcn_mfma_f32_16x16x32_bf16(a[m], b[n], acc[m][n], 0, 0, 0);
        }
        __syncthreads();
    }
    int crow = (lane >> 4) * 4, ccol = lane & 15;
#pragma unroll
    for (int m = 0; m < 2; ++m)
#pragma unroll
        for (int n = 0; n < 4; ++n)
#pragma unroll
            for (int j = 0; j < 4; ++j) {
                int row = bm * 64 + wr + m * 16 + crow + j;
                int col = bn * 128 + wc + n * 16 + ccol;
                size_t off = (size_t)row * 1024 + col;
                float z = (float)Oz[off] + acc[m][n][j];
                Oz[off] = (__bf16)z;
            }
}

// ---------------- final projection: 4 batch rows per block ----------------
__global__ __launch_bounds__(256) void out_proj4(const __bf16* __restrict__ z,
                                                 const float* __restrict__ ow,
                                                 float* __restrict__ out) {
    __shared__ float red[4][8];
    int c = blockIdx.x;
    int tid = threadIdx.x;
    int a0 = tid * 4;
    const float4* w4 = (const float4*)(ow + (size_t)c * 2048);
    float4 wA = w4[tid * 2];
    float4 wB = w4[tid * 2 + 1];
    float y[8];
#pragma unroll
    for (int jj = 0; jj < 8; ++jj) y[jj] = 0.f;
#pragma unroll
    for (int bb = 0; bb < 4; ++bb) {
        bf16x4 zv = *(const bf16x4*)(z + (size_t)((bb << 12) + c) * 1024 + a0);
        float z0 = (float)zv[0], z1 = (float)zv[1], z2 = (float)zv[2], z3 = (float)zv[3];
        y[2 * bb] += z0 * wA.x + z1 * wA.z + z2 * wB.x + z3 * wB.z;
        y[2 * bb + 1] += z0 * wA.y + z1 * wA.w + z2 * wB.y + z3 * wB.w;
    }
#pragma unroll
    for (int jj = 0; jj < 8; ++jj) y[jj] = wave_sum(y[jj]);
    if ((tid & 63) == 0) {
#pragma unroll
        for (int jj = 0; jj < 8; ++jj) red[tid >> 6][jj] = y[jj];
    }
    __syncthreads();
    if (tid < 4) {
        float a0s = red[0][2 * tid] + red[1][2 * tid] + red[2][2 * tid] + red[3][2 * tid];
        float a1s = red[0][2 * tid + 1] + red[1][2 * tid + 1] + red[2][2 * tid + 1] + red[3][2 * tid + 1];
        out[(size_t)tid * 4096 + c] = a0s / (1.f + expf(-a0s)) * a1s;
    }
}

extern "C" void kernel_launch(void* const* d_in, const int* in_sizes, int n_in,
                              void* d_out, int out_size, void* d_ws, size_t ws_size,
                              hipStream_t stream) {
    const float* x = (const float*)d_in[0];
    const float* cls = (const float*)d_in[1];
    const float* roots = (const float*)d_in[2];
    const float* crw = (const float*)d_in[3];
    const float* ccw = (const float*)d_in[4];
    const float* kv_w = (const float*)d_in[5];
    const float* gamma = (const float*)d_in[6];
    const float* beta = (const float*)d_in[7];
    const float* ffin = (const float*)d_in[8];
    const float* ffout = (const float*)d_in[9];
    const float* ow = (const float*)d_in[10];
    const int* cridx = (const int*)d_in[11];
    const int* ccidx = (const int*)d_in[12];
    float* out = (float*)d_out;

    // Workspace (floats), total 25,165,824 fl = 100.7 MB
    float* ws = (float*)d_ws;
    // Region A [0, 8388608)
    float* q = ws;                              // 4M fl
    float* kvb = ws + 4194304;                  // 2M fl
    __bf16* kbf = (__bf16*)(ws + 6291456);      // 1M bf16
    __bf16* vtb = (__bf16*)(ws + 6815744);      // 1M bf16
    // Region B [8388608, 16777216): o_bf; early: x/kvw hi-lo splits
    __bf16* o_bf = (__bf16*)(ws + 8388608);
    __bf16* xhi = (__bf16*)(ws + 8388608);
    __bf16* xlo = (__bf16*)(ws + 8912896);
    __bf16* kvwhi = (__bf16*)(ws + 9437184);
    __bf16* kvwlo = (__bf16*)(ws + 10485760);
    // Region D [16777216, 25165824)
    float* qdet = ws + 16777216;                // 4M fl (early)
    __bf16* qbf = (__bf16*)(ws + 20971520);     // 4M bf16
    // FFN phase (A + D reuse)
    __bf16* w1bf = (__bf16*)ws;
    __bf16* w2bf = (__bf16*)(ws + 3145728);
    float* mu = ws + 4718592;
    float* rstd = mu + 16384;
    __bf16* fbf = (__bf16*)(ws + 16777216);
    __bf16* u_s = (__bf16*)(ws + 18874368);

    hipMemcpyAsync(q, cls, 4194304 * sizeof(float), hipMemcpyDeviceToDevice, stream);
    scatter1<<<4096, 256, 0, stream>>>(roots, crw, cridx, q);
    hipMemcpyAsync(qdet, q, 4194304 * sizeof(float), hipMemcpyDeviceToDevice, stream);
    scatter2<<<8192, 256, 0, stream>>>(qdet, ccw, ccidx, q);
    rms_q_bf<<<16384, 256, 0, stream>>>(q, qbf);
    split8<<<512, 256, 0, stream>>>(x, xhi, xlo, 131072);
    split8<<<1024, 256, 0, stream>>>(kv_w, kvwhi, kvwlo, 262144);
    gemm_kv_mfma<<<dim3(16, 16), 256, 0, stream>>>(xhi, xlo, kvwhi, kvwlo, kvb);
    kvsplit_bf<<<4096, 256, 0, stream>>>(kvb, kbf);
    vtrans_bf<<<256, 256, 0, stream>>>(kvb, vtb);
    attn_mfma<<<4096, 256, 0, stream>>>(qbf, kbf, vtb, o_bf);

    cvt_bf16<<<3072, 256, 0, stream>>>(ffin, w1bf, 786432);
    cvt_bf16<<<1536, 256, 0, stream>>>(ffout, w2bf, 393216);
    ln_stats<<<16384, 256, 0, stream>>>(o_bf, mu, rstd);
    for (int sl = 0; sl < 4; ++sl) {
        int R0 = sl * 4096;
        ln_apply<<<2048, 256, 0, stream>>>(o_bf, mu, rstd, gamma, beta, fbf, R0);
        gemm1_mfma<<<dim3(48, 32), 256, 0, stream>>>(fbf, w1bf, u_s);
        gemm2_mfma<<<dim3(8, 64), 256, 0, stream>>>(u_s, w2bf, o_bf + (size_t)R0 * 1024);
    }
    out_proj4<<<4096, 256, 0, stream>>>(o_bf, ow, out);
}

// Round 7
// 894.450 us; speedup vs baseline: 7.8692x; 1.0062x over previous
//
#include <hip/hip_runtime.h>
#include <math.h>

#define EPS 1e-5f

typedef __bf16 bf16x8 __attribute__((ext_vector_type(8)));
typedef __bf16 bf16x4 __attribute__((ext_vector_type(4)));
typedef float f32x4 __attribute__((ext_vector_type(4)));

#define GPTR(p) ((const __attribute__((address_space(1))) void*)(p))
#define LPTR(p) ((__attribute__((address_space(3))) void*)(p))

// ---------------- wave reduction helpers ----------------
__device__ __forceinline__ float wave_sum(float v) {
#pragma unroll
    for (int o = 32; o; o >>= 1) v += __shfl_xor(v, o);
    return v;
}

// ---------------- scatter 1 ----------------
__global__ __launch_bounds__(256) void scatter1(const float* __restrict__ roots,
                                                const float* __restrict__ w,
                                                const int* __restrict__ idx,
                                                float* __restrict__ q) {
    int unit = (blockIdx.x << 2) + (threadIdx.x >> 6);
    int lane = threadIdx.x & 63;
    int h = unit >> 10;
    int i = unit & 1023;
    int r = idx[i];
    int c = idx[1024 + i];
    float val = roots[(h * 256 + r) * 64 + lane];
    float ss = wave_sum(val * val);
    float rs = rsqrtf(ss * (1.f / 64.f) + EPS);
    atomicAdd(&q[(h * 4096 + c) * 64 + lane], val * rs * w[(h << 10) + i]);
}

// ---------------- scatter 2 ----------------
__global__ __launch_bounds__(256) void scatter2(const float* __restrict__ qdet,
                                                const float* __restrict__ w,
                                                const int* __restrict__ idx,
                                                float* __restrict__ q) {
    int unit = (blockIdx.x << 2) + (threadIdx.x >> 6);
    int lane = threadIdx.x & 63;
    int h = unit >> 11;
    int i = unit & 2047;
    int c1 = idx[i];
    int c2 = idx[2048 + i];
    float val = qdet[(h * 4096 + c1) * 64 + lane] * w[(h << 11) + i];
    atomicAdd(&q[(h * 4096 + c2) * 64 + lane], val);
}

// ---------------- rmsnorm rows of 64 -> bf16 ----------------
__global__ __launch_bounds__(256) void rms_q_bf(const float* __restrict__ q,
                                                __bf16* __restrict__ qb) {
    int unit = (blockIdx.x << 2) + (threadIdx.x >> 6);
    int lane = threadIdx.x & 63;
    float v = q[(size_t)unit * 64 + lane];
    float ss = wave_sum(v * v);
    float r = v * rsqrtf(ss * (1.f / 64.f) + EPS);
    qb[(size_t)unit * 64 + lane] = (__bf16)r;
}

// ---------------- split fp32 -> hi/lo bf16 (8/thread) ----------------
__global__ __launch_bounds__(256) void split8(const float* __restrict__ in,
                                              __bf16* __restrict__ hi,
                                              __bf16* __restrict__ lo, int n8) {
    int i = blockIdx.x * 256 + threadIdx.x;
    if (i >= n8) return;
    const float4* p = (const float4*)in + (size_t)i * 2;
    float4 u0 = p[0], u1 = p[1];
    float f[8] = {u0.x, u0.y, u0.z, u0.w, u1.x, u1.y, u1.z, u1.w};
    bf16x8 vh, vl;
#pragma unroll
    for (int j = 0; j < 8; ++j) {
        vh[j] = (__bf16)f[j];
        vl[j] = (__bf16)(f[j] - (float)vh[j]);
    }
    *((bf16x8*)hi + i) = vh;
    *((bf16x8*)lo + i) = vl;
}

// ---------------- MFMA GEMM: kv = x @ kv_w^T, hi/lo 3-term, fp32 out ----------------
__global__ __launch_bounds__(256) void gemm_kv_mfma(const __bf16* __restrict__ Ah,
                                                    const __bf16* __restrict__ Al,
                                                    const __bf16* __restrict__ Bh,
                                                    const __bf16* __restrict__ Bl,
                                                    float* __restrict__ Cout) {
    __shared__ __bf16 sAh[64 * 64], sAl[64 * 64];
    __shared__ __bf16 sBh[128 * 64], sBl[128 * 64];
    int tid = threadIdx.x;
    int bn = blockIdx.x, bm = blockIdx.y;
    int lane = tid & 63;
    int w = tid >> 6;
    int wr = (w >> 1) * 32, wc = (w & 1) * 64;
    int frow = lane & 15, fk = (lane >> 4) * 8;
    f32x4 acc[2][4] = {};
    const __bf16* Ahb = Ah + (size_t)(bm * 64) * 1024;
    const __bf16* Alb = Al + (size_t)(bm * 64) * 1024;
    const __bf16* Bhb = Bh + (size_t)(bn * 128) * 1024;
    const __bf16* Blb = Bl + (size_t)(bn * 128) * 1024;
    for (int k0 = 0; k0 < 1024; k0 += 64) {
#pragma unroll
        for (int t = 0; t < 2; ++t) {
            int e = (t * 256 + tid) * 8;
            int r = e >> 6, c = e & 63;
            __builtin_amdgcn_global_load_lds(GPTR(Ahb + (size_t)r * 1024 + k0 + c), LPTR(sAh + e), 16, 0, 0);
            __builtin_amdgcn_global_load_lds(GPTR(Alb + (size_t)r * 1024 + k0 + c), LPTR(sAl + e), 16, 0, 0);
        }
#pragma unroll
        for (int t = 0; t < 4; ++t) {
            int e = (t * 256 + tid) * 8;
            int r = e >> 6, c = e & 63;
            __builtin_amdgcn_global_load_lds(GPTR(Bhb + (size_t)r * 1024 + k0 + c), LPTR(sBh + e), 16, 0, 0);
            __builtin_amdgcn_global_load_lds(GPTR(Blb + (size_t)r * 1024 + k0 + c), LPTR(sBl + e), 16, 0, 0);
        }
        __syncthreads();
#pragma unroll
        for (int ks = 0; ks < 2; ++ks) {
            bf16x8 ah[2], al[2], bh2[4], bl2[4];
#pragma unroll
            for (int m = 0; m < 2; ++m) {
                ah[m] = *(const bf16x8*)(sAh + (wr + m * 16 + frow) * 64 + ks * 32 + fk);
                al[m] = *(const bf16x8*)(sAl + (wr + m * 16 + frow) * 64 + ks * 32 + fk);
            }
#pragma unroll
            for (int n = 0; n < 4; ++n) {
                bh2[n] = *(const bf16x8*)(sBh + (wc + n * 16 + frow) * 64 + ks * 32 + fk);
                bl2[n] = *(const bf16x8*)(sBl + (wc + n * 16 + frow) * 64 + ks * 32 + fk);
            }
#pragma unroll
            for (int m = 0; m < 2; ++m)
#pragma unroll
                for (int n = 0; n < 4; ++n) {
                    acc[m][n] = __builtin_amdgcn_mfma_f32_16x16x32_bf16(ah[m], bh2[n], acc[m][n], 0, 0, 0);
                    acc[m][n] = __builtin_amdgcn_mfma_f32_16x16x32_bf16(ah[m], bl2[n], acc[m][n], 0, 0, 0);
                    acc[m][n] = __builtin_amdgcn_mfma_f32_16x16x32_bf16(al[m], bh2[n], acc[m][n], 0, 0, 0);
                }
        }
        __syncthreads();
    }
    int crow = (lane >> 4) * 4, ccol = lane & 15;
#pragma unroll
    for (int m = 0; m < 2; ++m)
#pragma unroll
        for (int n = 0; n < 4; ++n)
#pragma unroll
            for (int j = 0; j < 4; ++j) {
                int row = bm * 64 + wr + m * 16 + crow + j;
                int col = bn * 128 + wc + n * 16 + ccol;
                Cout[(size_t)row * 2048 + col] = acc[m][n][j];
            }
}

// ---------------- kv split: K rmsnorm -> bf16 [bh][s][64] ----------------
__global__ __launch_bounds__(256) void kvsplit_bf(const float* __restrict__ kv,
                                                  __bf16* __restrict__ kb) {
    int unit = (blockIdx.x << 2) + (threadIdx.x >> 6);  // bh*256+s
    int lane = threadIdx.x & 63;
    int b = unit >> 12;
    int h = (unit >> 8) & 15;
    int s = unit & 255;
    float kvl = kv[(size_t)(b * 256 + s) * 2048 + (h << 6) + lane];
    float ss = wave_sum(kvl * kvl);
    float kn = kvl * rsqrtf(ss * (1.f / 64.f) + EPS);
    kb[(size_t)unit * 64 + lane] = (__bf16)kn;
}

// ---------------- V transpose: kv -> vt bf16 [bh][d=64][s=256] ----------------
__global__ __launch_bounds__(256) void vtrans_bf(const float* __restrict__ kv,
                                                 __bf16* __restrict__ vt) {
    __shared__ float T[64][65];
    int bh = blockIdx.x >> 2;
    int sc = blockIdx.x & 3;
    int b = bh >> 4, h = bh & 15;
    int tid = threadIdx.x;
    int s0 = sc * 64;
    int sl = tid >> 2, d0 = (tid & 3) * 16;
    const float* src = kv + (size_t)(b * 256 + s0 + sl) * 2048 + 1024 + (h << 6) + d0;
#pragma unroll
    for (int t = 0; t < 4; ++t) {
        float4 v4 = *(const float4*)(src + t * 4);
        T[sl][d0 + t * 4 + 0] = v4.x;
        T[sl][d0 + t * 4 + 1] = v4.y;
        T[sl][d0 + t * 4 + 2] = v4.z;
        T[sl][d0 + t * 4 + 3] = v4.w;
    }
    __syncthreads();
    int dr = tid >> 2, c0 = (tid & 3) * 16;
    bf16x8 h0, h1;
#pragma unroll
    for (int jj = 0; jj < 8; ++jj) h0[jj] = (__bf16)T[c0 + jj][dr];
#pragma unroll
    for (int jj = 0; jj < 8; ++jj) h1[jj] = (__bf16)T[c0 + 8 + jj][dr];
    size_t base = (size_t)bh * 16384 + (size_t)dr * 256 + s0 + c0;
    *(bf16x8*)(vt + base) = h0;
    *(bf16x8*)(vt + base + 8) = h1;
}

// ---------------- MFMA attention (plain bf16, no-max softmax) ----------------
// s = q.k/8 with |q|=|k|=8 (RMSNorm) => s <= 8, exp(s) <= e^8: no max subtraction
// needed (softmax is shift-invariant; fp32/bf16 safely hold e^8).
// block: one (b,h) x 64-query tile; 4 waves.
// QK^T: scoresT[s][q] = mfma(K, Q); wave w owns s in [w*64, w*64+64).
// PV:   OT[d][q] = mfma(VT, P); wave w owns q in [w*16, w*16+16).
__global__ __launch_bounds__(256) void attn_mfma(const __bf16* __restrict__ qb,
                                                 const __bf16* __restrict__ kb,
                                                 const __bf16* __restrict__ vtb,
                                                 __bf16* __restrict__ ob) {
    const int PST = 268;  // P row stride in bf16 elems: dword-stride 134 ≡ 6 (mod 32), conflict-free
    __shared__ __align__(16) unsigned char smem[64 * 268 * 2];  // P; Ot aliased on top
    __shared__ float wsum[4][64];
    __shared__ float denomL[64];
    __bf16* P = (__bf16*)smem;
    __bf16* Ot = (__bf16*)smem;  // [64][72], alias (P dead when Ot written)

    int wg = blockIdx.x;
    int swz = (wg & 7) * 512 + (wg >> 3);  // XCD-chunked swizzle
    int bh = swz >> 6;
    int qt = swz & 63;
    int b = bh >> 4, h = bh & 15;
    int tid = threadIdx.x;
    int lane = tid & 63;
    int w = tid >> 6;
    int frow = lane & 15;
    int fk = (lane >> 4) * 8;
    int crow = (lane >> 4) * 4;
    int ccol = lane & 15;
    int q0 = qt * 64;
    int wsr = w * 64;

    const __bf16* kh = kb + (size_t)bh * 16384;
    const __bf16* qh = qb + (size_t)h * 262144 + (size_t)q0 * 64;
    const __bf16* vh = vtb + (size_t)bh * 16384;

    f32x4 acc[4][4] = {};  // [m=s-frag][n=q-frag]
#pragma unroll
    for (int ks = 0; ks < 2; ++ks) {
        bf16x8 kf[4];
#pragma unroll
        for (int m = 0; m < 4; ++m)
            kf[m] = *(const bf16x8*)(kh + (wsr + m * 16 + frow) * 64 + ks * 32 + fk);
#pragma unroll
        for (int n = 0; n < 4; ++n) {
            bf16x8 qf = *(const bf16x8*)(qh + (n * 16 + frow) * 64 + ks * 32 + fk);
#pragma unroll
            for (int m = 0; m < 4; ++m)
                acc[m][n] = __builtin_amdgcn_mfma_f32_16x16x32_bf16(kf[m], qf, acc[m][n], 0, 0, 0);
        }
    }

    // exp (no max needed) + per-wave sum per q
    float lsum[4] = {0.f, 0.f, 0.f, 0.f};
#pragma unroll
    for (int m = 0; m < 4; ++m)
#pragma unroll
        for (int n = 0; n < 4; ++n)
#pragma unroll
            for (int j = 0; j < 4; ++j) {
                float p = __expf(acc[m][n][j] * 0.125f);
                acc[m][n][j] = p;
                lsum[n] += p;
            }
#pragma unroll
    for (int n = 0; n < 4; ++n) {
        float v = lsum[n];
        v += __shfl_xor(v, 16);
        v += __shfl_xor(v, 32);
        lsum[n] = v;
    }
    if (lane < 16) {
#pragma unroll
        for (int n = 0; n < 4; ++n) wsum[w][n * 16 + lane] = lsum[n];
    }
    // write P to LDS [q][PST] as b64 chunks (s-consecutive)
#pragma unroll
    for (int m = 0; m < 4; ++m)
#pragma unroll
        for (int n = 0; n < 4; ++n) {
            bf16x4 pv;
#pragma unroll
            for (int j = 0; j < 4; ++j) pv[j] = (__bf16)acc[m][n][j];
            *(bf16x4*)(P + (n * 16 + ccol) * PST + wsr + m * 16 + crow) = pv;
        }
    // prefetch V ks=0,1 fragments; the barrier's vmcnt drain absorbs the latency
    bf16x8 vpre[2][4];
#pragma unroll
    for (int ks = 0; ks < 2; ++ks)
#pragma unroll
        for (int m = 0; m < 4; ++m)
            vpre[ks][m] = *(const bf16x8*)(vh + (m * 16 + frow) * 256 + ks * 32 + fk);
    __syncthreads();  // B1: P + wsum visible
    if (tid < 64)
        denomL[tid] = wsum[0][tid] + wsum[1][tid] + wsum[2][tid] + wsum[3][tid];

    // PV
    f32x4 accO[4] = {};
#pragma unroll
    for (int ks = 0; ks < 2; ++ks) {
        bf16x8 pf = *(const bf16x8*)(P + (w * 16 + frow) * PST + ks * 32 + fk);
#pragma unroll
        for (int m = 0; m < 4; ++m)
            accO[m] = __builtin_amdgcn_mfma_f32_16x16x32_bf16(vpre[ks][m], pf, accO[m], 0, 0, 0);
    }
#pragma unroll
    for (int ks = 2; ks < 8; ++ks) {
        bf16x8 pf = *(const bf16x8*)(P + (w * 16 + frow) * PST + ks * 32 + fk);
#pragma unroll
        for (int m = 0; m < 4; ++m) {
            bf16x8 vf = *(const bf16x8*)(vh + (m * 16 + frow) * 256 + ks * 32 + fk);
            accO[m] = __builtin_amdgcn_mfma_f32_16x16x32_bf16(vf, pf, accO[m], 0, 0, 0);
        }
    }
    __syncthreads();  // B2: all PV reads done (P dead); denomL visible
    float rd = 1.0f / denomL[w * 16 + ccol];
#pragma unroll
    for (int m = 0; m < 4; ++m) {
        bf16x4 ov;
#pragma unroll
        for (int j = 0; j < 4; ++j) ov[j] = (__bf16)(accO[m][j] * rd);
        *(bf16x4*)(Ot + (w * 16 + ccol) * 72 + m * 16 + crow) = ov;
    }
    __syncthreads();  // B3: Ot visible
    {
        int qq = tid >> 2, dc = tid & 3;
        bf16x8 o0 = *(const bf16x8*)(Ot + qq * 72 + dc * 16);
        bf16x8 o1 = *(const bf16x8*)(Ot + qq * 72 + dc * 16 + 8);
        size_t base = (size_t)((b << 12) + q0 + qq) * 1024 + (h << 6) + dc * 16;
        *(bf16x8*)(ob + base) = o0;
        *(bf16x8*)(ob + base + 8) = o1;
    }
}

// ---------------- fp32 -> bf16 conversion ----------------
__global__ __launch_bounds__(256) void cvt_bf16(const float* __restrict__ in,
                                                __bf16* __restrict__ out, int n8) {
    int i = blockIdx.x * 256 + threadIdx.x;
    if (i >= n8) return;
    const float4* p = (const float4*)in + (size_t)i * 2;
    float4 u0 = p[0], u1 = p[1];
    bf16x8 v;
    v[0] = (__bf16)u0.x; v[1] = (__bf16)u0.y; v[2] = (__bf16)u0.z; v[3] = (__bf16)u0.w;
    v[4] = (__bf16)u1.x; v[5] = (__bf16)u1.y; v[6] = (__bf16)u1.z; v[7] = (__bf16)u1.w;
    *((bf16x8*)out + i) = v;
}

// ---------------- LayerNorm stats (bf16 input) ----------------
__global__ __launch_bounds__(256) void ln_stats(const __bf16* __restrict__ ob,
                                                float* __restrict__ mu,
                                                float* __restrict__ rstd) {
    __shared__ float r0[4], r1[4];
    int row = blockIdx.x;
    int tid = threadIdx.x;
    const bf16x4* op = (const bf16x4*)(ob + (size_t)row * 1024);
    bf16x4 v = op[tid];
    float s = 0, sq = 0;
#pragma unroll
    for (int j = 0; j < 4; ++j) { float f = (float)v[j]; s += f; sq += f * f; }
    s = wave_sum(s);
    sq = wave_sum(sq);
    if ((tid & 63) == 0) { r0[tid >> 6] = s; r1[tid >> 6] = sq; }
    __syncthreads();
    if (tid == 0) {
        float S = r0[0] + r0[1] + r0[2] + r0[3];
        float Q = r1[0] + r1[1] + r1[2] + r1[3];
        float m = S * (1.f / 1024.f);
        float var = Q * (1.f / 1024.f) - m * m;
        mu[row] = m;
        rstd[row] = rsqrtf(var + EPS);
    }
}

// ---------------- LN apply -> bf16 f (slice-local) ----------------
__global__ __launch_bounds__(256) void ln_apply(const __bf16* __restrict__ ob,
                                                const float* __restrict__ mu,
                                                const float* __restrict__ rstd,
                                                const float* __restrict__ gamma,
                                                const float* __restrict__ beta,
                                                __bf16* __restrict__ f, int R0) {
    int i = blockIdx.x * 256 + threadIdx.x;
    int row = i >> 7;
    int c8 = (i & 127) * 8;
    int gr = R0 + row;
    float m = mu[gr], rs = rstd[gr];
    bf16x8 ov = *((const bf16x8*)(ob + (size_t)gr * 1024 + c8));
    bf16x8 r;
#pragma unroll
    for (int j = 0; j < 8; ++j) {
        float v = (float)ov[j];
        r[j] = (__bf16)((v - m) * rs * gamma[c8 + j] + beta[c8 + j]);
    }
    *((bf16x8*)(f + (size_t)row * 1024 + c8)) = r;
}

// ---------------- MFMA GEMM1: u = silu(f@W1a^T) * (f@W1b^T) ----------------
// B-tile = 64 rows of W1a (cols) + 64 rows of W1b for the SAME output cols.
// Waves 0,2 accumulate f1; waves 1,3 accumulate f2; f1 exchanged via LDS epilogue.
__global__ __launch_bounds__(256) void gemm1_mfma(const __bf16* __restrict__ A,
                                                  const __bf16* __restrict__ W,
                                                  __bf16* __restrict__ U) {
    __shared__ __align__(16) unsigned char smemraw[32768];
    __bf16* sA = (__bf16*)smemraw;             // [128*64]
    __bf16* sB = (__bf16*)(smemraw + 16384);   // [128*64]; rows 0-63 W1a, 64-127 W1b
    float* sEx = (float*)smemraw;              // epilogue: [128][64] f32
    const int K = 1024;
    int tid = threadIdx.x;
    int bn = blockIdx.x, bm = blockIdx.y;
    int lane = tid & 63;
    int w = tid >> 6;
    int wr = (w >> 1) * 64, wc = (w & 1) * 64;
    f32x4 acc[4][4] = {};
    const __bf16* Ab = A + (size_t)(bm * 128) * K;
    const __bf16* B1b = W + (size_t)(bn * 64) * K;
    const __bf16* B2b = W + (size_t)(3072 + bn * 64) * K;
    int frow = lane & 15, fk = (lane >> 4) * 8;
    for (int k0 = 0; k0 < K; k0 += 64) {
#pragma unroll
        for (int t = 0; t < 4; ++t) {
            int e = (t * 256 + tid) * 8;
            int r = e >> 6, c = e & 63;
            __builtin_amdgcn_global_load_lds(GPTR(Ab + (size_t)r * K + k0 + c), LPTR(sA + e), 16, 0, 0);
        }
#pragma unroll
        for (int t = 0; t < 2; ++t) {
            int e = (t * 256 + tid) * 8;
            int r = e >> 6, c = e & 63;
            __builtin_amdgcn_global_load_lds(GPTR(B1b + (size_t)r * K + k0 + c), LPTR(sB + e), 16, 0, 0);
        }
#pragma unroll
        for (int t = 2; t < 4; ++t) {
            int e = (t * 256 + tid) * 8;
            int r = (e >> 6) - 64, c = e & 63;
            __builtin_amdgcn_global_load_lds(GPTR(B2b + (size_t)r * K + k0 + c), LPTR(sB + e), 16, 0, 0);
        }
        __syncthreads();
#pragma unroll
        for (int ks = 0; ks < 2; ++ks) {
            bf16x8 a[4], b[4];
#pragma unroll
            for (int m = 0; m < 4; ++m)
                a[m] = *(const bf16x8*)(sA + (wr + m * 16 + frow) * 64 + ks * 32 + fk);
#pragma unroll
            for (int n = 0; n < 4; ++n)
                b[n] = *(const bf16x8*)(sB + (wc + n * 16 + frow) * 64 + ks * 32 + fk);
#pragma unroll
            for (int m = 0; m < 4; ++m)
#pragma unroll
                for (int n = 0; n < 4; ++n)
                    acc[m][n] = __builtin_amdgcn_mfma_f32_16x16x32_bf16(a[m], b[n], acc[m][n], 0, 0, 0);
        }
        __syncthreads();
    }
    int crow = (lane >> 4) * 4, ccol = lane & 15;
    // f1 waves (wc==0) publish their acc to LDS
    if ((w & 1) == 0) {
#pragma unroll
        for (int m = 0; m < 4; ++m)
#pragma unroll
            for (int n = 0; n < 4; ++n)
#pragma unroll
                for (int j = 0; j < 4; ++j)
                    sEx[(wr + m * 16 + crow + j) * 64 + n * 16 + ccol] = acc[m][n][j];
    }
    __syncthreads();
    // f2 waves (wc==64) apply SwiGLU and store u
    if (w & 1) {
#pragma unroll
        for (int m = 0; m < 4; ++m)
#pragma unroll
            for (int n = 0; n < 4; ++n)
#pragma unroll
                for (int j = 0; j < 4; ++j) {
                    int row = wr + m * 16 + crow + j;
                    int col = n * 16 + ccol;
                    float f1 = sEx[row * 64 + col];
                    float f2 = acc[m][n][j];
                    float sg = f1 / (1.f + expf(-f1));
                    U[(size_t)(bm * 128 + row) * 3072 + bn * 64 + col] = (__bf16)(sg * f2);
                }
    }
}

// ---------------- MFMA GEMM2: z = o + u@W2^T (in place), 64x128 tile ----------------
__global__ __launch_bounds__(256) void gemm2_mfma(const __bf16* __restrict__ U,
                                                  const __bf16* __restrict__ W2,
                                                  __bf16* __restrict__ Oz) {
    __shared__ __bf16 sA[64 * 64];
    __shared__ __bf16 sB[128 * 64];
    const int K = 3072;
    int tid = threadIdx.x;
    int bn = blockIdx.x, bm = blockIdx.y;
    int lane = tid & 63;
    int w = tid >> 6;
    int wr = (w >> 1) * 32, wc = (w & 1) * 64;
    f32x4 acc[2][4] = {};
    const __bf16* Ab = U + (size_t)(bm * 64) * K;
    const __bf16* Bb = W2 + (size_t)(bn * 128) * K;
    int frow = lane & 15, fk = (lane >> 4) * 8;
    for (int k0 = 0; k0 < K; k0 += 64) {
#pragma unroll
        for (int t = 0; t < 2; ++t) {
            int e = (t * 256 + tid) * 8;
            int r = e >> 6, c = e & 63;
            __builtin_amdgcn_global_load_lds(GPTR(Ab + (size_t)r * K + k0 + c), LPTR(sA + e), 16, 0, 0);
        }
#pragma unroll
        for (int t = 0; t < 4; ++t) {
            int e = (t * 256 + tid) * 8;
            int r = e >> 6, c = e & 63;
            __builtin_amdgcn_global_load_lds(GPTR(Bb + (size_t)r * K + k0 + c), LPTR(sB + e), 16, 0, 0);
        }
        __syncthreads();
#pragma unroll
        for (int ks = 0; ks < 2; ++ks) {
            bf16x8 a[2], b[4];
#pragma unroll
            for (int m = 0; m < 2; ++m)
                a[m] = *(const bf16x8*)(sA + (wr + m * 16 + frow) * 64 + ks * 32 + fk);
#pragma unroll
            for (int n = 0; n < 4; ++n)
                b[n] = *(const bf16x8*)(sB + (wc + n * 16 + frow) * 64 + ks * 32 + fk);
#pragma unroll
            for (int m = 0; m < 2; ++m)
#pragma unroll
                for (int n = 0; n < 4; ++n)
                    acc[m][n] = __builtin_amdgcn_mfma_f32_16x16x32_bf16(a[m], b[n], acc[m][n], 0, 0, 0);
        }
        __syncthreads();
    }
    int crow = (lane >> 4) * 4, ccol = lane & 15;
#pragma unroll
    for (int m = 0; m < 2; ++m)
#pragma unroll
        for (int n = 0; n < 4; ++n)
#pragma unroll
            for (int j = 0; j < 4; ++j) {
                int row = bm * 64 + wr + m * 16 + crow + j;
                int col = bn * 128 + wc + n * 16 + ccol;
                size_t off = (size_t)row * 1024 + col;
                float z = (float)Oz[off] + acc[m][n][j];
                Oz[off] = (__bf16)z;
            }
}

// ---------------- final projection: 4 batch rows per block ----------------
__global__ __launch_bounds__(256) void out_proj4(const __bf16* __restrict__ z,
                                                 const float* __restrict__ ow,
                                                 float* __restrict__ out) {
    __shared__ float red[4][8];
    int c = blockIdx.x;
    int tid = threadIdx.x;
    int a0 = tid * 4;
    const float4* w4 = (const float4*)(ow + (size_t)c * 2048);
    float4 wA = w4[tid * 2];
    float4 wB = w4[tid * 2 + 1];
    float y[8];
#pragma unroll
    for (int jj = 0; jj < 8; ++jj) y[jj] = 0.f;
#pragma unroll
    for (int bb = 0; bb < 4; ++bb) {
        bf16x4 zv = *(const bf16x4*)(z + (size_t)((bb << 12) + c) * 1024 + a0);
        float z0 = (float)zv[0], z1 = (float)zv[1], z2 = (float)zv[2], z3 = (float)zv[3];
        y[2 * bb] += z0 * wA.x + z1 * wA.z + z2 * wB.x + z3 * wB.z;
        y[2 * bb + 1] += z0 * wA.y + z1 * wA.w + z2 * wB.y + z3 * wB.w;
    }
#pragma unroll
    for (int jj = 0; jj < 8; ++jj) y[jj] = wave_sum(y[jj]);
    if ((tid & 63) == 0) {
#pragma unroll
        for (int jj = 0; jj < 8; ++jj) red[tid >> 6][jj] = y[jj];
    }
    __syncthreads();
    if (tid < 4) {
        float a0s = red[0][2 * tid] + red[1][2 * tid] + red[2][2 * tid] + red[3][2 * tid];
        float a1s = red[0][2 * tid + 1] + red[1][2 * tid + 1] + red[2][2 * tid + 1] + red[3][2 * tid + 1];
        out[(size_t)tid * 4096 + c] = a0s / (1.f + expf(-a0s)) * a1s;
    }
}

extern "C" void kernel_launch(void* const* d_in, const int* in_sizes, int n_in,
                              void* d_out, int out_size, void* d_ws, size_t ws_size,
                              hipStream_t stream) {
    const float* x = (const float*)d_in[0];
    const float* cls = (const float*)d_in[1];
    const float* roots = (const float*)d_in[2];
    const float* crw = (const float*)d_in[3];
    const float* ccw = (const float*)d_in[4];
    const float* kv_w = (const float*)d_in[5];
    const float* gamma = (const float*)d_in[6];
    const float* beta = (const float*)d_in[7];
    const float* ffin = (const float*)d_in[8];
    const float* ffout = (const float*)d_in[9];
    const float* ow = (const float*)d_in[10];
    const int* cridx = (const int*)d_in[11];
    const int* ccidx = (const int*)d_in[12];
    float* out = (float*)d_out;

    // Workspace (floats), total 25,165,824 fl = 100.7 MB
    float* ws = (float*)d_ws;
    // Region A [0, 8388608)
    float* q = ws;                              // 4M fl
    float* kvb = ws + 4194304;                  // 2M fl
    __bf16* kbf = (__bf16*)(ws + 6291456);      // 1M bf16
    __bf16* vtb = (__bf16*)(ws + 6815744);      // 1M bf16
    // Region B [8388608, 16777216): o_bf; early: x/kvw hi-lo splits
    __bf16* o_bf = (__bf16*)(ws + 8388608);
    __bf16* xhi = (__bf16*)(ws + 8388608);
    __bf16* xlo = (__bf16*)(ws + 8912896);
    __bf16* kvwhi = (__bf16*)(ws + 9437184);
    __bf16* kvwlo = (__bf16*)(ws + 10485760);
    // Region D [16777216, 25165824)
    float* qdet = ws + 16777216;                // 4M fl (early)
    __bf16* qbf = (__bf16*)(ws + 20971520);     // 4M bf16
    // FFN phase (A + D reuse)
    __bf16* w1bf = (__bf16*)ws;
    __bf16* w2bf = (__bf16*)(ws + 3145728);
    float* mu = ws + 4718592;
    float* rstd = mu + 16384;
    __bf16* fbf = (__bf16*)(ws + 16777216);
    __bf16* u_s = (__bf16*)(ws + 18874368);

    hipMemcpyAsync(q, cls, 4194304 * sizeof(float), hipMemcpyDeviceToDevice, stream);
    scatter1<<<4096, 256, 0, stream>>>(roots, crw, cridx, q);
    hipMemcpyAsync(qdet, q, 4194304 * sizeof(float), hipMemcpyDeviceToDevice, stream);
    scatter2<<<8192, 256, 0, stream>>>(qdet, ccw, ccidx, q);
    rms_q_bf<<<16384, 256, 0, stream>>>(q, qbf);
    split8<<<512, 256, 0, stream>>>(x, xhi, xlo, 131072);
    split8<<<1024, 256, 0, stream>>>(kv_w, kvwhi, kvwlo, 262144);
    gemm_kv_mfma<<<dim3(16, 16), 256, 0, stream>>>(xhi, xlo, kvwhi, kvwlo, kvb);
    kvsplit_bf<<<4096, 256, 0, stream>>>(kvb, kbf);
    vtrans_bf<<<256, 256, 0, stream>>>(kvb, vtb);
    attn_mfma<<<4096, 256, 0, stream>>>(qbf, kbf, vtb, o_bf);

    cvt_bf16<<<3072, 256, 0, stream>>>(ffin, w1bf, 786432);
    cvt_bf16<<<1536, 256, 0, stream>>>(ffout, w2bf, 393216);
    ln_stats<<<16384, 256, 0, stream>>>(o_bf, mu, rstd);
    for (int sl = 0; sl < 4; ++sl) {
        int R0 = sl * 4096;
        ln_apply<<<2048, 256, 0, stream>>>(o_bf, mu, rstd, gamma, beta, fbf, R0);
        gemm1_mfma<<<dim3(48, 32), 256, 0, stream>>>(fbf, w1bf, u_s);
        gemm2_mfma<<<dim3(8, 64), 256, 0, stream>>>(u_s, w2bf, o_bf + (size_t)R0 * 1024);
    }
    out_proj4<<<4096, 256, 0, stream>>>(o_bf, ow, out);
}

// Round 8
// 884.977 us; speedup vs baseline: 7.9534x; 1.0107x over previous
//
#include <hip/hip_runtime.h>
#include <math.h>

#define EPS 1e-5f

typedef __bf16 bf16x8 __attribute__((ext_vector_type(8)));
typedef __bf16 bf16x4 __attribute__((ext_vector_type(4)));
typedef float f32x4 __attribute__((ext_vector_type(4)));

#define GPTR(p) ((const __attribute__((address_space(1))) void*)(p))
#define LPTR(p) ((__attribute__((address_space(3))) void*)(p))

// ---------------- wave reduction helpers ----------------
__device__ __forceinline__ float wave_sum(float v) {
#pragma unroll
    for (int o = 32; o; o >>= 1) v += __shfl_xor(v, o);
    return v;
}

// ---------------- scatter 1 ----------------
__global__ __launch_bounds__(256) void scatter1(const float* __restrict__ roots,
                                                const float* __restrict__ w,
                                                const int* __restrict__ idx,
                                                float* __restrict__ q) {
    int unit = (blockIdx.x << 2) + (threadIdx.x >> 6);
    int lane = threadIdx.x & 63;
    int h = unit >> 10;
    int i = unit & 1023;
    int r = idx[i];
    int c = idx[1024 + i];
    float val = roots[(h * 256 + r) * 64 + lane];
    float ss = wave_sum(val * val);
    float rs = rsqrtf(ss * (1.f / 64.f) + EPS);
    atomicAdd(&q[(h * 4096 + c) * 64 + lane], val * rs * w[(h << 10) + i]);
}

// ---------------- scatter 2 ----------------
__global__ __launch_bounds__(256) void scatter2(const float* __restrict__ qdet,
                                                const float* __restrict__ w,
                                                const int* __restrict__ idx,
                                                float* __restrict__ q) {
    int unit = (blockIdx.x << 2) + (threadIdx.x >> 6);
    int lane = threadIdx.x & 63;
    int h = unit >> 11;
    int i = unit & 2047;
    int c1 = idx[i];
    int c2 = idx[2048 + i];
    float val = qdet[(h * 4096 + c1) * 64 + lane] * w[(h << 11) + i];
    atomicAdd(&q[(h * 4096 + c2) * 64 + lane], val);
}

// ---------------- rmsnorm rows of 64 -> bf16 ----------------
__global__ __launch_bounds__(256) void rms_q_bf(const float* __restrict__ q,
                                                __bf16* __restrict__ qb) {
    int unit = (blockIdx.x << 2) + (threadIdx.x >> 6);
    int lane = threadIdx.x & 63;
    float v = q[(size_t)unit * 64 + lane];
    float ss = wave_sum(v * v);
    float r = v * rsqrtf(ss * (1.f / 64.f) + EPS);
    qb[(size_t)unit * 64 + lane] = (__bf16)r;
}

// ---------------- split fp32 -> hi/lo bf16 (8/thread) ----------------
__global__ __launch_bounds__(256) void split8(const float* __restrict__ in,
                                              __bf16* __restrict__ hi,
                                              __bf16* __restrict__ lo, int n8) {
    int i = blockIdx.x * 256 + threadIdx.x;
    if (i >= n8) return;
    const float4* p = (const float4*)in + (size_t)i * 2;
    float4 u0 = p[0], u1 = p[1];
    float f[8] = {u0.x, u0.y, u0.z, u0.w, u1.x, u1.y, u1.z, u1.w};
    bf16x8 vh, vl;
#pragma unroll
    for (int j = 0; j < 8; ++j) {
        vh[j] = (__bf16)f[j];
        vl[j] = (__bf16)(f[j] - (float)vh[j]);
    }
    *((bf16x8*)hi + i) = vh;
    *((bf16x8*)lo + i) = vl;
}

// ---------------- MFMA GEMM: kv = x @ kv_w^T, hi/lo 3-term, fp32 out ----------------
// BM=32, BN=128, BK=64; grid (16,32) = 512 blocks = 2/CU
__global__ __launch_bounds__(256) void gemm_kv_mfma(const __bf16* __restrict__ Ah,
                                                    const __bf16* __restrict__ Al,
                                                    const __bf16* __restrict__ Bh,
                                                    const __bf16* __restrict__ Bl,
                                                    float* __restrict__ Cout) {
    __shared__ __bf16 sAh[32 * 64], sAl[32 * 64];
    __shared__ __bf16 sBh[128 * 64], sBl[128 * 64];
    int tid = threadIdx.x;
    int bn = blockIdx.x, bm = blockIdx.y;
    int lane = tid & 63;
    int w = tid >> 6;
    int wr = (w >> 1) * 16, wc = (w & 1) * 64;
    int frow = lane & 15, fk = (lane >> 4) * 8;
    f32x4 acc[4] = {};
    const __bf16* Ahb = Ah + (size_t)(bm * 32) * 1024;
    const __bf16* Alb = Al + (size_t)(bm * 32) * 1024;
    const __bf16* Bhb = Bh + (size_t)(bn * 128) * 1024;
    const __bf16* Blb = Bl + (size_t)(bn * 128) * 1024;
    for (int k0 = 0; k0 < 1024; k0 += 64) {
        {
            int e = tid * 8;
            int r = e >> 6, c = e & 63;
            __builtin_amdgcn_global_load_lds(GPTR(Ahb + (size_t)r * 1024 + k0 + c), LPTR(sAh + e), 16, 0, 0);
            __builtin_amdgcn_global_load_lds(GPTR(Alb + (size_t)r * 1024 + k0 + c), LPTR(sAl + e), 16, 0, 0);
        }
#pragma unroll
        for (int t = 0; t < 4; ++t) {
            int e = (t * 256 + tid) * 8;
            int r = e >> 6, c = e & 63;
            __builtin_amdgcn_global_load_lds(GPTR(Bhb + (size_t)r * 1024 + k0 + c), LPTR(sBh + e), 16, 0, 0);
            __builtin_amdgcn_global_load_lds(GPTR(Blb + (size_t)r * 1024 + k0 + c), LPTR(sBl + e), 16, 0, 0);
        }
        __syncthreads();
#pragma unroll
        for (int ks = 0; ks < 2; ++ks) {
            bf16x8 ah, al, bh2[4], bl2[4];
            ah = *(const bf16x8*)(sAh + (wr + frow) * 64 + ks * 32 + fk);
            al = *(const bf16x8*)(sAl + (wr + frow) * 64 + ks * 32 + fk);
#pragma unroll
            for (int n = 0; n < 4; ++n) {
                bh2[n] = *(const bf16x8*)(sBh + (wc + n * 16 + frow) * 64 + ks * 32 + fk);
                bl2[n] = *(const bf16x8*)(sBl + (wc + n * 16 + frow) * 64 + ks * 32 + fk);
            }
#pragma unroll
            for (int n = 0; n < 4; ++n) {
                acc[n] = __builtin_amdgcn_mfma_f32_16x16x32_bf16(ah, bh2[n], acc[n], 0, 0, 0);
                acc[n] = __builtin_amdgcn_mfma_f32_16x16x32_bf16(ah, bl2[n], acc[n], 0, 0, 0);
                acc[n] = __builtin_amdgcn_mfma_f32_16x16x32_bf16(al, bh2[n], acc[n], 0, 0, 0);
            }
        }
        __syncthreads();
    }
    int crow = (lane >> 4) * 4, ccol = lane & 15;
#pragma unroll
    for (int n = 0; n < 4; ++n)
#pragma unroll
        for (int j = 0; j < 4; ++j) {
            int row = bm * 32 + wr + crow + j;
            int col = bn * 128 + wc + n * 16 + ccol;
            Cout[(size_t)row * 2048 + col] = acc[n][j];
        }
}

// ---------------- kv split: K rmsnorm -> bf16 [bh][s][64] ----------------
__global__ __launch_bounds__(256) void kvsplit_bf(const float* __restrict__ kv,
                                                  __bf16* __restrict__ kb) {
    int unit = (blockIdx.x << 2) + (threadIdx.x >> 6);  // bh*256+s
    int lane = threadIdx.x & 63;
    int b = unit >> 12;
    int h = (unit >> 8) & 15;
    int s = unit & 255;
    float kvl = kv[(size_t)(b * 256 + s) * 2048 + (h << 6) + lane];
    float ss = wave_sum(kvl * kvl);
    float kn = kvl * rsqrtf(ss * (1.f / 64.f) + EPS);
    kb[(size_t)unit * 64 + lane] = (__bf16)kn;
}

// ---------------- V transpose: kv -> vt bf16 [bh][d=64][s=256] ----------------
__global__ __launch_bounds__(256) void vtrans_bf(const float* __restrict__ kv,
                                                 __bf16* __restrict__ vt) {
    __shared__ float T[64][65];
    int bh = blockIdx.x >> 2;
    int sc = blockIdx.x & 3;
    int b = bh >> 4, h = bh & 15;
    int tid = threadIdx.x;
    int s0 = sc * 64;
    int sl = tid >> 2, d0 = (tid & 3) * 16;
    const float* src = kv + (size_t)(b * 256 + s0 + sl) * 2048 + 1024 + (h << 6) + d0;
#pragma unroll
    for (int t = 0; t < 4; ++t) {
        float4 v4 = *(const float4*)(src + t * 4);
        T[sl][d0 + t * 4 + 0] = v4.x;
        T[sl][d0 + t * 4 + 1] = v4.y;
        T[sl][d0 + t * 4 + 2] = v4.z;
        T[sl][d0 + t * 4 + 3] = v4.w;
    }
    __syncthreads();
    int dr = tid >> 2, c0 = (tid & 3) * 16;
    bf16x8 h0, h1;
#pragma unroll
    for (int jj = 0; jj < 8; ++jj) h0[jj] = (__bf16)T[c0 + jj][dr];
#pragma unroll
    for (int jj = 0; jj < 8; ++jj) h1[jj] = (__bf16)T[c0 + 8 + jj][dr];
    size_t base = (size_t)bh * 16384 + (size_t)dr * 256 + s0 + c0;
    *(bf16x8*)(vt + base) = h0;
    *(bf16x8*)(vt + base + 8) = h1;
}

// ---------------- MFMA attention (plain bf16, no-max softmax, 4 q-tiles/block) --------
// s = q.k/8 with |q|=|k|=8 (RMSNorm) => s <= 8, exp(s) <= e^8: no max subtraction.
// grid 1024: one block per (b,h, 4-tile q-group); 4 blocks/CU (one residency round).
// QK^T: scoresT[s][q] = mfma(K, Q); wave w owns s in [w*64, w*64+64).
// PV:   OT[d][q] = mfma(VT, P); wave w owns q in [w*16, w*16+16).
__global__ __launch_bounds__(256) void attn_mfma(const __bf16* __restrict__ qb,
                                                 const __bf16* __restrict__ kb,
                                                 const __bf16* __restrict__ vtb,
                                                 __bf16* __restrict__ ob) {
    const int PST = 268;  // P row stride (bf16): dword-stride 134 ≡ 6 (mod 32), conflict-free
    __shared__ __align__(16) unsigned char smem[64 * 268 * 2];  // P; Ot aliased on top
    __shared__ float wsum[4][64];
    __shared__ float denomL[64];
    __bf16* P = (__bf16*)smem;
    __bf16* Ot = (__bf16*)smem;  // [64][72] alias (hazard guarded by B0)

    int wg = blockIdx.x;
    int swz = (wg & 7) * 128 + (wg >> 3);  // XCD-chunked swizzle over 1024 blocks
    int bh = swz >> 4;
    int qg = swz & 15;
    int b = bh >> 4, h = bh & 15;
    int tid = threadIdx.x;
    int lane = tid & 63;
    int w = tid >> 6;
    int frow = lane & 15;
    int fk = (lane >> 4) * 8;
    int crow = (lane >> 4) * 4;
    int ccol = lane & 15;
    int wsr = w * 64;

    const __bf16* kh = kb + (size_t)bh * 16384;
    const __bf16* vh = vtb + (size_t)bh * 16384;

    for (int t = 0; t < 4; ++t) {
        int q0 = qg * 256 + t * 64;
        const __bf16* qh = qb + (size_t)h * 262144 + (size_t)q0 * 64;

        f32x4 acc[4][4] = {};  // [m=s-frag][n=q-frag]
#pragma unroll
        for (int ks = 0; ks < 2; ++ks) {
            bf16x8 kf[4];
#pragma unroll
            for (int m = 0; m < 4; ++m)
                kf[m] = *(const bf16x8*)(kh + (wsr + m * 16 + frow) * 64 + ks * 32 + fk);
#pragma unroll
            for (int n = 0; n < 4; ++n) {
                bf16x8 qf = *(const bf16x8*)(qh + (n * 16 + frow) * 64 + ks * 32 + fk);
#pragma unroll
                for (int m = 0; m < 4; ++m)
                    acc[m][n] = __builtin_amdgcn_mfma_f32_16x16x32_bf16(kf[m], qf, acc[m][n], 0, 0, 0);
            }
        }

        // exp (no max needed) + per-wave sum per q
        float lsum[4] = {0.f, 0.f, 0.f, 0.f};
#pragma unroll
        for (int m = 0; m < 4; ++m)
#pragma unroll
            for (int n = 0; n < 4; ++n)
#pragma unroll
                for (int j = 0; j < 4; ++j) {
                    float p = __expf(acc[m][n][j] * 0.125f);
                    acc[m][n][j] = p;
                    lsum[n] += p;
                }
#pragma unroll
        for (int n = 0; n < 4; ++n) {
            float v = lsum[n];
            v += __shfl_xor(v, 16);
            v += __shfl_xor(v, 32);
            lsum[n] = v;
        }

        if (t) __syncthreads();  // B0: prior tile's Ot reads done before P/wsum overwrite

        if (lane < 16) {
#pragma unroll
            for (int n = 0; n < 4; ++n) wsum[w][n * 16 + lane] = lsum[n];
        }
        // write P to LDS [q][PST] as b64 chunks (s-consecutive)
#pragma unroll
        for (int m = 0; m < 4; ++m)
#pragma unroll
            for (int n = 0; n < 4; ++n) {
                bf16x4 pv;
#pragma unroll
                for (int j = 0; j < 4; ++j) pv[j] = (__bf16)acc[m][n][j];
                *(bf16x4*)(P + (n * 16 + ccol) * PST + wsr + m * 16 + crow) = pv;
            }
        // prefetch V ks=0,1 fragments (L1-hot after tile 0)
        bf16x8 vpre[2][4];
#pragma unroll
        for (int ks = 0; ks < 2; ++ks)
#pragma unroll
            for (int m = 0; m < 4; ++m)
                vpre[ks][m] = *(const bf16x8*)(vh + (m * 16 + frow) * 256 + ks * 32 + fk);
        __syncthreads();  // B1: P + wsum visible
        if (tid < 64)
            denomL[tid] = wsum[0][tid] + wsum[1][tid] + wsum[2][tid] + wsum[3][tid];

        // PV
        f32x4 accO[4] = {};
#pragma unroll
        for (int ks = 0; ks < 2; ++ks) {
            bf16x8 pf = *(const bf16x8*)(P + (w * 16 + frow) * PST + ks * 32 + fk);
#pragma unroll
            for (int m = 0; m < 4; ++m)
                accO[m] = __builtin_amdgcn_mfma_f32_16x16x32_bf16(vpre[ks][m], pf, accO[m], 0, 0, 0);
        }
#pragma unroll
        for (int ks = 2; ks < 8; ++ks) {
            bf16x8 pf = *(const bf16x8*)(P + (w * 16 + frow) * PST + ks * 32 + fk);
#pragma unroll
            for (int m = 0; m < 4; ++m) {
                bf16x8 vf = *(const bf16x8*)(vh + (m * 16 + frow) * 256 + ks * 32 + fk);
                accO[m] = __builtin_amdgcn_mfma_f32_16x16x32_bf16(vf, pf, accO[m], 0, 0, 0);
            }
        }
        __syncthreads();  // B2: all PV reads of P done; denomL visible
        float rd = 1.0f / denomL[w * 16 + ccol];
#pragma unroll
        for (int m = 0; m < 4; ++m) {
            bf16x4 ov;
#pragma unroll
            for (int j = 0; j < 4; ++j) ov[j] = (__bf16)(accO[m][j] * rd);
            *(bf16x4*)(Ot + (w * 16 + ccol) * 72 + m * 16 + crow) = ov;
        }
        __syncthreads();  // B3: Ot visible
        {
            int qq = tid >> 2, dc = tid & 3;
            bf16x8 o0 = *(const bf16x8*)(Ot + qq * 72 + dc * 16);
            bf16x8 o1 = *(const bf16x8*)(Ot + qq * 72 + dc * 16 + 8);
            size_t base = (size_t)((b << 12) + q0 + qq) * 1024 + (h << 6) + dc * 16;
            *(bf16x8*)(ob + base) = o0;
            *(bf16x8*)(ob + base + 8) = o1;
        }
    }
}

// ---------------- fp32 -> bf16 conversion ----------------
__global__ __launch_bounds__(256) void cvt_bf16(const float* __restrict__ in,
                                                __bf16* __restrict__ out, int n8) {
    int i = blockIdx.x * 256 + threadIdx.x;
    if (i >= n8) return;
    const float4* p = (const float4*)in + (size_t)i * 2;
    float4 u0 = p[0], u1 = p[1];
    bf16x8 v;
    v[0] = (__bf16)u0.x; v[1] = (__bf16)u0.y; v[2] = (__bf16)u0.z; v[3] = (__bf16)u0.w;
    v[4] = (__bf16)u1.x; v[5] = (__bf16)u1.y; v[6] = (__bf16)u1.z; v[7] = (__bf16)u1.w;
    *((bf16x8*)out + i) = v;
}

// ---------------- LayerNorm stats (bf16 input) ----------------
__global__ __launch_bounds__(256) void ln_stats(const __bf16* __restrict__ ob,
                                                float* __restrict__ mu,
                                                float* __restrict__ rstd) {
    __shared__ float r0[4], r1[4];
    int row = blockIdx.x;
    int tid = threadIdx.x;
    const bf16x4* op = (const bf16x4*)(ob + (size_t)row * 1024);
    bf16x4 v = op[tid];
    float s = 0, sq = 0;
#pragma unroll
    for (int j = 0; j < 4; ++j) { float f = (float)v[j]; s += f; sq += f * f; }
    s = wave_sum(s);
    sq = wave_sum(sq);
    if ((tid & 63) == 0) { r0[tid >> 6] = s; r1[tid >> 6] = sq; }
    __syncthreads();
    if (tid == 0) {
        float S = r0[0] + r0[1] + r0[2] + r0[3];
        float Q = r1[0] + r1[1] + r1[2] + r1[3];
        float m = S * (1.f / 1024.f);
        float var = Q * (1.f / 1024.f) - m * m;
        mu[row] = m;
        rstd[row] = rsqrtf(var + EPS);
    }
}

// ---------------- LN apply -> bf16 f (slice-local) ----------------
__global__ __launch_bounds__(256) void ln_apply(const __bf16* __restrict__ ob,
                                                const float* __restrict__ mu,
                                                const float* __restrict__ rstd,
                                                const float* __restrict__ gamma,
                                                const float* __restrict__ beta,
                                                __bf16* __restrict__ f, int R0) {
    int i = blockIdx.x * 256 + threadIdx.x;
    int row = i >> 7;
    int c8 = (i & 127) * 8;
    int gr = R0 + row;
    float m = mu[gr], rs = rstd[gr];
    bf16x8 ov = *((const bf16x8*)(ob + (size_t)gr * 1024 + c8));
    bf16x8 r;
#pragma unroll
    for (int j = 0; j < 8; ++j) {
        float v = (float)ov[j];
        r[j] = (__bf16)((v - m) * rs * gamma[c8 + j] + beta[c8 + j]);
    }
    *((bf16x8*)(f + (size_t)row * 1024 + c8)) = r;
}

// ---------------- MFMA GEMM1: u = silu(f@W1a^T) * (f@W1b^T) ----------------
// B-tile = 64 rows of W1a + 64 rows of W1b (same output cols).
// Waves 0,2 accumulate f1; waves 1,3 accumulate f2; f1 exchanged via LDS epilogue.
__global__ __launch_bounds__(256) void gemm1_mfma(const __bf16* __restrict__ A,
                                                  const __bf16* __restrict__ W,
                                                  __bf16* __restrict__ U) {
    __shared__ __align__(16) unsigned char smemraw[32768];
    __bf16* sA = (__bf16*)smemraw;             // [128*64]
    __bf16* sB = (__bf16*)(smemraw + 16384);   // [128*64]; rows 0-63 W1a, 64-127 W1b
    float* sEx = (float*)smemraw;              // epilogue: [128][64] f32
    const int K = 1024;
    int tid = threadIdx.x;
    int bn = blockIdx.x, bm = blockIdx.y;
    int lane = tid & 63;
    int w = tid >> 6;
    int wr = (w >> 1) * 64, wc = (w & 1) * 64;
    f32x4 acc[4][4] = {};
    const __bf16* Ab = A + (size_t)(bm * 128) * K;
    const __bf16* B1b = W + (size_t)(bn * 64) * K;
    const __bf16* B2b = W + (size_t)(3072 + bn * 64) * K;
    int frow = lane & 15, fk = (lane >> 4) * 8;
    for (int k0 = 0; k0 < K; k0 += 64) {
#pragma unroll
        for (int t = 0; t < 4; ++t) {
            int e = (t * 256 + tid) * 8;
            int r = e >> 6, c = e & 63;
            __builtin_amdgcn_global_load_lds(GPTR(Ab + (size_t)r * K + k0 + c), LPTR(sA + e), 16, 0, 0);
        }
#pragma unroll
        for (int t = 0; t < 2; ++t) {
            int e = (t * 256 + tid) * 8;
            int r = e >> 6, c = e & 63;
            __builtin_amdgcn_global_load_lds(GPTR(B1b + (size_t)r * K + k0 + c), LPTR(sB + e), 16, 0, 0);
        }
#pragma unroll
        for (int t = 2; t < 4; ++t) {
            int e = (t * 256 + tid) * 8;
            int r = (e >> 6) - 64, c = e & 63;
            __builtin_amdgcn_global_load_lds(GPTR(B2b + (size_t)r * K + k0 + c), LPTR(sB + e), 16, 0, 0);
        }
        __syncthreads();
#pragma unroll
        for (int ks = 0; ks < 2; ++ks) {
            bf16x8 a[4], b[4];
#pragma unroll
            for (int m = 0; m < 4; ++m)
                a[m] = *(const bf16x8*)(sA + (wr + m * 16 + frow) * 64 + ks * 32 + fk);
#pragma unroll
            for (int n = 0; n < 4; ++n)
                b[n] = *(const bf16x8*)(sB + (wc + n * 16 + frow) * 64 + ks * 32 + fk);
#pragma unroll
            for (int m = 0; m < 4; ++m)
#pragma unroll
                for (int n = 0; n < 4; ++n)
                    acc[m][n] = __builtin_amdgcn_mfma_f32_16x16x32_bf16(a[m], b[n], acc[m][n], 0, 0, 0);
        }
        __syncthreads();
    }
    int crow = (lane >> 4) * 4, ccol = lane & 15;
    if ((w & 1) == 0) {
#pragma unroll
        for (int m = 0; m < 4; ++m)
#pragma unroll
            for (int n = 0; n < 4; ++n)
#pragma unroll
                for (int j = 0; j < 4; ++j)
                    sEx[(wr + m * 16 + crow + j) * 64 + n * 16 + ccol] = acc[m][n][j];
    }
    __syncthreads();
    if (w & 1) {
#pragma unroll
        for (int m = 0; m < 4; ++m)
#pragma unroll
            for (int n = 0; n < 4; ++n)
#pragma unroll
                for (int j = 0; j < 4; ++j) {
                    int row = wr + m * 16 + crow + j;
                    int col = n * 16 + ccol;
                    float f1 = sEx[row * 64 + col];
                    float f2 = acc[m][n][j];
                    float sg = f1 / (1.f + expf(-f1));
                    U[(size_t)(bm * 128 + row) * 3072 + bn * 64 + col] = (__bf16)(sg * f2);
                }
    }
}

// ---------------- MFMA GEMM2: z = o + u@W2^T (in place), 64x128 tile ----------------
__global__ __launch_bounds__(256) void gemm2_mfma(const __bf16* __restrict__ U,
                                                  const __bf16* __restrict__ W2,
                                                  __bf16* __restrict__ Oz) {
    __shared__ __bf16 sA[64 * 64];
    __shared__ __bf16 sB[128 * 64];
    const int K = 3072;
    int tid = threadIdx.x;
    int bn = blockIdx.x, bm = blockIdx.y;
    int lane = tid & 63;
    int w = tid >> 6;
    int wr = (w >> 1) * 32, wc = (w & 1) * 64;
    f32x4 acc[2][4] = {};
    const __bf16* Ab = U + (size_t)(bm * 64) * K;
    const __bf16* Bb = W2 + (size_t)(bn * 128) * K;
    int frow = lane & 15, fk = (lane >> 4) * 8;
    for (int k0 = 0; k0 < K; k0 += 64) {
#pragma unroll
        for (int t = 0; t < 2; ++t) {
            int e = (t * 256 + tid) * 8;
            int r = e >> 6, c = e & 63;
            __builtin_amdgcn_global_load_lds(GPTR(Ab + (size_t)r * K + k0 + c), LPTR(sA + e), 16, 0, 0);
        }
#pragma unroll
        for (int t = 0; t < 4; ++t) {
            int e = (t * 256 + tid) * 8;
            int r = e >> 6, c = e & 63;
            __builtin_amdgcn_global_load_lds(GPTR(Bb + (size_t)r * K + k0 + c), LPTR(sB + e), 16, 0, 0);
        }
        __syncthreads();
#pragma unroll
        for (int ks = 0; ks < 2; ++ks) {
            bf16x8 a[2], b[4];
#pragma unroll
            for (int m = 0; m < 2; ++m)
                a[m] = *(const bf16x8*)(sA + (wr + m * 16 + frow) * 64 + ks * 32 + fk);
#pragma unroll
            for (int n = 0; n < 4; ++n)
                b[n] = *(const bf16x8*)(sB + (wc + n * 16 + frow) * 64 + ks * 32 + fk);
#pragma unroll
            for (int m = 0; m < 2; ++m)
#pragma unroll
                for (int n = 0; n < 4; ++n)
                    acc[m][n] = __builtin_amdgcn_mfma_f32_16x16x32_bf16(a[m], b[n], acc[m][n], 0, 0, 0);
        }
        __syncthreads();
    }
    int crow = (lane >> 4) * 4, ccol = lane & 15;
#pragma unroll
    for (int m = 0; m < 2; ++m)
#pragma unroll
        for (int n = 0; n < 4; ++n)
#pragma unroll
            for (int j = 0; j < 4; ++j) {
                int row = bm * 64 + wr + m * 16 + crow + j;
                int col = bn * 128 + wc + n * 16 + ccol;
                size_t off = (size_t)row * 1024 + col;
                float z = (float)Oz[off] + acc[m][n][j];
                Oz[off] = (__bf16)z;
            }
}

// ---------------- final projection: 4 batch rows per block ----------------
__global__ __launch_bounds__(256) void out_proj4(const __bf16* __restrict__ z,
                                                 const float* __restrict__ ow,
                                                 float* __restrict__ out) {
    __shared__ float red[4][8];
    int c = blockIdx.x;
    int tid = threadIdx.x;
    int a0 = tid * 4;
    const float4* w4 = (const float4*)(ow + (size_t)c * 2048);
    float4 wA = w4[tid * 2];
    float4 wB = w4[tid * 2 + 1];
    float y[8];
#pragma unroll
    for (int jj = 0; jj < 8; ++jj) y[jj] = 0.f;
#pragma unroll
    for (int bb = 0; bb < 4; ++bb) {
        bf16x4 zv = *(const bf16x4*)(z + (size_t)((bb << 12) + c) * 1024 + a0);
        float z0 = (float)zv[0], z1 = (float)zv[1], z2 = (float)zv[2], z3 = (float)zv[3];
        y[2 * bb] += z0 * wA.x + z1 * wA.z + z2 * wB.x + z3 * wB.z;
        y[2 * bb + 1] += z0 * wA.y + z1 * wA.w + z2 * wB.y + z3 * wB.w;
    }
#pragma unroll
    for (int jj = 0; jj < 8; ++jj) y[jj] = wave_sum(y[jj]);
    if ((tid & 63) == 0) {
#pragma unroll
        for (int jj = 0; jj < 8; ++jj) red[tid >> 6][jj] = y[jj];
    }
    __syncthreads();
    if (tid < 4) {
        float a0s = red[0][2 * tid] + red[1][2 * tid] + red[2][2 * tid] + red[3][2 * tid];
        float a1s = red[0][2 * tid + 1] + red[1][2 * tid + 1] + red[2][2 * tid + 1] + red[3][2 * tid + 1];
        out[(size_t)tid * 4096 + c] = a0s / (1.f + expf(-a0s)) * a1s;
    }
}

extern "C" void kernel_launch(void* const* d_in, const int* in_sizes, int n_in,
                              void* d_out, int out_size, void* d_ws, size_t ws_size,
                              hipStream_t stream) {
    const float* x = (const float*)d_in[0];
    const float* cls = (const float*)d_in[1];
    const float* roots = (const float*)d_in[2];
    const float* crw = (const float*)d_in[3];
    const float* ccw = (const float*)d_in[4];
    const float* kv_w = (const float*)d_in[5];
    const float* gamma = (const float*)d_in[6];
    const float* beta = (const float*)d_in[7];
    const float* ffin = (const float*)d_in[8];
    const float* ffout = (const float*)d_in[9];
    const float* ow = (const float*)d_in[10];
    const int* cridx = (const int*)d_in[11];
    const int* ccidx = (const int*)d_in[12];
    float* out = (float*)d_out;

    // Workspace (floats), total 25,165,824 fl = 100.7 MB
    float* ws = (float*)d_ws;
    // Region A [0, 8388608)
    float* q = ws;                              // 4M fl
    float* kvb = ws + 4194304;                  // 2M fl
    __bf16* kbf = (__bf16*)(ws + 6291456);      // 1M bf16
    __bf16* vtb = (__bf16*)(ws + 6815744);      // 1M bf16
    // Region B [8388608, 16777216): o_bf; early: x/kvw hi-lo splits
    __bf16* o_bf = (__bf16*)(ws + 8388608);
    __bf16* xhi = (__bf16*)(ws + 8388608);
    __bf16* xlo = (__bf16*)(ws + 8912896);
    __bf16* kvwhi = (__bf16*)(ws + 9437184);
    __bf16* kvwlo = (__bf16*)(ws + 10485760);
    // Region D [16777216, 25165824)
    float* qdet = ws + 16777216;                // 4M fl (early)
    __bf16* qbf = (__bf16*)(ws + 20971520);     // 4M bf16
    // FFN phase (A + D reuse)
    __bf16* w1bf = (__bf16*)ws;
    __bf16* w2bf = (__bf16*)(ws + 3145728);
    float* mu = ws + 4718592;
    float* rstd = mu + 16384;
    __bf16* fbf = (__bf16*)(ws + 16777216);
    __bf16* u_s = (__bf16*)(ws + 18874368);

    hipMemcpyAsync(q, cls, 4194304 * sizeof(float), hipMemcpyDeviceToDevice, stream);
    scatter1<<<4096, 256, 0, stream>>>(roots, crw, cridx, q);
    hipMemcpyAsync(qdet, q, 4194304 * sizeof(float), hipMemcpyDeviceToDevice, stream);
    scatter2<<<8192, 256, 0, stream>>>(qdet, ccw, ccidx, q);
    rms_q_bf<<<16384, 256, 0, stream>>>(q, qbf);
    split8<<<512, 256, 0, stream>>>(x, xhi, xlo, 131072);
    split8<<<1024, 256, 0, stream>>>(kv_w, kvwhi, kvwlo, 262144);
    gemm_kv_mfma<<<dim3(16, 32), 256, 0, stream>>>(xhi, xlo, kvwhi, kvwlo, kvb);
    kvsplit_bf<<<4096, 256, 0, stream>>>(kvb, kbf);
    vtrans_bf<<<256, 256, 0, stream>>>(kvb, vtb);
    attn_mfma<<<1024, 256, 0, stream>>>(qbf, kbf, vtb, o_bf);

    cvt_bf16<<<3072, 256, 0, stream>>>(ffin, w1bf, 786432);
    cvt_bf16<<<1536, 256, 0, stream>>>(ffout, w2bf, 393216);
    ln_stats<<<16384, 256, 0, stream>>>(o_bf, mu, rstd);
    for (int sl = 0; sl < 4; ++sl) {
        int R0 = sl * 4096;
        ln_apply<<<2048, 256, 0, stream>>>(o_bf, mu, rstd, gamma, beta, fbf, R0);
        gemm1_mfma<<<dim3(48, 32), 256, 0, stream>>>(fbf, w1bf, u_s);
        gemm2_mfma<<<dim3(8, 64), 256, 0, stream>>>(u_s, w2bf, o_bf + (size_t)R0 * 1024);
    }
    out_proj4<<<4096, 256, 0, stream>>>(o_bf, ow, out);
}

// Round 9
// 818.200 us; speedup vs baseline: 8.6025x; 1.0816x over previous
//
#include <hip/hip_runtime.h>
#include <math.h>

#define EPS 1e-5f

typedef __bf16 bf16x8 __attribute__((ext_vector_type(8)));
typedef __bf16 bf16x4 __attribute__((ext_vector_type(4)));
typedef float f32x4 __attribute__((ext_vector_type(4)));

#define GPTR(p) ((const __attribute__((address_space(1))) void*)(p))
#define LPTR(p) ((__attribute__((address_space(3))) void*)(p))

// ---------------- wave reduction helpers ----------------
__device__ __forceinline__ float wave_sum(float v) {
#pragma unroll
    for (int o = 32; o; o >>= 1) v += __shfl_xor(v, o);
    return v;
}

// ---------------- scatter 1 ----------------
__global__ __launch_bounds__(256) void scatter1(const float* __restrict__ roots,
                                                const float* __restrict__ w,
                                                const int* __restrict__ idx,
                                                float* __restrict__ q) {
    int unit = (blockIdx.x << 2) + (threadIdx.x >> 6);
    int lane = threadIdx.x & 63;
    int h = unit >> 10;
    int i = unit & 1023;
    int r = idx[i];
    int c = idx[1024 + i];
    float val = roots[(h * 256 + r) * 64 + lane];
    float ss = wave_sum(val * val);
    float rs = rsqrtf(ss * (1.f / 64.f) + EPS);
    atomicAdd(&q[(h * 4096 + c) * 64 + lane], val * rs * w[(h << 10) + i]);
}

// ---------------- scatter 2 ----------------
__global__ __launch_bounds__(256) void scatter2(const float* __restrict__ qdet,
                                                const float* __restrict__ w,
                                                const int* __restrict__ idx,
                                                float* __restrict__ q) {
    int unit = (blockIdx.x << 2) + (threadIdx.x >> 6);
    int lane = threadIdx.x & 63;
    int h = unit >> 11;
    int i = unit & 2047;
    int c1 = idx[i];
    int c2 = idx[2048 + i];
    float val = qdet[(h * 4096 + c1) * 64 + lane] * w[(h << 11) + i];
    atomicAdd(&q[(h * 4096 + c2) * 64 + lane], val);
}

// ---------------- rmsnorm rows of 64 -> bf16 ----------------
__global__ __launch_bounds__(256) void rms_q_bf(const float* __restrict__ q,
                                                __bf16* __restrict__ qb) {
    int unit = (blockIdx.x << 2) + (threadIdx.x >> 6);
    int lane = threadIdx.x & 63;
    float v = q[(size_t)unit * 64 + lane];
    float ss = wave_sum(v * v);
    float r = v * rsqrtf(ss * (1.f / 64.f) + EPS);
    qb[(size_t)unit * 64 + lane] = (__bf16)r;
}

// ---------------- split fp32 -> hi/lo bf16 (8/thread) ----------------
__global__ __launch_bounds__(256) void split8(const float* __restrict__ in,
                                              __bf16* __restrict__ hi,
                                              __bf16* __restrict__ lo, int n8) {
    int i = blockIdx.x * 256 + threadIdx.x;
    if (i >= n8) return;
    const float4* p = (const float4*)in + (size_t)i * 2;
    float4 u0 = p[0], u1 = p[1];
    float f[8] = {u0.x, u0.y, u0.z, u0.w, u1.x, u1.y, u1.z, u1.w};
    bf16x8 vh, vl;
#pragma unroll
    for (int j = 0; j < 8; ++j) {
        vh[j] = (__bf16)f[j];
        vl[j] = (__bf16)(f[j] - (float)vh[j]);
    }
    *((bf16x8*)hi + i) = vh;
    *((bf16x8*)lo + i) = vl;
}

// ---------------- MFMA GEMM: kv = x @ kv_w^T, hi/lo 3-term, fp32 out ----------------
// BM=32, BN=128, BK=64; grid (16,32) = 512 blocks = 2/CU. XOR-swizzled LDS.
__global__ __launch_bounds__(256) void gemm_kv_mfma(const __bf16* __restrict__ Ah,
                                                    const __bf16* __restrict__ Al,
                                                    const __bf16* __restrict__ Bh,
                                                    const __bf16* __restrict__ Bl,
                                                    float* __restrict__ Cout) {
    __shared__ __bf16 sAh[32 * 64], sAl[32 * 64];
    __shared__ __bf16 sBh[128 * 64], sBl[128 * 64];
    int tid = threadIdx.x;
    int bn = blockIdx.x, bm = blockIdx.y;
    int lane = tid & 63;
    int w = tid >> 6;
    int wr = (w >> 1) * 16, wc = (w & 1) * 64;
    int frow = lane & 15, g = lane >> 4;
    int rx = frow & 7;
    f32x4 acc[4] = {};
    const __bf16* Ahb = Ah + (size_t)(bm * 32) * 1024;
    const __bf16* Alb = Al + (size_t)(bm * 32) * 1024;
    const __bf16* Bhb = Bh + (size_t)(bn * 128) * 1024;
    const __bf16* Blb = Bl + (size_t)(bn * 128) * 1024;
    for (int k0 = 0; k0 < 1024; k0 += 64) {
        {
            int e = tid * 8;
            int r = e >> 6;
            int sc = (((e >> 3) & 7) ^ (r & 7)) << 3;
            __builtin_amdgcn_global_load_lds(GPTR(Ahb + (size_t)r * 1024 + k0 + sc), LPTR(sAh + e), 16, 0, 0);
            __builtin_amdgcn_global_load_lds(GPTR(Alb + (size_t)r * 1024 + k0 + sc), LPTR(sAl + e), 16, 0, 0);
        }
#pragma unroll
        for (int t = 0; t < 4; ++t) {
            int e = (t * 256 + tid) * 8;
            int r = e >> 6;
            int sc = (((e >> 3) & 7) ^ (r & 7)) << 3;
            __builtin_amdgcn_global_load_lds(GPTR(Bhb + (size_t)r * 1024 + k0 + sc), LPTR(sBh + e), 16, 0, 0);
            __builtin_amdgcn_global_load_lds(GPTR(Blb + (size_t)r * 1024 + k0 + sc), LPTR(sBl + e), 16, 0, 0);
        }
        __syncthreads();
#pragma unroll
        for (int ks = 0; ks < 2; ++ks) {
            int ch = ((ks * 4 + g) ^ rx) << 3;
            bf16x8 ah, al, bh2[4], bl2[4];
            ah = *(const bf16x8*)(sAh + (wr + frow) * 64 + ch);
            al = *(const bf16x8*)(sAl + (wr + frow) * 64 + ch);
#pragma unroll
            for (int n = 0; n < 4; ++n) {
                bh2[n] = *(const bf16x8*)(sBh + (wc + n * 16 + frow) * 64 + ch);
                bl2[n] = *(const bf16x8*)(sBl + (wc + n * 16 + frow) * 64 + ch);
            }
#pragma unroll
            for (int n = 0; n < 4; ++n) {
                acc[n] = __builtin_amdgcn_mfma_f32_16x16x32_bf16(ah, bh2[n], acc[n], 0, 0, 0);
                acc[n] = __builtin_amdgcn_mfma_f32_16x16x32_bf16(ah, bl2[n], acc[n], 0, 0, 0);
                acc[n] = __builtin_amdgcn_mfma_f32_16x16x32_bf16(al, bh2[n], acc[n], 0, 0, 0);
            }
        }
        __syncthreads();
    }
    int crow = (lane >> 4) * 4, ccol = lane & 15;
#pragma unroll
    for (int n = 0; n < 4; ++n)
#pragma unroll
        for (int j = 0; j < 4; ++j) {
            int row = bm * 32 + wr + crow + j;
            int col = bn * 128 + wc + n * 16 + ccol;
            Cout[(size_t)row * 2048 + col] = acc[n][j];
        }
}

// ---------------- kv split: K rmsnorm -> bf16 [bh][s][64] ----------------
__global__ __launch_bounds__(256) void kvsplit_bf(const float* __restrict__ kv,
                                                  __bf16* __restrict__ kb) {
    int unit = (blockIdx.x << 2) + (threadIdx.x >> 6);  // bh*256+s
    int lane = threadIdx.x & 63;
    int b = unit >> 12;
    int h = (unit >> 8) & 15;
    int s = unit & 255;
    float kvl = kv[(size_t)(b * 256 + s) * 2048 + (h << 6) + lane];
    float ss = wave_sum(kvl * kvl);
    float kn = kvl * rsqrtf(ss * (1.f / 64.f) + EPS);
    kb[(size_t)unit * 64 + lane] = (__bf16)kn;
}

// ---------------- V transpose: kv -> vt bf16 [bh][d=64][s=256] ----------------
__global__ __launch_bounds__(256) void vtrans_bf(const float* __restrict__ kv,
                                                 __bf16* __restrict__ vt) {
    __shared__ float T[64][65];
    int bh = blockIdx.x >> 2;
    int sc = blockIdx.x & 3;
    int b = bh >> 4, h = bh & 15;
    int tid = threadIdx.x;
    int s0 = sc * 64;
    int sl = tid >> 2, d0 = (tid & 3) * 16;
    const float* src = kv + (size_t)(b * 256 + s0 + sl) * 2048 + 1024 + (h << 6) + d0;
#pragma unroll
    for (int t = 0; t < 4; ++t) {
        float4 v4 = *(const float4*)(src + t * 4);
        T[sl][d0 + t * 4 + 0] = v4.x;
        T[sl][d0 + t * 4 + 1] = v4.y;
        T[sl][d0 + t * 4 + 2] = v4.z;
        T[sl][d0 + t * 4 + 3] = v4.w;
    }
    __syncthreads();
    int dr = tid >> 2, c0 = (tid & 3) * 16;
    bf16x8 h0, h1;
#pragma unroll
    for (int jj = 0; jj < 8; ++jj) h0[jj] = (__bf16)T[c0 + jj][dr];
#pragma unroll
    for (int jj = 0; jj < 8; ++jj) h1[jj] = (__bf16)T[c0 + 8 + jj][dr];
    size_t base = (size_t)bh * 16384 + (size_t)dr * 256 + s0 + c0;
    *(bf16x8*)(vt + base) = h0;
    *(bf16x8*)(vt + base + 8) = h1;
}

// ---------------- MFMA attention (plain bf16, no-max softmax, 4 q-tiles/block) --------
__global__ __launch_bounds__(256) void attn_mfma(const __bf16* __restrict__ qb,
                                                 const __bf16* __restrict__ kb,
                                                 const __bf16* __restrict__ vtb,
                                                 __bf16* __restrict__ ob) {
    const int PST = 268;
    __shared__ __align__(16) unsigned char smem[64 * 268 * 2];
    __shared__ float wsum[4][64];
    __shared__ float denomL[64];
    __bf16* P = (__bf16*)smem;
    __bf16* Ot = (__bf16*)smem;

    int wg = blockIdx.x;
    int swz = (wg & 7) * 128 + (wg >> 3);
    int bh = swz >> 4;
    int qg = swz & 15;
    int b = bh >> 4, h = bh & 15;
    int tid = threadIdx.x;
    int lane = tid & 63;
    int w = tid >> 6;
    int frow = lane & 15;
    int fk = (lane >> 4) * 8;
    int crow = (lane >> 4) * 4;
    int ccol = lane & 15;
    int wsr = w * 64;

    const __bf16* kh = kb + (size_t)bh * 16384;
    const __bf16* vh = vtb + (size_t)bh * 16384;

    for (int t = 0; t < 4; ++t) {
        int q0 = qg * 256 + t * 64;
        const __bf16* qh = qb + (size_t)h * 262144 + (size_t)q0 * 64;

        f32x4 acc[4][4] = {};
#pragma unroll
        for (int ks = 0; ks < 2; ++ks) {
            bf16x8 kf[4];
#pragma unroll
            for (int m = 0; m < 4; ++m)
                kf[m] = *(const bf16x8*)(kh + (wsr + m * 16 + frow) * 64 + ks * 32 + fk);
#pragma unroll
            for (int n = 0; n < 4; ++n) {
                bf16x8 qf = *(const bf16x8*)(qh + (n * 16 + frow) * 64 + ks * 32 + fk);
#pragma unroll
                for (int m = 0; m < 4; ++m)
                    acc[m][n] = __builtin_amdgcn_mfma_f32_16x16x32_bf16(kf[m], qf, acc[m][n], 0, 0, 0);
            }
        }

        float lsum[4] = {0.f, 0.f, 0.f, 0.f};
#pragma unroll
        for (int m = 0; m < 4; ++m)
#pragma unroll
            for (int n = 0; n < 4; ++n)
#pragma unroll
                for (int j = 0; j < 4; ++j) {
                    float p = __expf(acc[m][n][j] * 0.125f);
                    acc[m][n][j] = p;
                    lsum[n] += p;
                }
#pragma unroll
        for (int n = 0; n < 4; ++n) {
            float v = lsum[n];
            v += __shfl_xor(v, 16);
            v += __shfl_xor(v, 32);
            lsum[n] = v;
        }

        if (t) __syncthreads();  // B0: prior tile's Ot reads done

        if (lane < 16) {
#pragma unroll
            for (int n = 0; n < 4; ++n) wsum[w][n * 16 + lane] = lsum[n];
        }
#pragma unroll
        for (int m = 0; m < 4; ++m)
#pragma unroll
            for (int n = 0; n < 4; ++n) {
                bf16x4 pv;
#pragma unroll
                for (int j = 0; j < 4; ++j) pv[j] = (__bf16)acc[m][n][j];
                *(bf16x4*)(P + (n * 16 + ccol) * PST + wsr + m * 16 + crow) = pv;
            }
        bf16x8 vpre[2][4];
#pragma unroll
        for (int ks = 0; ks < 2; ++ks)
#pragma unroll
            for (int m = 0; m < 4; ++m)
                vpre[ks][m] = *(const bf16x8*)(vh + (m * 16 + frow) * 256 + ks * 32 + fk);
        __syncthreads();  // B1: P + wsum visible
        if (tid < 64)
            denomL[tid] = wsum[0][tid] + wsum[1][tid] + wsum[2][tid] + wsum[3][tid];

        f32x4 accO[4] = {};
#pragma unroll
        for (int ks = 0; ks < 2; ++ks) {
            bf16x8 pf = *(const bf16x8*)(P + (w * 16 + frow) * PST + ks * 32 + fk);
#pragma unroll
            for (int m = 0; m < 4; ++m)
                accO[m] = __builtin_amdgcn_mfma_f32_16x16x32_bf16(vpre[ks][m], pf, accO[m], 0, 0, 0);
        }
#pragma unroll
        for (int ks = 2; ks < 8; ++ks) {
            bf16x8 pf = *(const bf16x8*)(P + (w * 16 + frow) * PST + ks * 32 + fk);
#pragma unroll
            for (int m = 0; m < 4; ++m) {
                bf16x8 vf = *(const bf16x8*)(vh + (m * 16 + frow) * 256 + ks * 32 + fk);
                accO[m] = __builtin_amdgcn_mfma_f32_16x16x32_bf16(vf, pf, accO[m], 0, 0, 0);
            }
        }
        __syncthreads();  // B2
        float rd = 1.0f / denomL[w * 16 + ccol];
#pragma unroll
        for (int m = 0; m < 4; ++m) {
            bf16x4 ov;
#pragma unroll
            for (int j = 0; j < 4; ++j) ov[j] = (__bf16)(accO[m][j] * rd);
            *(bf16x4*)(Ot + (w * 16 + ccol) * 72 + m * 16 + crow) = ov;
        }
        __syncthreads();  // B3
        {
            int qq = tid >> 2, dc = tid & 3;
            bf16x8 o0 = *(const bf16x8*)(Ot + qq * 72 + dc * 16);
            bf16x8 o1 = *(const bf16x8*)(Ot + qq * 72 + dc * 16 + 8);
            size_t base = (size_t)((b << 12) + q0 + qq) * 1024 + (h << 6) + dc * 16;
            *(bf16x8*)(ob + base) = o0;
            *(bf16x8*)(ob + base + 8) = o1;
        }
    }
}

// ---------------- fp32 -> bf16 conversion ----------------
__global__ __launch_bounds__(256) void cvt_bf16(const float* __restrict__ in,
                                                __bf16* __restrict__ out, int n8) {
    int i = blockIdx.x * 256 + threadIdx.x;
    if (i >= n8) return;
    const float4* p = (const float4*)in + (size_t)i * 2;
    float4 u0 = p[0], u1 = p[1];
    bf16x8 v;
    v[0] = (__bf16)u0.x; v[1] = (__bf16)u0.y; v[2] = (__bf16)u0.z; v[3] = (__bf16)u0.w;
    v[4] = (__bf16)u1.x; v[5] = (__bf16)u1.y; v[6] = (__bf16)u1.z; v[7] = (__bf16)u1.w;
    *((bf16x8*)out + i) = v;
}

// ---------------- LayerNorm stats (bf16 input) ----------------
__global__ __launch_bounds__(256) void ln_stats(const __bf16* __restrict__ ob,
                                                float* __restrict__ mu,
                                                float* __restrict__ rstd) {
    __shared__ float r0[4], r1[4];
    int row = blockIdx.x;
    int tid = threadIdx.x;
    const bf16x4* op = (const bf16x4*)(ob + (size_t)row * 1024);
    bf16x4 v = op[tid];
    float s = 0, sq = 0;
#pragma unroll
    for (int j = 0; j < 4; ++j) { float f = (float)v[j]; s += f; sq += f * f; }
    s = wave_sum(s);
    sq = wave_sum(sq);
    if ((tid & 63) == 0) { r0[tid >> 6] = s; r1[tid >> 6] = sq; }
    __syncthreads();
    if (tid == 0) {
        float S = r0[0] + r0[1] + r0[2] + r0[3];
        float Q = r1[0] + r1[1] + r1[2] + r1[3];
        float m = S * (1.f / 1024.f);
        float var = Q * (1.f / 1024.f) - m * m;
        mu[row] = m;
        rstd[row] = rsqrtf(var + EPS);
    }
}

// ---------------- LN apply -> bf16 f (slice-local) ----------------
__global__ __launch_bounds__(256) void ln_apply(const __bf16* __restrict__ ob,
                                                const float* __restrict__ mu,
                                                const float* __restrict__ rstd,
                                                const float* __restrict__ gamma,
                                                const float* __restrict__ beta,
                                                __bf16* __restrict__ f, int R0) {
    int i = blockIdx.x * 256 + threadIdx.x;
    int row = i >> 7;
    int c8 = (i & 127) * 8;
    int gr = R0 + row;
    float m = mu[gr], rs = rstd[gr];
    bf16x8 ov = *((const bf16x8*)(ob + (size_t)gr * 1024 + c8));
    bf16x8 r;
#pragma unroll
    for (int j = 0; j < 8; ++j) {
        float v = (float)ov[j];
        r[j] = (__bf16)((v - m) * rs * gamma[c8 + j] + beta[c8 + j]);
    }
    *((bf16x8*)(f + (size_t)row * 1024 + c8)) = r;
}

// ---------------- MFMA GEMM1: u = silu(f@W1a^T) * (f@W1b^T) ----------------
// 1D grid 1536, XCD-bijective swizzle (6 bn x 32 bm per XCD). XOR-swizzled LDS.
// B-tile = 64 rows W1a + 64 rows W1b (same output cols); waves 0,2 f1; 1,3 f2.
__global__ __launch_bounds__(256) void gemm1_mfma(const __bf16* __restrict__ A,
                                                  const __bf16* __restrict__ W,
                                                  __bf16* __restrict__ U) {
    __shared__ __align__(16) unsigned char smemraw[32768];
    __bf16* sA = (__bf16*)smemraw;             // [128*64]
    __bf16* sB = (__bf16*)(smemraw + 16384);   // [128*64]
    float* sEx = (float*)smemraw;              // epilogue alias
    const int K = 1024;
    int tid = threadIdx.x;
    int flat = blockIdx.x;
    int f2i = (flat & 7) * 192 + (flat >> 3);
    int bm = f2i & 31;   // 0..31
    int bn = f2i >> 5;   // 0..47
    int lane = tid & 63;
    int w = tid >> 6;
    int wr = (w >> 1) * 64, wc = (w & 1) * 64;
    f32x4 acc[4][4] = {};
    const __bf16* Ab = A + (size_t)(bm * 128) * K;
    const __bf16* B1b = W + (size_t)(bn * 64) * K;
    const __bf16* B2b = W + (size_t)(3072 + bn * 64) * K;
    int frow = lane & 15, g = lane >> 4;
    int rx = frow & 7;
    for (int k0 = 0; k0 < K; k0 += 64) {
#pragma unroll
        for (int t = 0; t < 4; ++t) {
            int e = (t * 256 + tid) * 8;
            int r = e >> 6;
            int sc = (((e >> 3) & 7) ^ (r & 7)) << 3;
            __builtin_amdgcn_global_load_lds(GPTR(Ab + (size_t)r * K + k0 + sc), LPTR(sA + e), 16, 0, 0);
        }
#pragma unroll
        for (int t = 0; t < 2; ++t) {
            int e = (t * 256 + tid) * 8;
            int r = e >> 6;
            int sc = (((e >> 3) & 7) ^ (r & 7)) << 3;
            __builtin_amdgcn_global_load_lds(GPTR(B1b + (size_t)r * K + k0 + sc), LPTR(sB + e), 16, 0, 0);
        }
#pragma unroll
        for (int t = 2; t < 4; ++t) {
            int e = (t * 256 + tid) * 8;
            int r = e >> 6;  // 64..127
            int sc = (((e >> 3) & 7) ^ (r & 7)) << 3;
            __builtin_amdgcn_global_load_lds(GPTR(B2b + (size_t)(r - 64) * K + k0 + sc), LPTR(sB + e), 16, 0, 0);
        }
        __syncthreads();
#pragma unroll
        for (int ks = 0; ks < 2; ++ks) {
            int ch = ((ks * 4 + g) ^ rx) << 3;
            bf16x8 a[4], b[4];
#pragma unroll
            for (int m = 0; m < 4; ++m)
                a[m] = *(const bf16x8*)(sA + (wr + m * 16 + frow) * 64 + ch);
#pragma unroll
            for (int n = 0; n < 4; ++n)
                b[n] = *(const bf16x8*)(sB + (wc + n * 16 + frow) * 64 + ch);
#pragma unroll
            for (int m = 0; m < 4; ++m)
#pragma unroll
                for (int n = 0; n < 4; ++n)
                    acc[m][n] = __builtin_amdgcn_mfma_f32_16x16x32_bf16(a[m], b[n], acc[m][n], 0, 0, 0);
        }
        __syncthreads();
    }
    int crow = (lane >> 4) * 4, ccol = lane & 15;
    if ((w & 1) == 0) {
#pragma unroll
        for (int m = 0; m < 4; ++m)
#pragma unroll
            for (int n = 0; n < 4; ++n)
#pragma unroll
                for (int j = 0; j < 4; ++j)
                    sEx[(wr + m * 16 + crow + j) * 64 + n * 16 + ccol] = acc[m][n][j];
    }
    __syncthreads();
    if (w & 1) {
#pragma unroll
        for (int m = 0; m < 4; ++m)
#pragma unroll
            for (int n = 0; n < 4; ++n)
#pragma unroll
                for (int j = 0; j < 4; ++j) {
                    int row = wr + m * 16 + crow + j;
                    int col = n * 16 + ccol;
                    float f1 = sEx[row * 64 + col];
                    float fv2 = acc[m][n][j];
                    float sg = f1 / (1.f + expf(-f1));
                    U[(size_t)(bm * 128 + row) * 3072 + bn * 64 + col] = (__bf16)(sg * fv2);
                }
    }
}

// ---------------- MFMA GEMM2: z = o + u@W2^T (in place), 64x128 tile ----------------
// 1D grid 512, XCD-bijective swizzle (8 bn x 8 bm per XCD). XOR-swizzled LDS.
__global__ __launch_bounds__(256) void gemm2_mfma(const __bf16* __restrict__ U,
                                                  const __bf16* __restrict__ W2,
                                                  __bf16* __restrict__ Oz) {
    __shared__ __bf16 sA[64 * 64];
    __shared__ __bf16 sB[128 * 64];
    const int K = 3072;
    int tid = threadIdx.x;
    int flat = blockIdx.x;
    int f2i = (flat & 7) * 64 + (flat >> 3);
    int bn = f2i & 7;    // 0..7
    int bm = f2i >> 3;   // 0..63
    int lane = tid & 63;
    int w = tid >> 6;
    int wr = (w >> 1) * 32, wc = (w & 1) * 64;
    f32x4 acc[2][4] = {};
    const __bf16* Ab = U + (size_t)(bm * 64) * K;
    const __bf16* Bb = W2 + (size_t)(bn * 128) * K;
    int frow = lane & 15, g = lane >> 4;
    int rx = frow & 7;
    for (int k0 = 0; k0 < K; k0 += 64) {
#pragma unroll
        for (int t = 0; t < 2; ++t) {
            int e = (t * 256 + tid) * 8;
            int r = e >> 6;
            int sc = (((e >> 3) & 7) ^ (r & 7)) << 3;
            __builtin_amdgcn_global_load_lds(GPTR(Ab + (size_t)r * K + k0 + sc), LPTR(sA + e), 16, 0, 0);
        }
#pragma unroll
        for (int t = 0; t < 4; ++t) {
            int e = (t * 256 + tid) * 8;
            int r = e >> 6;
            int sc = (((e >> 3) & 7) ^ (r & 7)) << 3;
            __builtin_amdgcn_global_load_lds(GPTR(Bb + (size_t)r * K + k0 + sc), LPTR(sB + e), 16, 0, 0);
        }
        __syncthreads();
#pragma unroll
        for (int ks = 0; ks < 2; ++ks) {
            int ch = ((ks * 4 + g) ^ rx) << 3;
            bf16x8 a[2], b[4];
#pragma unroll
            for (int m = 0; m < 2; ++m)
                a[m] = *(const bf16x8*)(sA + (wr + m * 16 + frow) * 64 + ch);
#pragma unroll
            for (int n = 0; n < 4; ++n)
                b[n] = *(const bf16x8*)(sB + (wc + n * 16 + frow) * 64 + ch);
#pragma unroll
            for (int m = 0; m < 2; ++m)
#pragma unroll
                for (int n = 0; n < 4; ++n)
                    acc[m][n] = __builtin_amdgcn_mfma_f32_16x16x32_bf16(a[m], b[n], acc[m][n], 0, 0, 0);
        }
        __syncthreads();
    }
    int crow = (lane >> 4) * 4, ccol = lane & 15;
#pragma unroll
    for (int m = 0; m < 2; ++m)
#pragma unroll
        for (int n = 0; n < 4; ++n)
#pragma unroll
            for (int j = 0; j < 4; ++j) {
                int row = bm * 64 + wr + m * 16 + crow + j;
                int col = bn * 128 + wc + n * 16 + ccol;
                size_t off = (size_t)row * 1024 + col;
                float z = (float)Oz[off] + acc[m][n][j];
                Oz[off] = (__bf16)z;
            }
}

// ---------------- final projection: 4 batch rows per block ----------------
__global__ __launch_bounds__(256) void out_proj4(const __bf16* __restrict__ z,
                                                 const float* __restrict__ ow,
                                                 float* __restrict__ out) {
    __shared__ float red[4][8];
    int c = blockIdx.x;
    int tid = threadIdx.x;
    int a0 = tid * 4;
    const float4* w4 = (const float4*)(ow + (size_t)c * 2048);
    float4 wA = w4[tid * 2];
    float4 wB = w4[tid * 2 + 1];
    float y[8];
#pragma unroll
    for (int jj = 0; jj < 8; ++jj) y[jj] = 0.f;
#pragma unroll
    for (int bb = 0; bb < 4; ++bb) {
        bf16x4 zv = *(const bf16x4*)(z + (size_t)((bb << 12) + c) * 1024 + a0);
        float z0 = (float)zv[0], z1 = (float)zv[1], z2 = (float)zv[2], z3 = (float)zv[3];
        y[2 * bb] += z0 * wA.x + z1 * wA.z + z2 * wB.x + z3 * wB.z;
        y[2 * bb + 1] += z0 * wA.y + z1 * wA.w + z2 * wB.y + z3 * wB.w;
    }
#pragma unroll
    for (int jj = 0; jj < 8; ++jj) y[jj] = wave_sum(y[jj]);
    if ((tid & 63) == 0) {
#pragma unroll
        for (int jj = 0; jj < 8; ++jj) red[tid >> 6][jj] = y[jj];
    }
    __syncthreads();
    if (tid < 4) {
        float a0s = red[0][2 * tid] + red[1][2 * tid] + red[2][2 * tid] + red[3][2 * tid];
        float a1s = red[0][2 * tid + 1] + red[1][2 * tid + 1] + red[2][2 * tid + 1] + red[3][2 * tid + 1];
        out[(size_t)tid * 4096 + c] = a0s / (1.f + expf(-a0s)) * a1s;
    }
}

extern "C" void kernel_launch(void* const* d_in, const int* in_sizes, int n_in,
                              void* d_out, int out_size, void* d_ws, size_t ws_size,
                              hipStream_t stream) {
    const float* x = (const float*)d_in[0];
    const float* cls = (const float*)d_in[1];
    const float* roots = (const float*)d_in[2];
    const float* crw = (const float*)d_in[3];
    const float* ccw = (const float*)d_in[4];
    const float* kv_w = (const float*)d_in[5];
    const float* gamma = (const float*)d_in[6];
    const float* beta = (const float*)d_in[7];
    const float* ffin = (const float*)d_in[8];
    const float* ffout = (const float*)d_in[9];
    const float* ow = (const float*)d_in[10];
    const int* cridx = (const int*)d_in[11];
    const int* ccidx = (const int*)d_in[12];
    float* out = (float*)d_out;

    // Workspace (floats), total 25,165,824 fl = 100.7 MB
    float* ws = (float*)d_ws;
    // Region A [0, 8388608)
    float* q = ws;                              // 4M fl
    float* kvb = ws + 4194304;                  // 2M fl
    __bf16* kbf = (__bf16*)(ws + 6291456);      // 1M bf16
    __bf16* vtb = (__bf16*)(ws + 6815744);      // 1M bf16
    // Region B [8388608, 16777216): o_bf; early: x/kvw hi-lo splits
    __bf16* o_bf = (__bf16*)(ws + 8388608);
    __bf16* xhi = (__bf16*)(ws + 8388608);
    __bf16* xlo = (__bf16*)(ws + 8912896);
    __bf16* kvwhi = (__bf16*)(ws + 9437184);
    __bf16* kvwlo = (__bf16*)(ws + 10485760);
    // Region D [16777216, 25165824)
    float* qdet = ws + 16777216;                // 4M fl (early)
    __bf16* qbf = (__bf16*)(ws + 20971520);     // 4M bf16
    // FFN phase (A + D reuse)
    __bf16* w1bf = (__bf16*)ws;
    __bf16* w2bf = (__bf16*)(ws + 3145728);
    float* mu = ws + 4718592;
    float* rstd = mu + 16384;
    __bf16* fbf = (__bf16*)(ws + 16777216);
    __bf16* u_s = (__bf16*)(ws + 18874368);

    hipMemcpyAsync(q, cls, 4194304 * sizeof(float), hipMemcpyDeviceToDevice, stream);
    scatter1<<<4096, 256, 0, stream>>>(roots, crw, cridx, q);
    hipMemcpyAsync(qdet, q, 4194304 * sizeof(float), hipMemcpyDeviceToDevice, stream);
    scatter2<<<8192, 256, 0, stream>>>(qdet, ccw, ccidx, q);
    rms_q_bf<<<16384, 256, 0, stream>>>(q, qbf);
    split8<<<512, 256, 0, stream>>>(x, xhi, xlo, 131072);
    split8<<<1024, 256, 0, stream>>>(kv_w, kvwhi, kvwlo, 262144);
    gemm_kv_mfma<<<dim3(16, 32), 256, 0, stream>>>(xhi, xlo, kvwhi, kvwlo, kvb);
    kvsplit_bf<<<4096, 256, 0, stream>>>(kvb, kbf);
    vtrans_bf<<<256, 256, 0, stream>>>(kvb, vtb);
    attn_mfma<<<1024, 256, 0, stream>>>(qbf, kbf, vtb, o_bf);

    cvt_bf16<<<3072, 256, 0, stream>>>(ffin, w1bf, 786432);
    cvt_bf16<<<1536, 256, 0, stream>>>(ffout, w2bf, 393216);
    ln_stats<<<16384, 256, 0, stream>>>(o_bf, mu, rstd);
    for (int sl = 0; sl < 4; ++sl) {
        int R0 = sl * 4096;
        ln_apply<<<2048, 256, 0, stream>>>(o_bf, mu, rstd, gamma, beta, fbf, R0);
        gemm1_mfma<<<1536, 256, 0, stream>>>(fbf, w1bf, u_s);
        gemm2_mfma<<<512, 256, 0, stream>>>(u_s, w2bf, o_bf + (size_t)R0 * 1024);
    }
    out_proj4<<<4096, 256, 0, stream>>>(o_bf, ow, out);
}